// Round 1
// 226.930 us; speedup vs baseline: 1.0241x; 1.0241x over previous
//
#include <hip/hip_runtime.h>
#include <hip/hip_bf16.h>
#include <cstdint>
#include <cstddef>

// MHA B=2,S=2048,D=1024,H=16,HD=64.
// cvt(fp32->bf16) -> fused QKV GEMM (m97 global_load_lds) -> V-transpose ->
// flash attn (S^T form, 128q x 128k tiles, 8 waves x 16q, in-register P via
// cvt_pk + permlane swaps, exp2-domain softmax, defer-max) -> O GEMM.

#define B_  2
#define S_  2048
#define D_  1024
#define H_  16
#define HD_ 64

typedef __bf16 bf16x8 __attribute__((ext_vector_type(8)));
typedef __bf16 bf16x4 __attribute__((ext_vector_type(4)));
typedef float  f32x4  __attribute__((ext_vector_type(4)));

// ---- async global->LDS, 16B per lane. LDS dest must be wave-uniform base;
// HW adds lane*16 (guide §5 m97/m104). AS(3) ptr = low 32 bits of flat addr.
__device__ __forceinline__ void async16(const __bf16* g, const __bf16* l) {
  __builtin_amdgcn_global_load_lds(
      (const __attribute__((address_space(1))) void*)(uintptr_t)g,
      (__attribute__((address_space(3))) void*)(uint32_t)(uintptr_t)l,
      16, 0, 0);
}

// v_cvt_pk_bf16_f32: dst.lo16 = bf16(lo), dst.hi16 = bf16(hi)
__device__ __forceinline__ unsigned cvt_pk_bf16(float lo, float hi) {
  unsigned r;
  asm("v_cvt_pk_bf16_f32 %0, %1, %2" : "=v"(r) : "v"(lo), "v"(hi));
  return r;
}

// ---------------- fp32 -> bf16 convert (x + 4 weights) ----------------
__global__ __launch_bounds__(256) void cvt_all(const float* __restrict__ x,
    const float* __restrict__ wq, const float* __restrict__ wk,
    const float* __restrict__ wv, const float* __restrict__ wo,
    __bf16* __restrict__ xb, __bf16* __restrict__ wqb, __bf16* __restrict__ wkb,
    __bf16* __restrict__ wvb, __bf16* __restrict__ wob) {
  const int sel = blockIdx.y;
  const float* src; __bf16* dst; int n;
  if      (sel == 0) { src = x;  dst = xb;  n = B_ * S_ * D_; }
  else if (sel == 1) { src = wq; dst = wqb; n = D_ * D_; }
  else if (sel == 2) { src = wk; dst = wkb; n = D_ * D_; }
  else if (sel == 3) { src = wv; dst = wvb; n = D_ * D_; }
  else               { src = wo; dst = wob; n = D_ * D_; }
  for (int i = blockIdx.x * 256 + threadIdx.x; i * 4 < n; i += gridDim.x * 256) {
    const float4 v = *(const float4*)(src + (size_t)i * 4);
    bf16x4 o;
    o[0] = (__bf16)v.x; o[1] = (__bf16)v.y; o[2] = (__bf16)v.z; o[3] = (__bf16)v.w;
    *(bf16x4*)(dst + (size_t)i * 4) = o;
  }
}

// ---------------- m97-style GEMM body: C[M][N] = A[M][K] * B[N][K]^T ----------------
template <typename TC>
__device__ __forceinline__ void gemm97_body(const __bf16* __restrict__ A,
                                            const __bf16* __restrict__ Bm,
                                            TC* __restrict__ C,
                                            const int m0, const int n0,
                                            const int N, const int K) {
  __shared__ __align__(16) __bf16 As[128 * 64];  // unpadded: global_load_lds order
  __shared__ __align__(16) __bf16 Bs[128 * 64];
  const int tid  = threadIdx.x, lane = tid & 63, wave = tid >> 6;
  const int l15  = lane & 15,   quad = lane >> 4;
  const int wr   = wave >> 1,   wc   = wave & 1;
  const int ebase = wave * 2048 + lane * 8;  // elem offset this lane covers (chunk 0)

  f32x4 acc[4][4] = {};
  for (int k0 = 0; k0 < K; k0 += 64) {
#pragma unroll
    for (int i = 0; i < 4; ++i) {
      const int e = ebase + i * 512;
      const int row = e >> 6, col = e & 63;
      async16(A  + (size_t)(m0 + row) * K + k0 + col, As + (wave * 4 + i) * 512);
      async16(Bm + (size_t)(n0 + row) * K + k0 + col, Bs + (wave * 4 + i) * 512);
    }
    __syncthreads();
#pragma unroll
    for (int kk = 0; kk < 2; ++kk) {
      bf16x8 af[4], bfv[4];
#pragma unroll
      for (int rt = 0; rt < 4; ++rt)
        af[rt] = *(const bf16x8*)(As + (wr * 64 + rt * 16 + l15) * 64 + kk * 32 + quad * 8);
#pragma unroll
      for (int ct = 0; ct < 4; ++ct)
        bfv[ct] = *(const bf16x8*)(Bs + (wc * 64 + ct * 16 + l15) * 64 + kk * 32 + quad * 8);
#pragma unroll
      for (int rt = 0; rt < 4; ++rt)
#pragma unroll
        for (int ct = 0; ct < 4; ++ct)
          acc[rt][ct] = __builtin_amdgcn_mfma_f32_16x16x32_bf16(af[rt], bfv[ct], acc[rt][ct], 0, 0, 0);
    }
    __syncthreads();
  }
#pragma unroll
  for (int rt = 0; rt < 4; ++rt)
#pragma unroll
    for (int ct = 0; ct < 4; ++ct)
#pragma unroll
      for (int r = 0; r < 4; ++r) {
        const int row = m0 + wr * 64 + rt * 16 + quad * 4 + r;
        const int col = n0 + wc * 64 + ct * 16 + l15;
        C[(size_t)row * N + col] = (TC)acc[rt][ct][r];
      }
}

__global__ __launch_bounds__(256) void qkv_gemm(const __bf16* __restrict__ xb,
                                                const __bf16* __restrict__ wq,
                                                const __bf16* __restrict__ wk,
                                                const __bf16* __restrict__ wv,
                                                __bf16* __restrict__ qkv) {
  const int sel = blockIdx.x >> 3;  // 0..2 -> Q,K,V
  const __bf16* Bm = (sel == 0) ? wq : (sel == 1) ? wk : wv;
  __bf16* C = qkv + (size_t)sel * ((size_t)B_ * S_ * D_);
  gemm97_body<__bf16>(xb, Bm, C, blockIdx.y * 128, (blockIdx.x & 7) * 128, D_, D_);
}

__global__ __launch_bounds__(256) void o_gemm(const __bf16* __restrict__ cb,
                                              const __bf16* __restrict__ wo,
                                              float* __restrict__ out) {
  gemm97_body<float>(cb, wo, out, blockIdx.y * 128, blockIdx.x * 128, D_, D_);
}

// ---------------- V transpose: vb[B*S][D] -> vt[(b*16+h)*64+hd][S] ----------------
__global__ __launch_bounds__(256) void vtrans(const __bf16* __restrict__ vb,
                                              __bf16* __restrict__ vt) {
  __shared__ __bf16 tbuf[64][72];
  const int tid = threadIdx.x;
  const int s0 = blockIdx.x * 64, bh = blockIdx.y;
  const int b = bh >> 4, h = bh & 15;
  const __bf16* src = vb + ((size_t)b * S_ + s0) * D_ + h * HD_;
#pragma unroll
  for (int i = 0; i < 2; ++i) {
    const int r = i * 32 + (tid >> 3), c8 = (tid & 7) * 8;
    *(bf16x8*)(&tbuf[r][c8]) = *(const bf16x8*)(src + (size_t)r * D_ + c8);
  }
  __syncthreads();
  __bf16* dst = vt + (size_t)bh * HD_ * S_ + s0;
#pragma unroll
  for (int i = 0; i < 2; ++i) {
    const int hd = i * 32 + (tid >> 3), sc = (tid & 7) * 8;
    bf16x8 v;
#pragma unroll
    for (int j = 0; j < 8; ++j) v[j] = tbuf[sc + j][hd];
    *(bf16x8*)(dst + (size_t)hd * S_ + sc) = v;
  }
}

// ---------------- flash attention, S^T form, in-register P ----------------
// Block: 128 q-rows of one (b,h); 8 waves x 16 q. KV tile = 128 keys.
// S^T = K·Q^T (A=K rows from LDS, B=Q in registers): lane holds P[q=l15][32 keys]
// -> softmax fully per-lane + 2 shuffle hops (exp2 domain, mask pre-scaled).
// P->bf16 A-fragments via v_cvt_pk_bf16_f32 + permlane32/16_swap (no ps LDS).
// Defer-max rescale (THR=8 in exp2 domain -> P<=256). V pre-transposed, vt[hd][key].
__global__ __launch_bounds__(512, 4) void attn2(const __bf16* __restrict__ Q,
                                                const __bf16* __restrict__ K,
                                                const __bf16* __restrict__ Vt,
                                                const float* __restrict__ mask,
                                                __bf16* __restrict__ O) {
  constexpr int LKT = 72, LVT = 136;
  __shared__ __align__(16) __bf16 kt[128 * LKT];   // 18432 B
  __shared__ __align__(16) __bf16 vt[64 * LVT];    // 17408 B
  __shared__ __align__(16) float  msk[128];        //   512 B  (pre-scaled by log2e)

  const int tid  = threadIdx.x, lane = tid & 63, wave = tid >> 6;
  const int l15  = lane & 15,   quad = lane >> 4;
  const int b = blockIdx.z, h = blockIdx.y, q0 = blockIdx.x * 128;
  const size_t base   = (size_t)b * S_ * D_ + h * HD_;
  const size_t vtbase = (size_t)(b * H_ + h) * HD_ * S_;
  const int qw = q0 + wave * 16;
  constexpr float LOG2E = 1.44269504088896340736f;
  constexpr float SC    = 0.125f * LOG2E;          // 1/sqrt(HD) * log2(e)

  // Q fragments (B-operand: n=l15 -> q row, k = kb*32+quad*8+j)
  bf16x8 qf[2];
#pragma unroll
  for (int kb = 0; kb < 2; ++kb)
    qf[kb] = *(const bf16x8*)(Q + base + (size_t)(qw + l15) * D_ + kb * 32 + quad * 8);

  float m_run = -1e30f, l_run = 0.f;
  f32x4 oacc[4] = {};

  for (int t0 = 0; t0 < S_; t0 += 128) {
    __syncthreads();  // prior iter's readers done before restage
#pragma unroll
    for (int i = 0; i < 2; ++i) {
      const int idx = i * 512 + tid;
      { const int row = idx >> 3, c8 = (idx & 7) * 8;     // kt[128][72]
        *(bf16x8*)(kt + row * LKT + c8) =
            *(const bf16x8*)(K + base + (size_t)(t0 + row) * D_ + c8); }
      { const int row = idx >> 4, c8 = (idx & 15) * 8;    // vt[64][136]
        *(bf16x8*)(vt + row * LVT + c8) =
            *(const bf16x8*)(Vt + vtbase + (size_t)row * S_ + t0 + c8); }
    }
    if (tid < 128) msk[tid] = mask[(size_t)b * S_ + t0 + tid] * LOG2E;
    __syncthreads();

    // S^T tile: D[m=key][n=q]; lane (l15,quad): key = kti*16+quad*4+r, q = l15
    f32x4 sacc[8] = {};
    __builtin_amdgcn_s_setprio(1);
#pragma unroll
    for (int kti = 0; kti < 8; ++kti) {
      const __bf16* kr = kt + (kti * 16 + l15) * LKT + quad * 8;
      const bf16x8 a0 = *(const bf16x8*)(kr);
      const bf16x8 a1 = *(const bf16x8*)(kr + 32);
      sacc[kti] = __builtin_amdgcn_mfma_f32_16x16x32_bf16(a0, qf[0], sacc[kti], 0, 0, 0);
      sacc[kti] = __builtin_amdgcn_mfma_f32_16x16x32_bf16(a1, qf[1], sacc[kti], 0, 0, 0);
    }
    __builtin_amdgcn_s_setprio(0);

    // scale (exp2 domain) + mask, running max with 4 independent chains
    f32x4 tm4;
#pragma unroll
    for (int r = 0; r < 4; ++r) tm4[r] = -1e30f;
#pragma unroll
    for (int kti = 0; kti < 8; ++kti) {
      const f32x4 mv = *(const f32x4*)(msk + kti * 16 + quad * 4);
#pragma unroll
      for (int r = 0; r < 4; ++r) {
        sacc[kti][r] = sacc[kti][r] * SC + mv[r];
        tm4[r] = fmaxf(tm4[r], sacc[kti][r]);
      }
    }
    float tm = fmaxf(fmaxf(tm4[0], tm4[1]), fmaxf(tm4[2], tm4[3]));
    tm = fmaxf(tm, __shfl_xor(tm, 16));
    tm = fmaxf(tm, __shfl_xor(tm, 32));

    // defer-max (T13): only rescale when tile max grows past THR=8 (p <= 2^8)
    if (!__all(tm <= m_run + 8.f)) {
      const float mnew  = fmaxf(m_run, tm);
      const float alpha = __builtin_amdgcn_exp2f(m_run - mnew);
      m_run = mnew;
      l_run *= alpha;
#pragma unroll
      for (int r = 0; r < 4; ++r) {
        const float aR = __shfl(alpha, quad * 4 + r);
#pragma unroll
        for (int nt = 0; nt < 4; ++nt) oacc[nt][r] *= aR;
      }
    }

    // exp2 + pack + permlane-redistribute + PV, per kb (keys kb*32..kb*32+31)
    float ts = 0.f;
#pragma unroll
    for (int kb = 0; kb < 4; ++kb) {
      unsigned dd[2][2];
#pragma unroll
      for (int kk = 0; kk < 2; ++kk) {
        const int kti = 2 * kb + kk;
        float p[4];
#pragma unroll
        for (int r = 0; r < 4; ++r) {
          p[r] = __builtin_amdgcn_exp2f(sacc[kti][r] - m_run);
          ts += p[r];
        }
        dd[kk][0] = cvt_pk_bf16(p[0], p[1]);
        dd[kk][1] = cvt_pk_bf16(p[2], p[3]);
      }
      // quad shuffle: rows [A0,A1,A2,A3],[B0,B1,B2,B3] -> [A0,A2,B0,B2],[A1,A3,B1,B3]
      unsigned a0 = dd[0][0], b0 = dd[1][0], a1 = dd[0][1], b1 = dd[1][1];
      asm("v_permlane32_swap_b32 %0, %1" : "+v"(a0), "+v"(b0));
      asm("v_permlane16_swap_b32 %0, %1" : "+v"(a0), "+v"(b0));
      asm("v_permlane32_swap_b32 %0, %1" : "+v"(a1), "+v"(b1));
      asm("v_permlane16_swap_b32 %0, %1" : "+v"(a1), "+v"(b1));
      union { unsigned u[4]; bf16x8 v; } pw;
      pw.u[0] = a0; pw.u[1] = a1; pw.u[2] = b0; pw.u[3] = b1;
      const bf16x8 pa = pw.v;  // A[q=l15][key = kb*32 + quad*8 + j]
      __builtin_amdgcn_s_setprio(1);
#pragma unroll
      for (int nt = 0; nt < 4; ++nt) {
        const bf16x8 vf = *(const bf16x8*)(vt + (nt * 16 + l15) * LVT + kb * 32 + quad * 8);
        oacc[nt] = __builtin_amdgcn_mfma_f32_16x16x32_bf16(pa, vf, oacc[nt], 0, 0, 0);
      }
      __builtin_amdgcn_s_setprio(0);
    }
    ts += __shfl_xor(ts, 16);
    ts += __shfl_xor(ts, 32);
    l_run += ts;
  }

  // epilogue: divide by l (broadcast per acc row), store ctx
#pragma unroll
  for (int r = 0; r < 4; ++r) {
    const float lR  = __shfl(l_run, quad * 4 + r);
    const float inv = 1.0f / lR;
    const int row = qw + quad * 4 + r;
#pragma unroll
    for (int nt = 0; nt < 4; ++nt)
      O[base + (size_t)row * D_ + nt * 16 + l15] = (__bf16)(oacc[nt][r] * inv);
  }
}

extern "C" void kernel_launch(void* const* d_in, const int* in_sizes, int n_in,
                              void* d_out, int out_size, void* d_ws, size_t ws_size,
                              hipStream_t stream) {
  const float* x    = (const float*)d_in[0];
  const float* mask = (const float*)d_in[1];
  const float* Wq   = (const float*)d_in[2];
  const float* Wk   = (const float*)d_in[3];
  const float* Wv   = (const float*)d_in[4];
  const float* Wo   = (const float*)d_in[5];

  char* ws = (char*)d_ws;
  const size_t MB = 1ull << 20;
  const size_t NT = (size_t)B_ * S_ * D_;  // 4M elems, 8 MB bf16
  __bf16* xb  = (__bf16*)(ws);             // 8 MB; reused as vtb after qkv_gemm
  __bf16* wqb = (__bf16*)(ws + 8 * MB);
  __bf16* wkb = (__bf16*)(ws + 10 * MB);
  __bf16* wvb = (__bf16*)(ws + 12 * MB);
  __bf16* wob = (__bf16*)(ws + 14 * MB);
  __bf16* qkv = (__bf16*)(ws + 16 * MB);   // 24 MB
  __bf16* qb  = qkv;
  __bf16* kb  = qkv + NT;
  __bf16* vb  = qkv + 2 * NT;
  __bf16* vtb = xb;   // x consumed by qkv_gemm before vtrans writes (stream order)
  __bf16* cb  = vb;   // v consumed by vtrans before attn writes ctx

  cvt_all<<<dim3(1024, 5), 256, 0, stream>>>(x, Wq, Wk, Wv, Wo, xb, wqb, wkb, wvb, wob);
  qkv_gemm<<<dim3(24, 32), 256, 0, stream>>>(xb, wqb, wkb, wvb, qkv);
  vtrans<<<dim3(32, 32), 256, 0, stream>>>(vb, vtb);
  attn2<<<dim3(S_ / 128, H_, B_), 512, 0, stream>>>(qb, kb, vtb, mask, cb);
  o_gemm<<<dim3(8, 32), 256, 0, stream>>>(cb, wob, (float*)d_out);
}

// Round 2
// 219.219 us; speedup vs baseline: 1.0601x; 1.0352x over previous
//
#include <hip/hip_runtime.h>
#include <hip/hip_bf16.h>
#include <cstdint>
#include <cstddef>

// MHA B=2,S=2048,D=1024,H=16,HD=64.
// cvt(fp32->bf16) -> fused QKV GEMM (m97 global_load_lds) -> V-transpose ->
// flash attn (S^T form, 128q x 128k tiles, 8 waves x 16q, in-register P via
// cvt_pk + permlane swaps, exp2-domain softmax, defer-max, T14 async-stage +
// double-buffered K/V, row-sum via ones-MFMA) -> O GEMM.

#define B_  2
#define S_  2048
#define D_  1024
#define H_  16
#define HD_ 64

typedef __bf16 bf16x8 __attribute__((ext_vector_type(8)));
typedef __bf16 bf16x4 __attribute__((ext_vector_type(4)));
typedef float  f32x4  __attribute__((ext_vector_type(4)));

// ---- async global->LDS, 16B per lane. LDS dest must be wave-uniform base;
// HW adds lane*16 (guide §5 m97/m104). AS(3) ptr = low 32 bits of flat addr.
__device__ __forceinline__ void async16(const __bf16* g, const __bf16* l) {
  __builtin_amdgcn_global_load_lds(
      (const __attribute__((address_space(1))) void*)(uintptr_t)g,
      (__attribute__((address_space(3))) void*)(uint32_t)(uintptr_t)l,
      16, 0, 0);
}

// v_cvt_pk_bf16_f32: dst.lo16 = bf16(lo), dst.hi16 = bf16(hi)
__device__ __forceinline__ unsigned cvt_pk_bf16(float lo, float hi) {
  unsigned r;
  asm("v_cvt_pk_bf16_f32 %0, %1, %2" : "=v"(r) : "v"(lo), "v"(hi));
  return r;
}

// ---------------- fp32 -> bf16 convert (x + 4 weights) ----------------
__global__ __launch_bounds__(256) void cvt_all(const float* __restrict__ x,
    const float* __restrict__ wq, const float* __restrict__ wk,
    const float* __restrict__ wv, const float* __restrict__ wo,
    __bf16* __restrict__ xb, __bf16* __restrict__ wqb, __bf16* __restrict__ wkb,
    __bf16* __restrict__ wvb, __bf16* __restrict__ wob) {
  const int sel = blockIdx.y;
  const float* src; __bf16* dst; int n;
  if      (sel == 0) { src = x;  dst = xb;  n = B_ * S_ * D_; }
  else if (sel == 1) { src = wq; dst = wqb; n = D_ * D_; }
  else if (sel == 2) { src = wk; dst = wkb; n = D_ * D_; }
  else if (sel == 3) { src = wv; dst = wvb; n = D_ * D_; }
  else               { src = wo; dst = wob; n = D_ * D_; }
  for (int i = blockIdx.x * 256 + threadIdx.x; i * 4 < n; i += gridDim.x * 256) {
    const float4 v = *(const float4*)(src + (size_t)i * 4);
    bf16x4 o;
    o[0] = (__bf16)v.x; o[1] = (__bf16)v.y; o[2] = (__bf16)v.z; o[3] = (__bf16)v.w;
    *(bf16x4*)(dst + (size_t)i * 4) = o;
  }
}

// ---------------- m97-style GEMM body: C[M][N] = A[M][K] * B[N][K]^T ----------------
template <typename TC>
__device__ __forceinline__ void gemm97_body(const __bf16* __restrict__ A,
                                            const __bf16* __restrict__ Bm,
                                            TC* __restrict__ C,
                                            const int m0, const int n0,
                                            const int N, const int K) {
  __shared__ __align__(16) __bf16 As[128 * 64];  // unpadded: global_load_lds order
  __shared__ __align__(16) __bf16 Bs[128 * 64];
  const int tid  = threadIdx.x, lane = tid & 63, wave = tid >> 6;
  const int l15  = lane & 15,   quad = lane >> 4;
  const int wr   = wave >> 1,   wc   = wave & 1;
  const int ebase = wave * 2048 + lane * 8;  // elem offset this lane covers (chunk 0)

  f32x4 acc[4][4] = {};
  for (int k0 = 0; k0 < K; k0 += 64) {
#pragma unroll
    for (int i = 0; i < 4; ++i) {
      const int e = ebase + i * 512;
      const int row = e >> 6, col = e & 63;
      async16(A  + (size_t)(m0 + row) * K + k0 + col, As + (wave * 4 + i) * 512);
      async16(Bm + (size_t)(n0 + row) * K + k0 + col, Bs + (wave * 4 + i) * 512);
    }
    __syncthreads();
#pragma unroll
    for (int kk = 0; kk < 2; ++kk) {
      bf16x8 af[4], bfv[4];
#pragma unroll
      for (int rt = 0; rt < 4; ++rt)
        af[rt] = *(const bf16x8*)(As + (wr * 64 + rt * 16 + l15) * 64 + kk * 32 + quad * 8);
#pragma unroll
      for (int ct = 0; ct < 4; ++ct)
        bfv[ct] = *(const bf16x8*)(Bs + (wc * 64 + ct * 16 + l15) * 64 + kk * 32 + quad * 8);
#pragma unroll
      for (int rt = 0; rt < 4; ++rt)
#pragma unroll
        for (int ct = 0; ct < 4; ++ct)
          acc[rt][ct] = __builtin_amdgcn_mfma_f32_16x16x32_bf16(af[rt], bfv[ct], acc[rt][ct], 0, 0, 0);
    }
    __syncthreads();
  }
#pragma unroll
  for (int rt = 0; rt < 4; ++rt)
#pragma unroll
    for (int ct = 0; ct < 4; ++ct)
#pragma unroll
      for (int r = 0; r < 4; ++r) {
        const int row = m0 + wr * 64 + rt * 16 + quad * 4 + r;
        const int col = n0 + wc * 64 + ct * 16 + l15;
        C[(size_t)row * N + col] = (TC)acc[rt][ct][r];
      }
}

__global__ __launch_bounds__(256) void qkv_gemm(const __bf16* __restrict__ xb,
                                                const __bf16* __restrict__ wq,
                                                const __bf16* __restrict__ wk,
                                                const __bf16* __restrict__ wv,
                                                __bf16* __restrict__ qkv) {
  const int sel = blockIdx.x >> 3;  // 0..2 -> Q,K,V
  const __bf16* Bm = (sel == 0) ? wq : (sel == 1) ? wk : wv;
  __bf16* C = qkv + (size_t)sel * ((size_t)B_ * S_ * D_);
  gemm97_body<__bf16>(xb, Bm, C, blockIdx.y * 128, (blockIdx.x & 7) * 128, D_, D_);
}

__global__ __launch_bounds__(256) void o_gemm(const __bf16* __restrict__ cb,
                                              const __bf16* __restrict__ wo,
                                              float* __restrict__ out) {
  gemm97_body<float>(cb, wo, out, blockIdx.y * 128, blockIdx.x * 128, D_, D_);
}

// ---------------- V transpose: vb[B*S][D] -> vt[(b*16+h)*64+hd][S] ----------------
__global__ __launch_bounds__(256) void vtrans(const __bf16* __restrict__ vb,
                                              __bf16* __restrict__ vt) {
  __shared__ __bf16 tbuf[64][72];
  const int tid = threadIdx.x;
  const int s0 = blockIdx.x * 64, bh = blockIdx.y;
  const int b = bh >> 4, h = bh & 15;
  const __bf16* src = vb + ((size_t)b * S_ + s0) * D_ + h * HD_;
#pragma unroll
  for (int i = 0; i < 2; ++i) {
    const int r = i * 32 + (tid >> 3), c8 = (tid & 7) * 8;
    *(bf16x8*)(&tbuf[r][c8]) = *(const bf16x8*)(src + (size_t)r * D_ + c8);
  }
  __syncthreads();
  __bf16* dst = vt + (size_t)bh * HD_ * S_ + s0;
#pragma unroll
  for (int i = 0; i < 2; ++i) {
    const int hd = i * 32 + (tid >> 3), sc = (tid & 7) * 8;
    bf16x8 v;
#pragma unroll
    for (int j = 0; j < 8; ++j) v[j] = tbuf[sc + j][hd];
    *(bf16x8*)(dst + (size_t)hd * S_ + sc) = v;
  }
}

// ---------------- flash attention, S^T form, in-register P, T14 pipeline ----------
// Block: 128 q-rows of one (b,h); 8 waves x 16 q. KV tile = 128 keys.
// S^T = K·Q^T (A=K rows from LDS, B=Q in registers): lane holds P[q=l15][32 keys].
// P->bf16 A-fragments via v_cvt_pk_bf16_f32 + permlane32/16_swap (no ps LDS).
// Row-sum l via ones-vector MFMA (lands directly in C/D row layout).
// Defer-max rescale (THR=8 in exp2 domain -> P<=256). V pre-transposed, vt[hd][key].
// T14: issue tile t+1 global loads before computing tile t; ds_write into the
// alternate buffer after the post-compute barrier (double-buffered K/V).
__global__ __launch_bounds__(512, 4) void attn2(const __bf16* __restrict__ Q,
                                                const __bf16* __restrict__ K,
                                                const __bf16* __restrict__ Vt,
                                                const float* __restrict__ mask,
                                                __bf16* __restrict__ O) {
  constexpr int LKT = 72, LVT = 136;
  __shared__ __align__(16) __bf16 kt[2][128 * LKT];   // 2 x 18432 B
  __shared__ __align__(16) __bf16 vt[2][64 * LVT];    // 2 x 17408 B
  __shared__ __align__(16) float  mfull[S_];          // 8192 B (pre-scaled by log2e)

  const int tid  = threadIdx.x, lane = tid & 63, wave = tid >> 6;
  const int l15  = lane & 15,   quad = lane >> 4;
  const int b = blockIdx.z, h = blockIdx.y, q0 = blockIdx.x * 128;
  const size_t base   = (size_t)b * S_ * D_ + h * HD_;
  const size_t vtbase = (size_t)(b * H_ + h) * HD_ * S_;
  const int qw = q0 + wave * 16;
  constexpr float LOG2E = 1.44269504088896340736f;
  constexpr float SC    = 0.125f * LOG2E;          // 1/sqrt(HD) * log2(e)
  constexpr int  NT     = S_ / 128;

  // per-thread staging slots (2 x 16B each for K and V tiles)
  const int idx0 = tid,        kr0 = idx0 >> 3, kc0 = (idx0 & 7) * 8;
  const int idx1 = 512 + tid,  kr1 = idx1 >> 3, kc1 = (idx1 & 7) * 8;
  const int vr0 = idx0 >> 4, vc0 = (idx0 & 15) * 8;
  const int vr1 = idx1 >> 4, vc1 = (idx1 & 15) * 8;

  // Q fragments (B-operand: n=l15 -> q row, k = kb*32+quad*8+j)
  bf16x8 qf[2];
#pragma unroll
  for (int kb = 0; kb < 2; ++kb)
    qf[kb] = *(const bf16x8*)(Q + base + (size_t)(qw + l15) * D_ + kb * 32 + quad * 8);

  bf16x8 ones;
#pragma unroll
  for (int j = 0; j < 8; ++j) ones[j] = (__bf16)1.0f;

  float m_run = -1e30f;
  f32x4 oacc[4] = {};
  f32x4 lacc   = {};

  // prologue: mask table + stage tile 0 into buf 0
  bf16x8 rk0, rk1, rv0, rv1;
  rk0 = *(const bf16x8*)(K + base + (size_t)kr0 * D_ + kc0);
  rk1 = *(const bf16x8*)(K + base + (size_t)kr1 * D_ + kc1);
  rv0 = *(const bf16x8*)(Vt + vtbase + (size_t)vr0 * S_ + vc0);
  rv1 = *(const bf16x8*)(Vt + vtbase + (size_t)vr1 * S_ + vc1);
#pragma unroll
  for (int i = 0; i < S_ / 512; ++i)
    mfull[i * 512 + tid] = mask[(size_t)b * S_ + i * 512 + tid] * LOG2E;
  *(bf16x8*)(&kt[0][kr0 * LKT + kc0]) = rk0;
  *(bf16x8*)(&kt[0][kr1 * LKT + kc1]) = rk1;
  *(bf16x8*)(&vt[0][vr0 * LVT + vc0]) = rv0;
  *(bf16x8*)(&vt[0][vr1 * LVT + vc1]) = rv1;
  __syncthreads();

  for (int t = 0; t < NT; ++t) {
    const int cur = t & 1;
    const int t0  = t * 128;
    const __bf16* ktb = &kt[cur][0];
    const __bf16* vtb = &vt[cur][0];

    // T14: issue next tile's global loads now; latency hides under compute
    if (t + 1 < NT) {
      const int tn = t0 + 128;
      rk0 = *(const bf16x8*)(K + base + (size_t)(tn + kr0) * D_ + kc0);
      rk1 = *(const bf16x8*)(K + base + (size_t)(tn + kr1) * D_ + kc1);
      rv0 = *(const bf16x8*)(Vt + vtbase + (size_t)vr0 * S_ + tn + vc0);
      rv1 = *(const bf16x8*)(Vt + vtbase + (size_t)vr1 * S_ + tn + vc1);
    }

    // S^T tile: D[m=key][n=q]; lane (l15,quad): key = kti*16+quad*4+r, q = l15
    f32x4 sacc[8] = {};
    __builtin_amdgcn_s_setprio(1);
#pragma unroll
    for (int kti = 0; kti < 8; ++kti) {
      const __bf16* kr = ktb + (kti * 16 + l15) * LKT + quad * 8;
      const bf16x8 a0 = *(const bf16x8*)(kr);
      const bf16x8 a1 = *(const bf16x8*)(kr + 32);
      sacc[kti] = __builtin_amdgcn_mfma_f32_16x16x32_bf16(a0, qf[0], sacc[kti], 0, 0, 0);
      sacc[kti] = __builtin_amdgcn_mfma_f32_16x16x32_bf16(a1, qf[1], sacc[kti], 0, 0, 0);
    }
    __builtin_amdgcn_s_setprio(0);

    // scale (exp2 domain) + mask, running max with 4 independent chains
    f32x4 tm4;
#pragma unroll
    for (int r = 0; r < 4; ++r) tm4[r] = -1e30f;
#pragma unroll
    for (int kti = 0; kti < 8; ++kti) {
      const f32x4 mv = *(const f32x4*)(mfull + t0 + kti * 16 + quad * 4);
#pragma unroll
      for (int r = 0; r < 4; ++r) {
        sacc[kti][r] = sacc[kti][r] * SC + mv[r];
        tm4[r] = fmaxf(tm4[r], sacc[kti][r]);
      }
    }
    float tm = fmaxf(fmaxf(tm4[0], tm4[1]), fmaxf(tm4[2], tm4[3]));
    tm = fmaxf(tm, __shfl_xor(tm, 16));
    tm = fmaxf(tm, __shfl_xor(tm, 32));

    // defer-max (T13): only rescale when tile max grows past THR=8 (p <= 2^8)
    if (!__all(tm <= m_run + 8.f)) {
      const float mnew  = fmaxf(m_run, tm);
      const float alpha = __builtin_amdgcn_exp2f(m_run - mnew);
      m_run = mnew;
#pragma unroll
      for (int r = 0; r < 4; ++r) {
        const float aR = __shfl(alpha, quad * 4 + r);
        lacc[r] *= aR;
#pragma unroll
        for (int nt = 0; nt < 4; ++nt) oacc[nt][r] *= aR;
      }
    }

    // exp2 + pack + permlane-redistribute + PV + row-sum, per kb (32 keys each)
#pragma unroll
    for (int kb = 0; kb < 4; ++kb) {
      unsigned dd[2][2];
#pragma unroll
      for (int kk = 0; kk < 2; ++kk) {
        const int kti = 2 * kb + kk;
        float p[4];
#pragma unroll
        for (int r = 0; r < 4; ++r)
          p[r] = __builtin_amdgcn_exp2f(sacc[kti][r] - m_run);
        dd[kk][0] = cvt_pk_bf16(p[0], p[1]);
        dd[kk][1] = cvt_pk_bf16(p[2], p[3]);
      }
      // quad shuffle: rows [A0,A1,A2,A3],[B0,B1,B2,B3] -> [A0,A2,B0,B2],[A1,A3,B1,B3]
      unsigned a0 = dd[0][0], b0 = dd[1][0], a1 = dd[0][1], b1 = dd[1][1];
      asm("v_permlane32_swap_b32 %0, %1" : "+v"(a0), "+v"(b0));
      asm("v_permlane16_swap_b32 %0, %1" : "+v"(a0), "+v"(b0));
      asm("v_permlane32_swap_b32 %0, %1" : "+v"(a1), "+v"(b1));
      asm("v_permlane16_swap_b32 %0, %1" : "+v"(a1), "+v"(b1));
      union { unsigned u[4]; bf16x8 v; } pw;
      pw.u[0] = a0; pw.u[1] = a1; pw.u[2] = b0; pw.u[3] = b1;
      const bf16x8 pa = pw.v;  // A[q=l15][key = kb*32 + quad*8 + j]
      __builtin_amdgcn_s_setprio(1);
      lacc = __builtin_amdgcn_mfma_f32_16x16x32_bf16(pa, ones, lacc, 0, 0, 0);
#pragma unroll
      for (int nt = 0; nt < 4; ++nt) {
        const bf16x8 vf = *(const bf16x8*)(vtb + (nt * 16 + l15) * LVT + kb * 32 + quad * 8);
        oacc[nt] = __builtin_amdgcn_mfma_f32_16x16x32_bf16(pa, vf, oacc[nt], 0, 0, 0);
      }
      __builtin_amdgcn_s_setprio(0);
    }

    __syncthreads();  // barrier A: all waves done reading buf[cur^1] (iter t-1)
    if (t + 1 < NT) {
      const int nxt = cur ^ 1;
      *(bf16x8*)(&kt[nxt][kr0 * LKT + kc0]) = rk0;
      *(bf16x8*)(&kt[nxt][kr1 * LKT + kc1]) = rk1;
      *(bf16x8*)(&vt[nxt][vr0 * LVT + vc0]) = rv0;
      *(bf16x8*)(&vt[nxt][vr1 * LVT + vc1]) = rv1;
    }
    __syncthreads();  // barrier B: buf[cur^1] ready for next iter
  }

  // epilogue: divide by l (already in row layout via ones-MFMA), store ctx
#pragma unroll
  for (int r = 0; r < 4; ++r) {
    const float inv = 1.0f / lacc[r];
    const int row = qw + quad * 4 + r;
#pragma unroll
    for (int nt = 0; nt < 4; ++nt)
      O[base + (size_t)row * D_ + nt * 16 + l15] = (__bf16)(oacc[nt][r] * inv);
  }
}

extern "C" void kernel_launch(void* const* d_in, const int* in_sizes, int n_in,
                              void* d_out, int out_size, void* d_ws, size_t ws_size,
                              hipStream_t stream) {
  const float* x    = (const float*)d_in[0];
  const float* mask = (const float*)d_in[1];
  const float* Wq   = (const float*)d_in[2];
  const float* Wk   = (const float*)d_in[3];
  const float* Wv   = (const float*)d_in[4];
  const float* Wo   = (const float*)d_in[5];

  char* ws = (char*)d_ws;
  const size_t MB = 1ull << 20;
  const size_t NT = (size_t)B_ * S_ * D_;  // 4M elems, 8 MB bf16
  __bf16* xb  = (__bf16*)(ws);             // 8 MB; reused as vtb after qkv_gemm
  __bf16* wqb = (__bf16*)(ws + 8 * MB);
  __bf16* wkb = (__bf16*)(ws + 10 * MB);
  __bf16* wvb = (__bf16*)(ws + 12 * MB);
  __bf16* wob = (__bf16*)(ws + 14 * MB);
  __bf16* qkv = (__bf16*)(ws + 16 * MB);   // 24 MB
  __bf16* qb  = qkv;
  __bf16* kb  = qkv + NT;
  __bf16* vb  = qkv + 2 * NT;
  __bf16* vtb = xb;   // x consumed by qkv_gemm before vtrans writes (stream order)
  __bf16* cb  = vb;   // v consumed by vtrans before attn writes ctx

  cvt_all<<<dim3(1024, 5), 256, 0, stream>>>(x, Wq, Wk, Wv, Wo, xb, wqb, wkb, wvb, wob);
  qkv_gemm<<<dim3(24, 32), 256, 0, stream>>>(xb, wqb, wkb, wvb, qkv);
  vtrans<<<dim3(32, 32), 256, 0, stream>>>(vb, vtb);
  attn2<<<dim3(S_ / 128, H_, B_), 512, 0, stream>>>(qb, kb, vtb, mask, cb);
  o_gemm<<<dim3(8, 32), 256, 0, stream>>>(cb, wob, (float*)d_out);
}

// Round 3
// 214.983 us; speedup vs baseline: 1.0810x; 1.0197x over previous
//
#include <hip/hip_runtime.h>
#include <hip/hip_bf16.h>
#include <cstdint>
#include <cstddef>

// MHA B=2,S=2048,D=1024,H=16,HD=64.
// cvt(fp32->bf16) -> fused QKV GEMM (m97 global_load_lds, LDS-bounced vector
// epilogue; V written pre-transposed -> no vtrans kernel) ->
// flash attn (S^T form, 128q x 128k tiles, 8 waves x 16q, in-register P via
// cvt_pk + permlane swaps, exp2-domain softmax, defer-max, T14 async-stage +
// double-buffered K/V, row-sum via ones-MFMA) -> O GEMM.

#define B_  2
#define S_  2048
#define D_  1024
#define H_  16
#define HD_ 64

typedef __bf16 bf16x8 __attribute__((ext_vector_type(8)));
typedef __bf16 bf16x4 __attribute__((ext_vector_type(4)));
typedef float  f32x4  __attribute__((ext_vector_type(4)));

// ---- async global->LDS, 16B per lane. LDS dest must be wave-uniform base;
// HW adds lane*16 (guide §5 m97/m104). AS(3) ptr = low 32 bits of flat addr.
__device__ __forceinline__ void async16(const __bf16* g, const __bf16* l) {
  __builtin_amdgcn_global_load_lds(
      (const __attribute__((address_space(1))) void*)(uintptr_t)g,
      (__attribute__((address_space(3))) void*)(uint32_t)(uintptr_t)l,
      16, 0, 0);
}

// v_cvt_pk_bf16_f32: dst.lo16 = bf16(lo), dst.hi16 = bf16(hi)
__device__ __forceinline__ unsigned cvt_pk_bf16(float lo, float hi) {
  unsigned r;
  asm("v_cvt_pk_bf16_f32 %0, %1, %2" : "=v"(r) : "v"(lo), "v"(hi));
  return r;
}

// ---------------- fp32 -> bf16 convert (x + 4 weights) ----------------
__global__ __launch_bounds__(256) void cvt_all(const float* __restrict__ x,
    const float* __restrict__ wq, const float* __restrict__ wk,
    const float* __restrict__ wv, const float* __restrict__ wo,
    __bf16* __restrict__ xb, __bf16* __restrict__ wqb, __bf16* __restrict__ wkb,
    __bf16* __restrict__ wvb, __bf16* __restrict__ wob) {
  const int sel = blockIdx.y;
  const float* src; __bf16* dst; int n;
  if      (sel == 0) { src = x;  dst = xb;  n = B_ * S_ * D_; }
  else if (sel == 1) { src = wq; dst = wqb; n = D_ * D_; }
  else if (sel == 2) { src = wk; dst = wkb; n = D_ * D_; }
  else if (sel == 3) { src = wv; dst = wvb; n = D_ * D_; }
  else               { src = wo; dst = wob; n = D_ * D_; }
  for (int i = blockIdx.x * 256 + threadIdx.x; i * 4 < n; i += gridDim.x * 256) {
    const float4 v = *(const float4*)(src + (size_t)i * 4);
    bf16x4 o;
    o[0] = (__bf16)v.x; o[1] = (__bf16)v.y; o[2] = (__bf16)v.z; o[3] = (__bf16)v.w;
    *(bf16x4*)(dst + (size_t)i * 4) = o;
  }
}

// ---------------- m97-style GEMM body: C[M][N] = A[M][K] * B[N][K]^T ----------------
// (used by o_gemm; qkv_gemm has its own body with LDS-bounced epilogue)
template <typename TC>
__device__ __forceinline__ void gemm97_body(const __bf16* __restrict__ A,
                                            const __bf16* __restrict__ Bm,
                                            TC* __restrict__ C,
                                            const int m0, const int n0,
                                            const int N, const int K) {
  __shared__ __align__(16) __bf16 As[128 * 64];  // unpadded: global_load_lds order
  __shared__ __align__(16) __bf16 Bs[128 * 64];
  const int tid  = threadIdx.x, lane = tid & 63, wave = tid >> 6;
  const int l15  = lane & 15,   quad = lane >> 4;
  const int wr   = wave >> 1,   wc   = wave & 1;
  const int ebase = wave * 2048 + lane * 8;  // elem offset this lane covers (chunk 0)

  f32x4 acc[4][4] = {};
  for (int k0 = 0; k0 < K; k0 += 64) {
#pragma unroll
    for (int i = 0; i < 4; ++i) {
      const int e = ebase + i * 512;
      const int row = e >> 6, col = e & 63;
      async16(A  + (size_t)(m0 + row) * K + k0 + col, As + (wave * 4 + i) * 512);
      async16(Bm + (size_t)(n0 + row) * K + k0 + col, Bs + (wave * 4 + i) * 512);
    }
    __syncthreads();
#pragma unroll
    for (int kk = 0; kk < 2; ++kk) {
      bf16x8 af[4], bfv[4];
#pragma unroll
      for (int rt = 0; rt < 4; ++rt)
        af[rt] = *(const bf16x8*)(As + (wr * 64 + rt * 16 + l15) * 64 + kk * 32 + quad * 8);
#pragma unroll
      for (int ct = 0; ct < 4; ++ct)
        bfv[ct] = *(const bf16x8*)(Bs + (wc * 64 + ct * 16 + l15) * 64 + kk * 32 + quad * 8);
#pragma unroll
      for (int rt = 0; rt < 4; ++rt)
#pragma unroll
        for (int ct = 0; ct < 4; ++ct)
          acc[rt][ct] = __builtin_amdgcn_mfma_f32_16x16x32_bf16(af[rt], bfv[ct], acc[rt][ct], 0, 0, 0);
    }
    __syncthreads();
  }
#pragma unroll
  for (int rt = 0; rt < 4; ++rt)
#pragma unroll
    for (int ct = 0; ct < 4; ++ct)
#pragma unroll
      for (int r = 0; r < 4; ++r) {
        const int row = m0 + wr * 64 + rt * 16 + quad * 4 + r;
        const int col = n0 + wc * 64 + ct * 16 + l15;
        C[(size_t)row * N + col] = (TC)acc[rt][ct][r];
      }
}

// ---------------- fused QKV GEMM with LDS-bounced epilogue ----------------
// sel 0/1 (Q,K): vectorized bf16x8 row-major stores.
// sel 2   (V) : transposed store direct to Vt[b*1024 + e][s] (kills vtrans).
__global__ __launch_bounds__(256) void qkv_gemm(const __bf16* __restrict__ xb,
                                                const __bf16* __restrict__ wq,
                                                const __bf16* __restrict__ wk,
                                                const __bf16* __restrict__ wv,
                                                __bf16* __restrict__ qkv) {
  __shared__ __align__(16) __bf16 As[128 * 64];
  __shared__ __align__(16) __bf16 Bs[128 * 64];
  __shared__ __align__(16) __bf16 cs[64 * 136];   // epilogue bounce (one 64-row pass)
  const int sel = blockIdx.x >> 3;  // 0..2 -> Q,K,V
  const __bf16* Bm = (sel == 0) ? wq : (sel == 1) ? wk : wv;
  const int m0 = blockIdx.y * 128, n0 = (blockIdx.x & 7) * 128;
  constexpr int K = D_, N = D_;
  constexpr size_t NTE = (size_t)B_ * S_ * D_;

  const int tid  = threadIdx.x, lane = tid & 63, wave = tid >> 6;
  const int l15  = lane & 15,   quad = lane >> 4;
  const int wr   = wave >> 1,   wc   = wave & 1;
  const int ebase = wave * 2048 + lane * 8;

  f32x4 acc[4][4] = {};
  for (int k0 = 0; k0 < K; k0 += 64) {
#pragma unroll
    for (int i = 0; i < 4; ++i) {
      const int e = ebase + i * 512;
      const int row = e >> 6, col = e & 63;
      async16(xb + (size_t)(m0 + row) * K + k0 + col, As + (wave * 4 + i) * 512);
      async16(Bm + (size_t)(n0 + row) * K + k0 + col, Bs + (wave * 4 + i) * 512);
    }
    __syncthreads();
#pragma unroll
    for (int kk = 0; kk < 2; ++kk) {
      bf16x8 af[4], bfv[4];
#pragma unroll
      for (int rt = 0; rt < 4; ++rt)
        af[rt] = *(const bf16x8*)(As + (wr * 64 + rt * 16 + l15) * 64 + kk * 32 + quad * 8);
#pragma unroll
      for (int ct = 0; ct < 4; ++ct)
        bfv[ct] = *(const bf16x8*)(Bs + (wc * 64 + ct * 16 + l15) * 64 + kk * 32 + quad * 8);
#pragma unroll
      for (int rt = 0; rt < 4; ++rt)
#pragma unroll
        for (int ct = 0; ct < 4; ++ct)
          acc[rt][ct] = __builtin_amdgcn_mfma_f32_16x16x32_bf16(af[rt], bfv[ct], acc[rt][ct], 0, 0, 0);
    }
    __syncthreads();
  }

  // epilogue: two 64-row passes through cs
  const int b  = m0 >> 11;       // batch (S_=2048 rows per batch)
  const int s0 = m0 & (S_ - 1);
  __bf16* vtb = qkv + 2 * NTE;   // Vt lives in the old V slot
#pragma unroll
  for (int pass = 0; pass < 2; ++pass) {
    __syncthreads();  // prior pass's readers (or main-loop) done
    if (wr == pass) {
#pragma unroll
      for (int rt = 0; rt < 4; ++rt)
#pragma unroll
        for (int ct = 0; ct < 4; ++ct)
#pragma unroll
          for (int r = 0; r < 4; ++r)
            cs[(rt * 16 + quad * 4 + r) * 136 + wc * 64 + ct * 16 + l15] =
                (__bf16)acc[rt][ct][r];
    }
    __syncthreads();
    if (sel < 2) {
      __bf16* C = qkv + (size_t)sel * NTE;
      const int cc = tid & 15, rr = tid >> 4;
#pragma unroll
      for (int p2 = 0; p2 < 4; ++p2) {
        const int row = p2 * 16 + rr;
        const bf16x8 v = *(const bf16x8*)(cs + row * 136 + cc * 8);
        *(bf16x8*)(C + (size_t)(m0 + pass * 64 + row) * N + n0 + cc * 8) = v;
      }
    } else {
      // transposed: output row = b*1024 + (n0 + e_loc), cols = s
      const int e_loc = tid >> 1, sh = (tid & 1) * 32;
      __bf16* dst = vtb + (size_t)(b * 1024 + n0 + e_loc) * S_ + s0 + pass * 64 + sh;
#pragma unroll
      for (int p2 = 0; p2 < 4; ++p2) {
        bf16x8 v;
#pragma unroll
        for (int j = 0; j < 8; ++j)
          v[j] = cs[(sh + p2 * 8 + j) * 136 + e_loc];
        *(bf16x8*)(dst + p2 * 8) = v;
      }
    }
  }
}

__global__ __launch_bounds__(256) void o_gemm(const __bf16* __restrict__ cb,
                                              const __bf16* __restrict__ wo,
                                              float* __restrict__ out) {
  gemm97_body<float>(cb, wo, out, blockIdx.y * 128, blockIdx.x * 128, D_, D_);
}

// ---------------- flash attention, S^T form, in-register P, T14 pipeline ----------
// Block: 128 q-rows of one (b,h); 8 waves x 16 q. KV tile = 128 keys.
// S^T = K·Q^T (A=K rows from LDS, B=Q in registers): lane holds P[q=l15][32 keys].
// P->bf16 A-fragments via v_cvt_pk_bf16_f32 + permlane32/16_swap (no ps LDS).
// Row-sum l via ones-vector MFMA (lands directly in C/D row layout).
// Defer-max rescale (THR=8 in exp2 domain -> P<=256). V pre-transposed, vt[hd][key].
// T14: issue tile t+1 global loads before computing tile t; ds_write into the
// alternate buffer after the post-compute barrier (double-buffered K/V).
__global__ __launch_bounds__(512, 4) void attn2(const __bf16* __restrict__ Q,
                                                const __bf16* __restrict__ K,
                                                const __bf16* __restrict__ Vt,
                                                const float* __restrict__ mask,
                                                __bf16* __restrict__ O) {
  constexpr int LKT = 72, LVT = 136;
  __shared__ __align__(16) __bf16 kt[2][128 * LKT];   // 2 x 18432 B
  __shared__ __align__(16) __bf16 vt[2][64 * LVT];    // 2 x 17408 B
  __shared__ __align__(16) float  mfull[S_];          // 8192 B (pre-scaled by log2e)

  const int tid  = threadIdx.x, lane = tid & 63, wave = tid >> 6;
  const int l15  = lane & 15,   quad = lane >> 4;
  const int b = blockIdx.z, h = blockIdx.y, q0 = blockIdx.x * 128;
  const size_t base   = (size_t)b * S_ * D_ + h * HD_;
  const size_t vtbase = (size_t)(b * H_ + h) * HD_ * S_;
  const int qw = q0 + wave * 16;
  constexpr float LOG2E = 1.44269504088896340736f;
  constexpr float SC    = 0.125f * LOG2E;          // 1/sqrt(HD) * log2(e)
  constexpr int  NT     = S_ / 128;

  // per-thread staging slots (2 x 16B each for K and V tiles)
  const int idx0 = tid,        kr0 = idx0 >> 3, kc0 = (idx0 & 7) * 8;
  const int idx1 = 512 + tid,  kr1 = idx1 >> 3, kc1 = (idx1 & 7) * 8;
  const int vr0 = idx0 >> 4, vc0 = (idx0 & 15) * 8;
  const int vr1 = idx1 >> 4, vc1 = (idx1 & 15) * 8;

  // Q fragments (B-operand: n=l15 -> q row, k = kb*32+quad*8+j)
  bf16x8 qf[2];
#pragma unroll
  for (int kb = 0; kb < 2; ++kb)
    qf[kb] = *(const bf16x8*)(Q + base + (size_t)(qw + l15) * D_ + kb * 32 + quad * 8);

  bf16x8 ones;
#pragma unroll
  for (int j = 0; j < 8; ++j) ones[j] = (__bf16)1.0f;

  float m_run = -1e30f;
  f32x4 oacc[4] = {};
  f32x4 lacc   = {};

  // prologue: mask table + stage tile 0 into buf 0
  bf16x8 rk0, rk1, rv0, rv1;
  rk0 = *(const bf16x8*)(K + base + (size_t)kr0 * D_ + kc0);
  rk1 = *(const bf16x8*)(K + base + (size_t)kr1 * D_ + kc1);
  rv0 = *(const bf16x8*)(Vt + vtbase + (size_t)vr0 * S_ + vc0);
  rv1 = *(const bf16x8*)(Vt + vtbase + (size_t)vr1 * S_ + vc1);
#pragma unroll
  for (int i = 0; i < S_ / 512; ++i)
    mfull[i * 512 + tid] = mask[(size_t)b * S_ + i * 512 + tid] * LOG2E;
  *(bf16x8*)(&kt[0][kr0 * LKT + kc0]) = rk0;
  *(bf16x8*)(&kt[0][kr1 * LKT + kc1]) = rk1;
  *(bf16x8*)(&vt[0][vr0 * LVT + vc0]) = rv0;
  *(bf16x8*)(&vt[0][vr1 * LVT + vc1]) = rv1;
  __syncthreads();

  for (int t = 0; t < NT; ++t) {
    const int cur = t & 1;
    const int t0  = t * 128;
    const __bf16* ktb = &kt[cur][0];
    const __bf16* vtb = &vt[cur][0];

    // T14: issue next tile's global loads now; latency hides under compute
    if (t + 1 < NT) {
      const int tn = t0 + 128;
      rk0 = *(const bf16x8*)(K + base + (size_t)(tn + kr0) * D_ + kc0);
      rk1 = *(const bf16x8*)(K + base + (size_t)(tn + kr1) * D_ + kc1);
      rv0 = *(const bf16x8*)(Vt + vtbase + (size_t)vr0 * S_ + tn + vc0);
      rv1 = *(const bf16x8*)(Vt + vtbase + (size_t)vr1 * S_ + tn + vc1);
    }

    // S^T tile: D[m=key][n=q]; lane (l15,quad): key = kti*16+quad*4+r, q = l15
    f32x4 sacc[8] = {};
    __builtin_amdgcn_s_setprio(1);
#pragma unroll
    for (int kti = 0; kti < 8; ++kti) {
      const __bf16* kr = ktb + (kti * 16 + l15) * LKT + quad * 8;
      const bf16x8 a0 = *(const bf16x8*)(kr);
      const bf16x8 a1 = *(const bf16x8*)(kr + 32);
      sacc[kti] = __builtin_amdgcn_mfma_f32_16x16x32_bf16(a0, qf[0], sacc[kti], 0, 0, 0);
      sacc[kti] = __builtin_amdgcn_mfma_f32_16x16x32_bf16(a1, qf[1], sacc[kti], 0, 0, 0);
    }
    __builtin_amdgcn_s_setprio(0);

    // scale (exp2 domain) + mask, running max with 4 independent chains
    f32x4 tm4;
#pragma unroll
    for (int r = 0; r < 4; ++r) tm4[r] = -1e30f;
#pragma unroll
    for (int kti = 0; kti < 8; ++kti) {
      const f32x4 mv = *(const f32x4*)(mfull + t0 + kti * 16 + quad * 4);
#pragma unroll
      for (int r = 0; r < 4; ++r) {
        sacc[kti][r] = sacc[kti][r] * SC + mv[r];
        tm4[r] = fmaxf(tm4[r], sacc[kti][r]);
      }
    }
    float tm = fmaxf(fmaxf(tm4[0], tm4[1]), fmaxf(tm4[2], tm4[3]));
    tm = fmaxf(tm, __shfl_xor(tm, 16));
    tm = fmaxf(tm, __shfl_xor(tm, 32));

    // defer-max (T13): only rescale when tile max grows past THR=8 (p <= 2^8)
    if (!__all(tm <= m_run + 8.f)) {
      const float mnew  = fmaxf(m_run, tm);
      const float alpha = __builtin_amdgcn_exp2f(m_run - mnew);
      m_run = mnew;
#pragma unroll
      for (int r = 0; r < 4; ++r) {
        const float aR = __shfl(alpha, quad * 4 + r);
        lacc[r] *= aR;
#pragma unroll
        for (int nt = 0; nt < 4; ++nt) oacc[nt][r] *= aR;
      }
    }

    // exp2 + pack + permlane-redistribute + PV + row-sum, per kb (32 keys each)
#pragma unroll
    for (int kb = 0; kb < 4; ++kb) {
      unsigned dd[2][2];
#pragma unroll
      for (int kk = 0; kk < 2; ++kk) {
        const int kti = 2 * kb + kk;
        float p[4];
#pragma unroll
        for (int r = 0; r < 4; ++r)
          p[r] = __builtin_amdgcn_exp2f(sacc[kti][r] - m_run);
        dd[kk][0] = cvt_pk_bf16(p[0], p[1]);
        dd[kk][1] = cvt_pk_bf16(p[2], p[3]);
      }
      // quad shuffle: rows [A0,A1,A2,A3],[B0,B1,B2,B3] -> [A0,A2,B0,B2],[A1,A3,B1,B3]
      unsigned a0 = dd[0][0], b0 = dd[1][0], a1 = dd[0][1], b1 = dd[1][1];
      asm("v_permlane32_swap_b32 %0, %1" : "+v"(a0), "+v"(b0));
      asm("v_permlane16_swap_b32 %0, %1" : "+v"(a0), "+v"(b0));
      asm("v_permlane32_swap_b32 %0, %1" : "+v"(a1), "+v"(b1));
      asm("v_permlane16_swap_b32 %0, %1" : "+v"(a1), "+v"(b1));
      union { unsigned u[4]; bf16x8 v; } pw;
      pw.u[0] = a0; pw.u[1] = a1; pw.u[2] = b0; pw.u[3] = b1;
      const bf16x8 pa = pw.v;  // A[q=l15][key = kb*32 + quad*8 + j]
      __builtin_amdgcn_s_setprio(1);
      lacc = __builtin_amdgcn_mfma_f32_16x16x32_bf16(pa, ones, lacc, 0, 0, 0);
#pragma unroll
      for (int nt = 0; nt < 4; ++nt) {
        const bf16x8 vf = *(const bf16x8*)(vtb + (nt * 16 + l15) * LVT + kb * 32 + quad * 8);
        oacc[nt] = __builtin_amdgcn_mfma_f32_16x16x32_bf16(pa, vf, oacc[nt], 0, 0, 0);
      }
      __builtin_amdgcn_s_setprio(0);
    }

    __syncthreads();  // barrier A: all waves done reading buf[cur^1] (iter t-1)
    if (t + 1 < NT) {
      const int nxt = cur ^ 1;
      *(bf16x8*)(&kt[nxt][kr0 * LKT + kc0]) = rk0;
      *(bf16x8*)(&kt[nxt][kr1 * LKT + kc1]) = rk1;
      *(bf16x8*)(&vt[nxt][vr0 * LVT + vc0]) = rv0;
      *(bf16x8*)(&vt[nxt][vr1 * LVT + vc1]) = rv1;
    }
    __syncthreads();  // barrier B: buf[cur^1] ready for next iter
  }

  // epilogue: divide by l (already in row layout via ones-MFMA), store ctx
#pragma unroll
  for (int r = 0; r < 4; ++r) {
    const float inv = 1.0f / lacc[r];
    const int row = qw + quad * 4 + r;
#pragma unroll
    for (int nt = 0; nt < 4; ++nt)
      O[base + (size_t)row * D_ + nt * 16 + l15] = (__bf16)(oacc[nt][r] * inv);
  }
}

extern "C" void kernel_launch(void* const* d_in, const int* in_sizes, int n_in,
                              void* d_out, int out_size, void* d_ws, size_t ws_size,
                              hipStream_t stream) {
  const float* x    = (const float*)d_in[0];
  const float* mask = (const float*)d_in[1];
  const float* Wq   = (const float*)d_in[2];
  const float* Wk   = (const float*)d_in[3];
  const float* Wv   = (const float*)d_in[4];
  const float* Wo   = (const float*)d_in[5];

  char* ws = (char*)d_ws;
  const size_t MB = 1ull << 20;
  const size_t NT = (size_t)B_ * S_ * D_;  // 4M elems, 8 MB bf16
  __bf16* xb  = (__bf16*)(ws);             // 8 MB; freed after qkv_gemm -> reused as cb
  __bf16* wqb = (__bf16*)(ws + 8 * MB);
  __bf16* wkb = (__bf16*)(ws + 10 * MB);
  __bf16* wvb = (__bf16*)(ws + 12 * MB);
  __bf16* wob = (__bf16*)(ws + 14 * MB);
  __bf16* qkv = (__bf16*)(ws + 16 * MB);   // 24 MB: Q, K, Vt
  __bf16* qb  = qkv;
  __bf16* kb  = qkv + NT;
  __bf16* vtb = qkv + 2 * NT;  // qkv_gemm sel==2 writes V pre-transposed here
  __bf16* cb  = xb;            // x consumed by qkv_gemm before attn writes ctx

  cvt_all<<<dim3(1024, 5), 256, 0, stream>>>(x, Wq, Wk, Wv, Wo, xb, wqb, wkb, wvb, wob);
  qkv_gemm<<<dim3(24, 32), 256, 0, stream>>>(xb, wqb, wkb, wvb, qkv);
  attn2<<<dim3(S_ / 128, H_, B_), 512, 0, stream>>>(qb, kb, vtb, mask, cb);
  o_gemm<<<dim3(8, 32), 256, 0, stream>>>(cb, wob, (float*)d_out);
}

// Round 4
// 214.165 us; speedup vs baseline: 1.0852x; 1.0038x over previous
//
#include <hip/hip_runtime.h>
#include <hip/hip_bf16.h>
#include <cstdint>
#include <cstddef>

// MHA B=2,S=2048,D=1024,H=16,HD=64.
// cvt(fp32->bf16) -> fused QKV GEMM (m97 global_load_lds, LDS-bounced vector
// epilogue; V written pre-transposed) ->
// flash attn (S^T form, 128q x 128k tiles, 4 waves x 32q so each kt/vt LDS read
// feeds 2 MFMAs; in-register P via cvt_pk + permlane swaps, exp2-domain softmax,
// defer-max, T14 async-stage + double-buffered K/V, row-sum via ones-MFMA) ->
// O GEMM (64x128 tiles, 512 blocks = 2/CU for barrier-drain overlap).

#define B_  2
#define S_  2048
#define D_  1024
#define H_  16
#define HD_ 64

typedef __bf16 bf16x8 __attribute__((ext_vector_type(8)));
typedef __bf16 bf16x4 __attribute__((ext_vector_type(4)));
typedef float  f32x4  __attribute__((ext_vector_type(4)));

// ---- async global->LDS, 16B per lane. LDS dest must be wave-uniform base;
// HW adds lane*16 (guide §5 m97/m104). AS(3) ptr = low 32 bits of flat addr.
__device__ __forceinline__ void async16(const __bf16* g, const __bf16* l) {
  __builtin_amdgcn_global_load_lds(
      (const __attribute__((address_space(1))) void*)(uintptr_t)g,
      (__attribute__((address_space(3))) void*)(uint32_t)(uintptr_t)l,
      16, 0, 0);
}

// v_cvt_pk_bf16_f32: dst.lo16 = bf16(lo), dst.hi16 = bf16(hi)
__device__ __forceinline__ unsigned cvt_pk_bf16(float lo, float hi) {
  unsigned r;
  asm("v_cvt_pk_bf16_f32 %0, %1, %2" : "=v"(r) : "v"(lo), "v"(hi));
  return r;
}

// ---------------- fp32 -> bf16 convert (x + 4 weights) ----------------
__global__ __launch_bounds__(256) void cvt_all(const float* __restrict__ x,
    const float* __restrict__ wq, const float* __restrict__ wk,
    const float* __restrict__ wv, const float* __restrict__ wo,
    __bf16* __restrict__ xb, __bf16* __restrict__ wqb, __bf16* __restrict__ wkb,
    __bf16* __restrict__ wvb, __bf16* __restrict__ wob) {
  const int sel = blockIdx.y;
  const float* src; __bf16* dst; int n;
  if      (sel == 0) { src = x;  dst = xb;  n = B_ * S_ * D_; }
  else if (sel == 1) { src = wq; dst = wqb; n = D_ * D_; }
  else if (sel == 2) { src = wk; dst = wkb; n = D_ * D_; }
  else if (sel == 3) { src = wv; dst = wvb; n = D_ * D_; }
  else               { src = wo; dst = wob; n = D_ * D_; }
  for (int i = blockIdx.x * 256 + threadIdx.x; i * 4 < n; i += gridDim.x * 256) {
    const float4 v = *(const float4*)(src + (size_t)i * 4);
    bf16x4 o;
    o[0] = (__bf16)v.x; o[1] = (__bf16)v.y; o[2] = (__bf16)v.z; o[3] = (__bf16)v.w;
    *(bf16x4*)(dst + (size_t)i * 4) = o;
  }
}

// ---------------- fused QKV GEMM with LDS-bounced epilogue ----------------
// sel 0/1 (Q,K): vectorized bf16x8 row-major stores.
// sel 2   (V) : transposed store direct to Vt[b*1024 + e][s].
__global__ __launch_bounds__(256) void qkv_gemm(const __bf16* __restrict__ xb,
                                                const __bf16* __restrict__ wq,
                                                const __bf16* __restrict__ wk,
                                                const __bf16* __restrict__ wv,
                                                __bf16* __restrict__ qkv) {
  __shared__ __align__(16) __bf16 As[128 * 64];
  __shared__ __align__(16) __bf16 Bs[128 * 64];
  __shared__ __align__(16) __bf16 cs[64 * 136];   // epilogue bounce (one 64-row pass)
  const int sel = blockIdx.x >> 3;  // 0..2 -> Q,K,V
  const __bf16* Bm = (sel == 0) ? wq : (sel == 1) ? wk : wv;
  const int m0 = blockIdx.y * 128, n0 = (blockIdx.x & 7) * 128;
  constexpr int K = D_, N = D_;
  constexpr size_t NTE = (size_t)B_ * S_ * D_;

  const int tid  = threadIdx.x, lane = tid & 63, wave = tid >> 6;
  const int l15  = lane & 15,   quad = lane >> 4;
  const int wr   = wave >> 1,   wc   = wave & 1;
  const int ebase = wave * 2048 + lane * 8;

  f32x4 acc[4][4] = {};
  for (int k0 = 0; k0 < K; k0 += 64) {
#pragma unroll
    for (int i = 0; i < 4; ++i) {
      const int e = ebase + i * 512;
      const int row = e >> 6, col = e & 63;
      async16(xb + (size_t)(m0 + row) * K + k0 + col, As + (wave * 4 + i) * 512);
      async16(Bm + (size_t)(n0 + row) * K + k0 + col, Bs + (wave * 4 + i) * 512);
    }
    __syncthreads();
#pragma unroll
    for (int kk = 0; kk < 2; ++kk) {
      bf16x8 af[4], bfv[4];
#pragma unroll
      for (int rt = 0; rt < 4; ++rt)
        af[rt] = *(const bf16x8*)(As + (wr * 64 + rt * 16 + l15) * 64 + kk * 32 + quad * 8);
#pragma unroll
      for (int ct = 0; ct < 4; ++ct)
        bfv[ct] = *(const bf16x8*)(Bs + (wc * 64 + ct * 16 + l15) * 64 + kk * 32 + quad * 8);
#pragma unroll
      for (int rt = 0; rt < 4; ++rt)
#pragma unroll
        for (int ct = 0; ct < 4; ++ct)
          acc[rt][ct] = __builtin_amdgcn_mfma_f32_16x16x32_bf16(af[rt], bfv[ct], acc[rt][ct], 0, 0, 0);
    }
    __syncthreads();
  }

  // epilogue: two 64-row passes through cs
  const int b  = m0 >> 11;       // batch (S_=2048 rows per batch)
  const int s0 = m0 & (S_ - 1);
  __bf16* vtb = qkv + 2 * NTE;   // Vt lives in the old V slot
#pragma unroll
  for (int pass = 0; pass < 2; ++pass) {
    __syncthreads();  // prior pass's readers (or main-loop) done
    if (wr == pass) {
#pragma unroll
      for (int rt = 0; rt < 4; ++rt)
#pragma unroll
        for (int ct = 0; ct < 4; ++ct)
#pragma unroll
          for (int r = 0; r < 4; ++r)
            cs[(rt * 16 + quad * 4 + r) * 136 + wc * 64 + ct * 16 + l15] =
                (__bf16)acc[rt][ct][r];
    }
    __syncthreads();
    if (sel < 2) {
      __bf16* C = qkv + (size_t)sel * NTE;
      const int cc = tid & 15, rr = tid >> 4;
#pragma unroll
      for (int p2 = 0; p2 < 4; ++p2) {
        const int row = p2 * 16 + rr;
        const bf16x8 v = *(const bf16x8*)(cs + row * 136 + cc * 8);
        *(bf16x8*)(C + (size_t)(m0 + pass * 64 + row) * N + n0 + cc * 8) = v;
      }
    } else {
      // transposed: output row = b*1024 + (n0 + e_loc), cols = s
      const int e_loc = tid >> 1, sh = (tid & 1) * 32;
      __bf16* dst = vtb + (size_t)(b * 1024 + n0 + e_loc) * S_ + s0 + pass * 64 + sh;
#pragma unroll
      for (int p2 = 0; p2 < 4; ++p2) {
        bf16x8 v;
#pragma unroll
        for (int j = 0; j < 8; ++j)
          v[j] = cs[(sh + p2 * 8 + j) * 136 + e_loc];
        *(bf16x8*)(dst + p2 * 8) = v;
      }
    }
  }
}

// ---------------- O GEMM: 64x128 tiles -> 512 blocks = 2/CU ----------------
__global__ __launch_bounds__(256) void o_gemm(const __bf16* __restrict__ cb,
                                              const __bf16* __restrict__ wo,
                                              float* __restrict__ out) {
  __shared__ __align__(16) __bf16 As[64 * 64];
  __shared__ __align__(16) __bf16 Bs[128 * 64];
  const int m0 = blockIdx.y * 64, n0 = blockIdx.x * 128;
  constexpr int K = D_, N = D_;
  const int tid  = threadIdx.x, lane = tid & 63, wave = tid >> 6;
  const int l15  = lane & 15,   quad = lane >> 4;
  const int wr   = wave >> 1,   wc   = wave & 1;

  f32x4 acc[2][4] = {};
  for (int k0 = 0; k0 < K; k0 += 64) {
#pragma unroll
    for (int i = 0; i < 2; ++i) {
      const int e = i * 2048 + wave * 512 + (lane & 63) * 8;
      const int row = e >> 6, col = e & 63;
      async16(cb + (size_t)(m0 + row) * K + k0 + col, As + i * 2048 + wave * 512);
    }
#pragma unroll
    for (int j = 0; j < 4; ++j) {
      const int e = j * 2048 + wave * 512 + (lane & 63) * 8;
      const int row = e >> 6, col = e & 63;
      async16(wo + (size_t)(n0 + row) * K + k0 + col, Bs + j * 2048 + wave * 512);
    }
    __syncthreads();
#pragma unroll
    for (int kk = 0; kk < 2; ++kk) {
      bf16x8 af[2], bfv[4];
#pragma unroll
      for (int rt = 0; rt < 2; ++rt)
        af[rt] = *(const bf16x8*)(As + (wr * 32 + rt * 16 + l15) * 64 + kk * 32 + quad * 8);
#pragma unroll
      for (int ct = 0; ct < 4; ++ct)
        bfv[ct] = *(const bf16x8*)(Bs + (wc * 64 + ct * 16 + l15) * 64 + kk * 32 + quad * 8);
#pragma unroll
      for (int rt = 0; rt < 2; ++rt)
#pragma unroll
        for (int ct = 0; ct < 4; ++ct)
          acc[rt][ct] = __builtin_amdgcn_mfma_f32_16x16x32_bf16(af[rt], bfv[ct], acc[rt][ct], 0, 0, 0);
    }
    __syncthreads();
  }
#pragma unroll
  for (int rt = 0; rt < 2; ++rt)
#pragma unroll
    for (int ct = 0; ct < 4; ++ct)
#pragma unroll
      for (int r = 0; r < 4; ++r) {
        const int row = m0 + wr * 32 + rt * 16 + quad * 4 + r;
        const int col = n0 + wc * 64 + ct * 16 + l15;
        out[(size_t)row * N + col] = acc[rt][ct][r];
      }
}

// ---------------- flash attention, S^T form, in-register P, 4 waves x 32q ----------
// Block: 128 q-rows of one (b,h); 4 waves x 32 q. KV tile = 128 keys.
// Each kt/vt LDS read feeds 2 MFMAs (t=0,1 q-halves) -> per-q LDS traffic halved
// vs 8wx16q (LDS pipe was the bottleneck: ~42 instr x 12cyc vs 602cyc/wave-tile).
// S^T = K·Q^T: lane holds P[q=l15(+16t)][32 keys]; in-register P via cvt_pk +
// permlane32/16_swap; row-sum l via ones-MFMA; defer-max (THR=8, exp2 domain);
// T14 reg-prefetch + double-buffered K/V.
__global__ __launch_bounds__(256, 2) void attn2(const __bf16* __restrict__ Q,
                                                const __bf16* __restrict__ K,
                                                const __bf16* __restrict__ Vt,
                                                const float* __restrict__ mask,
                                                __bf16* __restrict__ O) {
  constexpr int LKT = 72, LVT = 136;
  __shared__ __align__(16) __bf16 kt[2][128 * LKT];   // 2 x 18432 B
  __shared__ __align__(16) __bf16 vt[2][64 * LVT];    // 2 x 17408 B
  __shared__ __align__(16) float  mfull[S_];          // 8192 B (pre-scaled by log2e)

  const int tid  = threadIdx.x, lane = tid & 63, wave = tid >> 6;
  const int l15  = lane & 15,   quad = lane >> 4;
  const int b = blockIdx.z, h = blockIdx.y, q0 = blockIdx.x * 128;
  const size_t base   = (size_t)b * S_ * D_ + h * HD_;
  const size_t vtbase = (size_t)(b * H_ + h) * HD_ * S_;
  const int qw = q0 + wave * 32;
  constexpr float LOG2E = 1.44269504088896340736f;
  constexpr float SC    = 0.125f * LOG2E;          // 1/sqrt(HD) * log2(e)
  constexpr int  NT     = S_ / 128;

  // per-thread staging slots (4 x 16B each for K and V tiles; 256 threads)
  int kr[4], kc[4], vr[4], vc[4];
#pragma unroll
  for (int i = 0; i < 4; ++i) {
    const int idx = i * 256 + tid;
    kr[i] = idx >> 3;  kc[i] = (idx & 7) * 8;
    vr[i] = idx >> 4;  vc[i] = (idx & 15) * 8;
  }

  // Q fragments (B-operand: n=l15 -> q row qw + t*16 + l15, k = kb*32+quad*8+j)
  bf16x8 qf[2][2];
#pragma unroll
  for (int t = 0; t < 2; ++t)
#pragma unroll
    for (int kb = 0; kb < 2; ++kb)
      qf[t][kb] = *(const bf16x8*)(Q + base + (size_t)(qw + t * 16 + l15) * D_ + kb * 32 + quad * 8);

  bf16x8 ones;
#pragma unroll
  for (int j = 0; j < 8; ++j) ones[j] = (__bf16)1.0f;

  float m_run[2] = {-1e30f, -1e30f};
  f32x4 oacc[2][4] = {};
  f32x4 lacc[2]    = {};

  // prologue: mask table + stage tile 0 into buf 0
  bf16x8 rk[4], rv[4];
#pragma unroll
  for (int i = 0; i < 4; ++i) {
    rk[i] = *(const bf16x8*)(K + base + (size_t)kr[i] * D_ + kc[i]);
    rv[i] = *(const bf16x8*)(Vt + vtbase + (size_t)vr[i] * S_ + vc[i]);
  }
#pragma unroll
  for (int i = 0; i < S_ / 256; ++i)
    mfull[i * 256 + tid] = mask[(size_t)b * S_ + i * 256 + tid] * LOG2E;
#pragma unroll
  for (int i = 0; i < 4; ++i) {
    *(bf16x8*)(&kt[0][kr[i] * LKT + kc[i]]) = rk[i];
    *(bf16x8*)(&vt[0][vr[i] * LVT + vc[i]]) = rv[i];
  }
  __syncthreads();

  for (int t = 0; t < NT; ++t) {
    const int cur = t & 1;
    const int t0  = t * 128;
    const __bf16* ktb = &kt[cur][0];
    const __bf16* vtb = &vt[cur][0];

    // T14: issue next tile's global loads now; latency hides under compute
    if (t + 1 < NT) {
      const int tn = t0 + 128;
#pragma unroll
      for (int i = 0; i < 4; ++i) {
        rk[i] = *(const bf16x8*)(K + base + (size_t)(tn + kr[i]) * D_ + kc[i]);
        rv[i] = *(const bf16x8*)(Vt + vtbase + (size_t)vr[i] * S_ + tn + vc[i]);
      }
    }

    // S^T tile: D[m=key][n=q]; lane (l15,quad): key = kti*16+quad*4+r, q-col l15
    f32x4 sacc[8][2] = {};
    __builtin_amdgcn_s_setprio(1);
#pragma unroll
    for (int kti = 0; kti < 8; ++kti) {
      const __bf16* krp = ktb + (kti * 16 + l15) * LKT + quad * 8;
      const bf16x8 a0 = *(const bf16x8*)(krp);
      const bf16x8 a1 = *(const bf16x8*)(krp + 32);
#pragma unroll
      for (int tt = 0; tt < 2; ++tt) {
        sacc[kti][tt] = __builtin_amdgcn_mfma_f32_16x16x32_bf16(a0, qf[tt][0], sacc[kti][tt], 0, 0, 0);
        sacc[kti][tt] = __builtin_amdgcn_mfma_f32_16x16x32_bf16(a1, qf[tt][1], sacc[kti][tt], 0, 0, 0);
      }
    }
    __builtin_amdgcn_s_setprio(0);

    // scale (exp2 domain) + mask, running max (mask read shared across t-halves)
    f32x4 tm4[2];
#pragma unroll
    for (int tt = 0; tt < 2; ++tt)
#pragma unroll
      for (int r = 0; r < 4; ++r) tm4[tt][r] = -1e30f;
#pragma unroll
    for (int kti = 0; kti < 8; ++kti) {
      const f32x4 mv = *(const f32x4*)(mfull + t0 + kti * 16 + quad * 4);
#pragma unroll
      for (int tt = 0; tt < 2; ++tt)
#pragma unroll
        for (int r = 0; r < 4; ++r) {
          sacc[kti][tt][r] = sacc[kti][tt][r] * SC + mv[r];
          tm4[tt][r] = fmaxf(tm4[tt][r], sacc[kti][tt][r]);
        }
    }
#pragma unroll
    for (int tt = 0; tt < 2; ++tt) {
      float tm = fmaxf(fmaxf(tm4[tt][0], tm4[tt][1]), fmaxf(tm4[tt][2], tm4[tt][3]));
      tm = fmaxf(tm, __shfl_xor(tm, 16));
      tm = fmaxf(tm, __shfl_xor(tm, 32));
      // defer-max (T13): only rescale when tile max grows past THR=8 (p <= 2^8)
      if (!__all(tm <= m_run[tt] + 8.f)) {
        const float mnew  = fmaxf(m_run[tt], tm);
        const float alpha = __builtin_amdgcn_exp2f(m_run[tt] - mnew);
        m_run[tt] = mnew;
#pragma unroll
        for (int r = 0; r < 4; ++r) {
          const float aR = __shfl(alpha, quad * 4 + r);
          lacc[tt][r] *= aR;
#pragma unroll
          for (int nt = 0; nt < 4; ++nt) oacc[tt][nt][r] *= aR;
        }
      }
    }

    // exp2 + pack + permlane-redistribute + PV + row-sum, per kb (32 keys each);
    // vt read shared across both t-halves.
#pragma unroll
    for (int kb = 0; kb < 4; ++kb) {
      bf16x8 pa[2];
#pragma unroll
      for (int tt = 0; tt < 2; ++tt) {
        unsigned dd[2][2];
#pragma unroll
        for (int kk = 0; kk < 2; ++kk) {
          const int kti = 2 * kb + kk;
          float p[4];
#pragma unroll
          for (int r = 0; r < 4; ++r)
            p[r] = __builtin_amdgcn_exp2f(sacc[kti][tt][r] - m_run[tt]);
          dd[kk][0] = cvt_pk_bf16(p[0], p[1]);
          dd[kk][1] = cvt_pk_bf16(p[2], p[3]);
        }
        // rows [A0,A1,A2,A3],[B0,B1,B2,B3] -> [A0,A2,B0,B2],[A1,A3,B1,B3]
        unsigned a0 = dd[0][0], b0 = dd[1][0], a1 = dd[0][1], b1 = dd[1][1];
        asm("v_permlane32_swap_b32 %0, %1" : "+v"(a0), "+v"(b0));
        asm("v_permlane16_swap_b32 %0, %1" : "+v"(a0), "+v"(b0));
        asm("v_permlane32_swap_b32 %0, %1" : "+v"(a1), "+v"(b1));
        asm("v_permlane16_swap_b32 %0, %1" : "+v"(a1), "+v"(b1));
        union { unsigned u[4]; bf16x8 v; } pw;
        pw.u[0] = a0; pw.u[1] = a1; pw.u[2] = b0; pw.u[3] = b1;
        pa[tt] = pw.v;  // A[q=l15]{t-half}[key = kb*32 + quad*8 + j]
      }
      __builtin_amdgcn_s_setprio(1);
#pragma unroll
      for (int tt = 0; tt < 2; ++tt)
        lacc[tt] = __builtin_amdgcn_mfma_f32_16x16x32_bf16(pa[tt], ones, lacc[tt], 0, 0, 0);
#pragma unroll
      for (int nt = 0; nt < 4; ++nt) {
        const bf16x8 vf = *(const bf16x8*)(vtb + (nt * 16 + l15) * LVT + kb * 32 + quad * 8);
#pragma unroll
        for (int tt = 0; tt < 2; ++tt)
          oacc[tt][nt] = __builtin_amdgcn_mfma_f32_16x16x32_bf16(pa[tt], vf, oacc[tt][nt], 0, 0, 0);
      }
      __builtin_amdgcn_s_setprio(0);
    }

    __syncthreads();  // barrier A: all waves done reading buf[cur]
    if (t + 1 < NT) {
      const int nxt = cur ^ 1;
#pragma unroll
      for (int i = 0; i < 4; ++i) {
        *(bf16x8*)(&kt[nxt][kr[i] * LKT + kc[i]]) = rk[i];
        *(bf16x8*)(&vt[nxt][vr[i] * LVT + vc[i]]) = rv[i];
      }
    }
    __syncthreads();  // barrier B: buf[cur^1] ready for next iter
  }

  // epilogue: divide by l (already in row layout via ones-MFMA), store ctx
#pragma unroll
  for (int tt = 0; tt < 2; ++tt)
#pragma unroll
    for (int r = 0; r < 4; ++r) {
      const float inv = 1.0f / lacc[tt][r];
      const int row = qw + tt * 16 + quad * 4 + r;
#pragma unroll
      for (int nt = 0; nt < 4; ++nt)
        O[base + (size_t)row * D_ + nt * 16 + l15] = (__bf16)(oacc[tt][nt][r] * inv);
    }
}

extern "C" void kernel_launch(void* const* d_in, const int* in_sizes, int n_in,
                              void* d_out, int out_size, void* d_ws, size_t ws_size,
                              hipStream_t stream) {
  const float* x    = (const float*)d_in[0];
  const float* mask = (const float*)d_in[1];
  const float* Wq   = (const float*)d_in[2];
  const float* Wk   = (const float*)d_in[3];
  const float* Wv   = (const float*)d_in[4];
  const float* Wo   = (const float*)d_in[5];

  char* ws = (char*)d_ws;
  const size_t MB = 1ull << 20;
  const size_t NT = (size_t)B_ * S_ * D_;  // 4M elems, 8 MB bf16
  __bf16* xb  = (__bf16*)(ws);             // 8 MB; freed after qkv_gemm -> reused as cb
  __bf16* wqb = (__bf16*)(ws + 8 * MB);
  __bf16* wkb = (__bf16*)(ws + 10 * MB);
  __bf16* wvb = (__bf16*)(ws + 12 * MB);
  __bf16* wob = (__bf16*)(ws + 14 * MB);
  __bf16* qkv = (__bf16*)(ws + 16 * MB);   // 24 MB: Q, K, Vt
  __bf16* qb  = qkv;
  __bf16* kb  = qkv + NT;
  __bf16* vtb = qkv + 2 * NT;  // qkv_gemm sel==2 writes V pre-transposed here
  __bf16* cb  = xb;            // x consumed by qkv_gemm before attn writes ctx

  cvt_all<<<dim3(1024, 5), 256, 0, stream>>>(x, Wq, Wk, Wv, Wo, xb, wqb, wkb, wvb, wob);
  qkv_gemm<<<dim3(24, 32), 256, 0, stream>>>(xb, wqb, wkb, wvb, qkv);
  attn2<<<dim3(S_ / 128, H_, B_), 256, 0, stream>>>(qb, kb, vtb, mask, cb);
  o_gemm<<<dim3(8, 64), 256, 0, stream>>>(cb, wob, (float*)d_out);
}

// Round 5
// 210.335 us; speedup vs baseline: 1.1049x; 1.0182x over previous
//
#include <hip/hip_runtime.h>
#include <hip/hip_bf16.h>
#include <cstdint>
#include <cstddef>

// MHA B=2,S=2048,D=1024,H=16,HD=64.
// cvt(fp32->bf16) -> fused QKV GEMM (packed [3072][1024] weights, m97
// global_load_lds, LDS-aliased vector epilogue, XCD 2D swizzle; V written
// pre-transposed) -> flash attn (S^T form, 128q x 128k tiles, 8 waves x 16q,
// in-register P via cvt_pk + permlane swaps, exp2-domain softmax, defer-max,
// T14 async-stage + double-buffered K/V, row-sum via ones-MFMA, XCD head
// clustering) -> O GEMM (64x128 tiles, XCD 2D swizzle).

#define B_  2
#define S_  2048
#define D_  1024
#define H_  16
#define HD_ 64

typedef __bf16 bf16x8 __attribute__((ext_vector_type(8)));
typedef __bf16 bf16x4 __attribute__((ext_vector_type(4)));
typedef float  f32x4  __attribute__((ext_vector_type(4)));

// ---- async global->LDS, 16B per lane. LDS dest must be wave-uniform base;
// HW adds lane*16 (guide §5 m97/m104). AS(3) ptr = low 32 bits of flat addr.
__device__ __forceinline__ void async16(const __bf16* g, const __bf16* l) {
  __builtin_amdgcn_global_load_lds(
      (const __attribute__((address_space(1))) void*)(uintptr_t)g,
      (__attribute__((address_space(3))) void*)(uint32_t)(uintptr_t)l,
      16, 0, 0);
}

// v_cvt_pk_bf16_f32: dst.lo16 = bf16(lo), dst.hi16 = bf16(hi)
__device__ __forceinline__ unsigned cvt_pk_bf16(float lo, float hi) {
  unsigned r;
  asm("v_cvt_pk_bf16_f32 %0, %1, %2" : "=v"(r) : "v"(lo), "v"(hi));
  return r;
}

// ---------------- fp32 -> bf16 convert (x + 4 weights) ----------------
__global__ __launch_bounds__(256) void cvt_all(const float* __restrict__ x,
    const float* __restrict__ wq, const float* __restrict__ wk,
    const float* __restrict__ wv, const float* __restrict__ wo,
    __bf16* __restrict__ xb, __bf16* __restrict__ wqb, __bf16* __restrict__ wkb,
    __bf16* __restrict__ wvb, __bf16* __restrict__ wob) {
  const int sel = blockIdx.y;
  const float* src; __bf16* dst; int n;
  if      (sel == 0) { src = x;  dst = xb;  n = B_ * S_ * D_; }
  else if (sel == 1) { src = wq; dst = wqb; n = D_ * D_; }
  else if (sel == 2) { src = wk; dst = wkb; n = D_ * D_; }
  else if (sel == 3) { src = wv; dst = wvb; n = D_ * D_; }
  else               { src = wo; dst = wob; n = D_ * D_; }
  for (int i = blockIdx.x * 256 + threadIdx.x; i * 4 < n; i += gridDim.x * 256) {
    const float4 v = *(const float4*)(src + (size_t)i * 4);
    bf16x4 o;
    o[0] = (__bf16)v.x; o[1] = (__bf16)v.y; o[2] = (__bf16)v.z; o[3] = (__bf16)v.w;
    *(bf16x4*)(dst + (size_t)i * 4) = o;
  }
}

// ---------------- fused QKV GEMM, packed weights [3072][1024] ----------------
// XCD 2D swizzle: lin%8 = XCD; each XCD owns a 16m x 6n region (panel traffic
// per XCD = 16 A-panels + 6 B-panels, L2-resident). LDS-aliased epilogue:
// cs reuses As/Bs after final K barrier (LDS stays 32768 B -> 4 blocks/CU).
// sel 0/1 (Q,K): vectorized bf16x8 row-major stores.
// sel 2   (V) : transposed store direct to Vt[b*1024 + e][s].
__global__ __launch_bounds__(256) void qkv_gemm(const __bf16* __restrict__ xb,
                                                const __bf16* __restrict__ wqkv,
                                                __bf16* __restrict__ qkv) {
  __shared__ __align__(16) char smem[32768];
  __bf16* As = (__bf16*)smem;            // [128*64]
  __bf16* Bs = (__bf16*)(smem + 16384);  // [128*64]
  __bf16* cs = (__bf16*)smem;            // 64*136 = 17408 B, alias; post-loop only

  const int lin = blockIdx.y * 24 + blockIdx.x;   // 0..767
  const int xcd = lin & 7, slot = lin >> 3;       // slot 0..95
  const int mi = xcd >> 2, ni = xcd & 3;
  const int mB = mi * 16 + slot / 6;              // 0..31
  const int nB = ni * 6  + slot % 6;              // 0..23
  const int m0  = mB * 128;
  const int sel = nB >> 3;                        // 0..2 -> Q,K,V
  const int n0s = (nB & 7) * 128;                 // col offset within sel
  const int n0w = nB * 128;                       // row offset in packed weights
  constexpr int K = D_, N = D_;
  constexpr size_t NTE = (size_t)B_ * S_ * D_;

  const int tid  = threadIdx.x, lane = tid & 63, wave = tid >> 6;
  const int l15  = lane & 15,   quad = lane >> 4;
  const int wr   = wave >> 1,   wc   = wave & 1;
  const int ebase = wave * 2048 + lane * 8;

  f32x4 acc[4][4] = {};
  for (int k0 = 0; k0 < K; k0 += 64) {
#pragma unroll
    for (int i = 0; i < 4; ++i) {
      const int e = ebase + i * 512;
      const int row = e >> 6, col = e & 63;
      async16(xb   + (size_t)(m0  + row) * K + k0 + col, As + (wave * 4 + i) * 512);
      async16(wqkv + (size_t)(n0w + row) * K + k0 + col, Bs + (wave * 4 + i) * 512);
    }
    __syncthreads();
#pragma unroll
    for (int kk = 0; kk < 2; ++kk) {
      bf16x8 af[4], bfv[4];
#pragma unroll
      for (int rt = 0; rt < 4; ++rt)
        af[rt] = *(const bf16x8*)(As + (wr * 64 + rt * 16 + l15) * 64 + kk * 32 + quad * 8);
#pragma unroll
      for (int ct = 0; ct < 4; ++ct)
        bfv[ct] = *(const bf16x8*)(Bs + (wc * 64 + ct * 16 + l15) * 64 + kk * 32 + quad * 8);
#pragma unroll
      for (int rt = 0; rt < 4; ++rt)
#pragma unroll
        for (int ct = 0; ct < 4; ++ct)
          acc[rt][ct] = __builtin_amdgcn_mfma_f32_16x16x32_bf16(af[rt], bfv[ct], acc[rt][ct], 0, 0, 0);
    }
    __syncthreads();
  }

  // epilogue: two 64-row passes through cs (aliases As/Bs; safe after last barrier)
  const int b  = m0 >> 11;       // batch (S_=2048 rows per batch)
  const int s0 = m0 & (S_ - 1);
  __bf16* vtb = qkv + 2 * NTE;   // Vt lives in the V slot
#pragma unroll
  for (int pass = 0; pass < 2; ++pass) {
    __syncthreads();  // prior pass's readers (or main-loop) done
    if (wr == pass) {
#pragma unroll
      for (int rt = 0; rt < 4; ++rt)
#pragma unroll
        for (int ct = 0; ct < 4; ++ct)
#pragma unroll
          for (int r = 0; r < 4; ++r)
            cs[(rt * 16 + quad * 4 + r) * 136 + wc * 64 + ct * 16 + l15] =
                (__bf16)acc[rt][ct][r];
    }
    __syncthreads();
    if (sel < 2) {
      __bf16* C = qkv + (size_t)sel * NTE;
      const int cc = tid & 15, rr = tid >> 4;
#pragma unroll
      for (int p2 = 0; p2 < 4; ++p2) {
        const int row = p2 * 16 + rr;
        const bf16x8 v = *(const bf16x8*)(cs + row * 136 + cc * 8);
        *(bf16x8*)(C + (size_t)(m0 + pass * 64 + row) * N + n0s + cc * 8) = v;
      }
    } else {
      // transposed: output row = b*1024 + (n0s + e_loc), cols = s
      const int e_loc = tid >> 1, sh = (tid & 1) * 32;
      __bf16* dst = vtb + (size_t)(b * 1024 + n0s + e_loc) * S_ + s0 + pass * 64 + sh;
#pragma unroll
      for (int p2 = 0; p2 < 4; ++p2) {
        bf16x8 v;
#pragma unroll
        for (int j = 0; j < 8; ++j)
          v[j] = cs[(sh + p2 * 8 + j) * 136 + e_loc];
        *(bf16x8*)(dst + p2 * 8) = v;
      }
    }
  }
}

// ---------------- O GEMM: 64x128 tiles, XCD 2D swizzle (16m x 4n / XCD) ------
__global__ __launch_bounds__(256) void o_gemm(const __bf16* __restrict__ cb,
                                              const __bf16* __restrict__ wo,
                                              float* __restrict__ out) {
  __shared__ __align__(16) __bf16 As[64 * 64];
  __shared__ __align__(16) __bf16 Bs[128 * 64];
  const int lin = blockIdx.y * 8 + blockIdx.x;   // 0..511
  const int xcd = lin & 7, slot = lin >> 3;      // slot 0..63
  const int mi = xcd >> 1, ni = xcd & 1;
  const int mB = mi * 16 + (slot >> 2);          // 0..63
  const int nB = ni * 4  + (slot & 3);           // 0..7
  const int m0 = mB * 64, n0 = nB * 128;
  constexpr int K = D_, N = D_;
  const int tid  = threadIdx.x, lane = tid & 63, wave = tid >> 6;
  const int l15  = lane & 15,   quad = lane >> 4;
  const int wr   = wave >> 1,   wc   = wave & 1;

  f32x4 acc[2][4] = {};
  for (int k0 = 0; k0 < K; k0 += 64) {
#pragma unroll
    for (int i = 0; i < 2; ++i) {
      const int e = i * 2048 + wave * 512 + (lane & 63) * 8;
      const int row = e >> 6, col = e & 63;
      async16(cb + (size_t)(m0 + row) * K + k0 + col, As + i * 2048 + wave * 512);
    }
#pragma unroll
    for (int j = 0; j < 4; ++j) {
      const int e = j * 2048 + wave * 512 + (lane & 63) * 8;
      const int row = e >> 6, col = e & 63;
      async16(wo + (size_t)(n0 + row) * K + k0 + col, Bs + j * 2048 + wave * 512);
    }
    __syncthreads();
#pragma unroll
    for (int kk = 0; kk < 2; ++kk) {
      bf16x8 af[2], bfv[4];
#pragma unroll
      for (int rt = 0; rt < 2; ++rt)
        af[rt] = *(const bf16x8*)(As + (wr * 32 + rt * 16 + l15) * 64 + kk * 32 + quad * 8);
#pragma unroll
      for (int ct = 0; ct < 4; ++ct)
        bfv[ct] = *(const bf16x8*)(Bs + (wc * 64 + ct * 16 + l15) * 64 + kk * 32 + quad * 8);
#pragma unroll
      for (int rt = 0; rt < 2; ++rt)
#pragma unroll
        for (int ct = 0; ct < 4; ++ct)
          acc[rt][ct] = __builtin_amdgcn_mfma_f32_16x16x32_bf16(af[rt], bfv[ct], acc[rt][ct], 0, 0, 0);
    }
    __syncthreads();
  }
#pragma unroll
  for (int rt = 0; rt < 2; ++rt)
#pragma unroll
    for (int ct = 0; ct < 4; ++ct)
#pragma unroll
      for (int r = 0; r < 4; ++r) {
        const int row = m0 + wr * 32 + rt * 16 + quad * 4 + r;
        const int col = n0 + wc * 64 + ct * 16 + l15;
        out[(size_t)row * N + col] = acc[rt][ct][r];
      }
}

// ---------------- flash attention, S^T form, in-register P, T14 pipeline ----------
// r2 config (best measured: 64.2us): 8 waves x 16 q, KV tile = 128 keys.
// + XCD head clustering: lin%8 = XCD -> each XCD serves 4 heads (2MB K/V in L2).
// S^T = K·Q^T: lane holds P[q=l15][32 keys]; in-register P via cvt_pk +
// permlane32/16_swap; row-sum l via ones-MFMA; defer-max (THR=8, exp2 domain);
// T14 reg-prefetch + double-buffered K/V.
__global__ __launch_bounds__(512, 4) void attn2(const __bf16* __restrict__ Q,
                                                const __bf16* __restrict__ K,
                                                const __bf16* __restrict__ Vt,
                                                const float* __restrict__ mask,
                                                __bf16* __restrict__ O) {
  constexpr int LKT = 72, LVT = 136;
  __shared__ __align__(16) __bf16 kt[2][128 * LKT];   // 2 x 18432 B
  __shared__ __align__(16) __bf16 vt[2][64 * LVT];    // 2 x 17408 B
  __shared__ __align__(16) float  mfull[S_];          // 8192 B (pre-scaled by log2e)

  const int tid  = threadIdx.x, lane = tid & 63, wave = tid >> 6;
  const int l15  = lane & 15,   quad = lane >> 4;
  // XCD-aware remap (bijective, 512 blocks): XCD c gets swz [c*64,(c+1)*64)
  // = one batch, 4 heads, all 16 q-blocks -> K/V panels L2-local.
  const int lin = blockIdx.z * 256 + blockIdx.y * 16 + blockIdx.x;
  const int swz = (lin & 7) * 64 + (lin >> 3);
  const int b = swz >> 8, h = (swz >> 4) & 15, q0 = (swz & 15) * 128;
  const size_t base   = (size_t)b * S_ * D_ + h * HD_;
  const size_t vtbase = (size_t)(b * H_ + h) * HD_ * S_;
  const int qw = q0 + wave * 16;
  constexpr float LOG2E = 1.44269504088896340736f;
  constexpr float SC    = 0.125f * LOG2E;          // 1/sqrt(HD) * log2(e)
  constexpr int  NT     = S_ / 128;

  // per-thread staging slots (2 x 16B each for K and V tiles)
  const int idx0 = tid,        kr0 = idx0 >> 3, kc0 = (idx0 & 7) * 8;
  const int idx1 = 512 + tid,  kr1 = idx1 >> 3, kc1 = (idx1 & 7) * 8;
  const int vr0 = idx0 >> 4, vc0 = (idx0 & 15) * 8;
  const int vr1 = idx1 >> 4, vc1 = (idx1 & 15) * 8;

  // Q fragments (B-operand: n=l15 -> q row, k = kb*32+quad*8+j)
  bf16x8 qf[2];
#pragma unroll
  for (int kb = 0; kb < 2; ++kb)
    qf[kb] = *(const bf16x8*)(Q + base + (size_t)(qw + l15) * D_ + kb * 32 + quad * 8);

  bf16x8 ones;
#pragma unroll
  for (int j = 0; j < 8; ++j) ones[j] = (__bf16)1.0f;

  float m_run = -1e30f;
  f32x4 oacc[4] = {};
  f32x4 lacc   = {};

  // prologue: mask table + stage tile 0 into buf 0
  bf16x8 rk0, rk1, rv0, rv1;
  rk0 = *(const bf16x8*)(K + base + (size_t)kr0 * D_ + kc0);
  rk1 = *(const bf16x8*)(K + base + (size_t)kr1 * D_ + kc1);
  rv0 = *(const bf16x8*)(Vt + vtbase + (size_t)vr0 * S_ + vc0);
  rv1 = *(const bf16x8*)(Vt + vtbase + (size_t)vr1 * S_ + vc1);
#pragma unroll
  for (int i = 0; i < S_ / 512; ++i)
    mfull[i * 512 + tid] = mask[(size_t)b * S_ + i * 512 + tid] * LOG2E;
  *(bf16x8*)(&kt[0][kr0 * LKT + kc0]) = rk0;
  *(bf16x8*)(&kt[0][kr1 * LKT + kc1]) = rk1;
  *(bf16x8*)(&vt[0][vr0 * LVT + vc0]) = rv0;
  *(bf16x8*)(&vt[0][vr1 * LVT + vc1]) = rv1;
  __syncthreads();

  for (int t = 0; t < NT; ++t) {
    const int cur = t & 1;
    const int t0  = t * 128;
    const __bf16* ktb = &kt[cur][0];
    const __bf16* vtb = &vt[cur][0];

    // T14: issue next tile's global loads now; latency hides under compute
    if (t + 1 < NT) {
      const int tn = t0 + 128;
      rk0 = *(const bf16x8*)(K + base + (size_t)(tn + kr0) * D_ + kc0);
      rk1 = *(const bf16x8*)(K + base + (size_t)(tn + kr1) * D_ + kc1);
      rv0 = *(const bf16x8*)(Vt + vtbase + (size_t)vr0 * S_ + tn + vc0);
      rv1 = *(const bf16x8*)(Vt + vtbase + (size_t)vr1 * S_ + tn + vc1);
    }

    // S^T tile: D[m=key][n=q]; lane (l15,quad): key = kti*16+quad*4+r, q = l15
    f32x4 sacc[8] = {};
    __builtin_amdgcn_s_setprio(1);
#pragma unroll
    for (int kti = 0; kti < 8; ++kti) {
      const __bf16* kr = ktb + (kti * 16 + l15) * LKT + quad * 8;
      const bf16x8 a0 = *(const bf16x8*)(kr);
      const bf16x8 a1 = *(const bf16x8*)(kr + 32);
      sacc[kti] = __builtin_amdgcn_mfma_f32_16x16x32_bf16(a0, qf[0], sacc[kti], 0, 0, 0);
      sacc[kti] = __builtin_amdgcn_mfma_f32_16x16x32_bf16(a1, qf[1], sacc[kti], 0, 0, 0);
    }
    __builtin_amdgcn_s_setprio(0);

    // scale (exp2 domain) + mask, running max with 4 independent chains
    f32x4 tm4;
#pragma unroll
    for (int r = 0; r < 4; ++r) tm4[r] = -1e30f;
#pragma unroll
    for (int kti = 0; kti < 8; ++kti) {
      const f32x4 mv = *(const f32x4*)(mfull + t0 + kti * 16 + quad * 4);
#pragma unroll
      for (int r = 0; r < 4; ++r) {
        sacc[kti][r] = sacc[kti][r] * SC + mv[r];
        tm4[r] = fmaxf(tm4[r], sacc[kti][r]);
      }
    }
    float tm = fmaxf(fmaxf(tm4[0], tm4[1]), fmaxf(tm4[2], tm4[3]));
    tm = fmaxf(tm, __shfl_xor(tm, 16));
    tm = fmaxf(tm, __shfl_xor(tm, 32));

    // defer-max (T13): only rescale when tile max grows past THR=8 (p <= 2^8)
    if (!__all(tm <= m_run + 8.f)) {
      const float mnew  = fmaxf(m_run, tm);
      const float alpha = __builtin_amdgcn_exp2f(m_run - mnew);
      m_run = mnew;
#pragma unroll
      for (int r = 0; r < 4; ++r) {
        const float aR = __shfl(alpha, quad * 4 + r);
        lacc[r] *= aR;
#pragma unroll
        for (int nt = 0; nt < 4; ++nt) oacc[nt][r] *= aR;
      }
    }

    // exp2 + pack + permlane-redistribute + PV + row-sum, per kb (32 keys each)
#pragma unroll
    for (int kb = 0; kb < 4; ++kb) {
      unsigned dd[2][2];
#pragma unroll
      for (int kk = 0; kk < 2; ++kk) {
        const int kti = 2 * kb + kk;
        float p[4];
#pragma unroll
        for (int r = 0; r < 4; ++r)
          p[r] = __builtin_amdgcn_exp2f(sacc[kti][r] - m_run);
        dd[kk][0] = cvt_pk_bf16(p[0], p[1]);
        dd[kk][1] = cvt_pk_bf16(p[2], p[3]);
      }
      // quad shuffle: rows [A0,A1,A2,A3],[B0,B1,B2,B3] -> [A0,A2,B0,B2],[A1,A3,B1,B3]
      unsigned a0 = dd[0][0], b0 = dd[1][0], a1 = dd[0][1], b1 = dd[1][1];
      asm("v_permlane32_swap_b32 %0, %1" : "+v"(a0), "+v"(b0));
      asm("v_permlane16_swap_b32 %0, %1" : "+v"(a0), "+v"(b0));
      asm("v_permlane32_swap_b32 %0, %1" : "+v"(a1), "+v"(b1));
      asm("v_permlane16_swap_b32 %0, %1" : "+v"(a1), "+v"(b1));
      union { unsigned u[4]; bf16x8 v; } pw;
      pw.u[0] = a0; pw.u[1] = a1; pw.u[2] = b0; pw.u[3] = b1;
      const bf16x8 pa = pw.v;  // A[q=l15][key = kb*32 + quad*8 + j]
      __builtin_amdgcn_s_setprio(1);
      lacc = __builtin_amdgcn_mfma_f32_16x16x32_bf16(pa, ones, lacc, 0, 0, 0);
#pragma unroll
      for (int nt = 0; nt < 4; ++nt) {
        const bf16x8 vf = *(const bf16x8*)(vtb + (nt * 16 + l15) * LVT + kb * 32 + quad * 8);
        oacc[nt] = __builtin_amdgcn_mfma_f32_16x16x32_bf16(pa, vf, oacc[nt], 0, 0, 0);
      }
      __builtin_amdgcn_s_setprio(0);
    }

    __syncthreads();  // barrier A: all waves done reading buf[cur]
    if (t + 1 < NT) {
      const int nxt = cur ^ 1;
      *(bf16x8*)(&kt[nxt][kr0 * LKT + kc0]) = rk0;
      *(bf16x8*)(&kt[nxt][kr1 * LKT + kc1]) = rk1;
      *(bf16x8*)(&vt[nxt][vr0 * LVT + vc0]) = rv0;
      *(bf16x8*)(&vt[nxt][vr1 * LVT + vc1]) = rv1;
    }
    __syncthreads();  // barrier B: buf[cur^1] ready for next iter
  }

  // epilogue: divide by l (already in row layout via ones-MFMA), store ctx
#pragma unroll
  for (int r = 0; r < 4; ++r) {
    const float inv = 1.0f / lacc[r];
    const int row = qw + quad * 4 + r;
#pragma unroll
    for (int nt = 0; nt < 4; ++nt)
      O[base + (size_t)row * D_ + nt * 16 + l15] = (__bf16)(oacc[nt][r] * inv);
  }
}

extern "C" void kernel_launch(void* const* d_in, const int* in_sizes, int n_in,
                              void* d_out, int out_size, void* d_ws, size_t ws_size,
                              hipStream_t stream) {
  const float* x    = (const float*)d_in[0];
  const float* mask = (const float*)d_in[1];
  const float* Wq   = (const float*)d_in[2];
  const float* Wk   = (const float*)d_in[3];
  const float* Wv   = (const float*)d_in[4];
  const float* Wo   = (const float*)d_in[5];

  char* ws = (char*)d_ws;
  const size_t MB = 1ull << 20;
  const size_t NT = (size_t)B_ * S_ * D_;  // 4M elems, 8 MB bf16
  __bf16* xb  = (__bf16*)(ws);             // 8 MB; freed after qkv_gemm -> reused as cb
  __bf16* wqb = (__bf16*)(ws + 8 * MB);    // wq/wk/wv contiguous = packed [3072][1024]
  __bf16* wkb = (__bf16*)(ws + 10 * MB);
  __bf16* wvb = (__bf16*)(ws + 12 * MB);
  __bf16* wob = (__bf16*)(ws + 14 * MB);
  __bf16* qkv = (__bf16*)(ws + 16 * MB);   // 24 MB: Q, K, Vt
  __bf16* qb  = qkv;
  __bf16* kb  = qkv + NT;
  __bf16* vtb = qkv + 2 * NT;  // qkv_gemm sel==2 writes V pre-transposed here
  __bf16* cb  = xb;            // x consumed by qkv_gemm before attn writes ctx

  cvt_all<<<dim3(1024, 5), 256, 0, stream>>>(x, Wq, Wk, Wv, Wo, xb, wqb, wkb, wvb, wob);
  qkv_gemm<<<dim3(24, 32), 256, 0, stream>>>(xb, wqb, qkv);
  attn2<<<dim3(S_ / 128, H_, B_), 512, 0, stream>>>(qb, kb, vtb, mask, cb);
  o_gemm<<<dim3(8, 64), 256, 0, stream>>>(cb, wob, (float*)d_out);
}

// Round 7
// 208.579 us; speedup vs baseline: 1.1142x; 1.0084x over previous
//
#include <hip/hip_runtime.h>
#include <hip/hip_bf16.h>
#include <cstdint>
#include <cstddef>

// MHA B=2,S=2048,D=1024,H=16,HD=64.
// cvt(fp32->bf16) -> fused QKV GEMM (packed [3072][1024] weights, m97
// global_load_lds, 512-thr/8-wave blocks for 24 waves/CU, LDS-aliased vector
// epilogue, XCD 2D swizzle; V written pre-transposed) -> flash attn (S^T form,
// 128q x 128k tiles, 8 waves x 16q, in-register P via cvt_pk + permlane swaps,
// exp2-domain softmax, defer-max, T14 async-stage + double-buffered K/V,
// row-sum via ones-MFMA, shfl_xor max-reduce) -> O GEMM (64x128 tiles,
// 512-thr/8-wave, XCD 2D swizzle).
//
// r6 lesson: NEVER feed two copies of the SAME value to a "+v","+v" permlane
// swap asm — the compiler CSEs them into one VGPR and the swap self-permutes
// instead of exchanging. Max-reduce uses __shfl_xor (verified r1-r5).

#define B_  2
#define S_  2048
#define D_  1024
#define H_  16
#define HD_ 64

typedef __bf16 bf16x8 __attribute__((ext_vector_type(8)));
typedef __bf16 bf16x4 __attribute__((ext_vector_type(4)));
typedef float  f32x4  __attribute__((ext_vector_type(4)));

// ---- async global->LDS, 16B per lane. LDS dest must be wave-uniform base;
// HW adds lane*16 (guide §5 m97/m104). AS(3) ptr = low 32 bits of flat addr.
__device__ __forceinline__ void async16(const __bf16* g, const __bf16* l) {
  __builtin_amdgcn_global_load_lds(
      (const __attribute__((address_space(1))) void*)(uintptr_t)g,
      (__attribute__((address_space(3))) void*)(uint32_t)(uintptr_t)l,
      16, 0, 0);
}

// v_cvt_pk_bf16_f32: dst.lo16 = bf16(lo), dst.hi16 = bf16(hi)
__device__ __forceinline__ unsigned cvt_pk_bf16(float lo, float hi) {
  unsigned r;
  asm("v_cvt_pk_bf16_f32 %0, %1, %2" : "=v"(r) : "v"(lo), "v"(hi));
  return r;
}

// ---------------- fp32 -> bf16 convert (x + 4 weights) ----------------
__global__ __launch_bounds__(256) void cvt_all(const float* __restrict__ x,
    const float* __restrict__ wq, const float* __restrict__ wk,
    const float* __restrict__ wv, const float* __restrict__ wo,
    __bf16* __restrict__ xb, __bf16* __restrict__ wqb, __bf16* __restrict__ wkb,
    __bf16* __restrict__ wvb, __bf16* __restrict__ wob) {
  const int sel = blockIdx.y;
  const float* src; __bf16* dst; int n;
  if      (sel == 0) { src = x;  dst = xb;  n = B_ * S_ * D_; }
  else if (sel == 1) { src = wq; dst = wqb; n = D_ * D_; }
  else if (sel == 2) { src = wk; dst = wkb; n = D_ * D_; }
  else if (sel == 3) { src = wv; dst = wvb; n = D_ * D_; }
  else               { src = wo; dst = wob; n = D_ * D_; }
  for (int i = blockIdx.x * 256 + threadIdx.x; i * 4 < n; i += gridDim.x * 256) {
    const float4 v = *(const float4*)(src + (size_t)i * 4);
    bf16x4 o;
    o[0] = (__bf16)v.x; o[1] = (__bf16)v.y; o[2] = (__bf16)v.z; o[3] = (__bf16)v.w;
    *(bf16x4*)(dst + (size_t)i * 4) = o;
  }
}

// ---------------- fused QKV GEMM, packed weights [3072][1024], 512 thr ------
// 8 waves (4 row x 2 col, 32x64 out each, acc 2x4): same 128x128 tile, grid
// 768 = 3 blocks/CU -> 24 waves/CU (vs 12 at 256 thr). XCD 2D swizzle.
// LDS-aliased epilogue (cs reuses As/Bs after final barrier; 32768 B total).
// sel 0/1 (Q,K): vectorized bf16x8 row-major stores.
// sel 2   (V) : transposed store direct to Vt[b*1024 + e][s].
__global__ __launch_bounds__(512, 4) void qkv_gemm(const __bf16* __restrict__ xb,
                                                   const __bf16* __restrict__ wqkv,
                                                   __bf16* __restrict__ qkv) {
  __shared__ __align__(16) char smem[32768];
  __bf16* As = (__bf16*)smem;            // [128*64]
  __bf16* Bs = (__bf16*)(smem + 16384);  // [128*64]
  __bf16* cs = (__bf16*)smem;            // 64*136 = 17408 B, alias; post-loop only

  const int lin = blockIdx.y * 24 + blockIdx.x;   // 0..767
  const int xcd = lin & 7, slot = lin >> 3;       // slot 0..95
  const int mi = xcd >> 2, ni = xcd & 3;
  const int mB = mi * 16 + slot / 6;              // 0..31
  const int nB = ni * 6  + slot % 6;              // 0..23
  const int m0  = mB * 128;
  const int sel = nB >> 3;                        // 0..2 -> Q,K,V
  const int n0s = (nB & 7) * 128;                 // col offset within sel
  const int n0w = nB * 128;                       // row offset in packed weights
  constexpr int K = D_, N = D_;
  constexpr size_t NTE = (size_t)B_ * S_ * D_;

  const int tid  = threadIdx.x, lane = tid & 63, wave = tid >> 6;  // wave 0..7
  const int l15  = lane & 15,   quad = lane >> 4;
  const int wr   = wave >> 1,   wc   = wave & 1;   // 4 x 2 wave grid

  f32x4 acc[2][4] = {};
  for (int k0 = 0; k0 < K; k0 += 64) {
#pragma unroll
    for (int i = 0; i < 2; ++i) {
      const int e = (wave * 2 + i) * 512 + lane * 8;
      const int row = e >> 6, col = e & 63;
      async16(xb   + (size_t)(m0  + row) * K + k0 + col, As + (wave * 2 + i) * 512);
      async16(wqkv + (size_t)(n0w + row) * K + k0 + col, Bs + (wave * 2 + i) * 512);
    }
    __syncthreads();
#pragma unroll
    for (int kk = 0; kk < 2; ++kk) {
      bf16x8 af[2], bfv[4];
#pragma unroll
      for (int rt = 0; rt < 2; ++rt)
        af[rt] = *(const bf16x8*)(As + (wr * 32 + rt * 16 + l15) * 64 + kk * 32 + quad * 8);
#pragma unroll
      for (int ct = 0; ct < 4; ++ct)
        bfv[ct] = *(const bf16x8*)(Bs + (wc * 64 + ct * 16 + l15) * 64 + kk * 32 + quad * 8);
#pragma unroll
      for (int rt = 0; rt < 2; ++rt)
#pragma unroll
        for (int ct = 0; ct < 4; ++ct)
          acc[rt][ct] = __builtin_amdgcn_mfma_f32_16x16x32_bf16(af[rt], bfv[ct], acc[rt][ct], 0, 0, 0);
    }
    __syncthreads();
  }

  // epilogue: two 64-row passes through cs (aliases As/Bs; safe after last barrier)
  const int b  = m0 >> 11;       // batch (S_=2048 rows per batch)
  const int s0 = m0 & (S_ - 1);
  __bf16* vtb = qkv + 2 * NTE;   // Vt lives in the V slot
#pragma unroll
  for (int pass = 0; pass < 2; ++pass) {
    __syncthreads();  // prior pass's readers (or main-loop) done
    if ((wave >> 2) == pass) {   // waves 0-3 own rows 0-63, waves 4-7 rows 64-127
#pragma unroll
      for (int rt = 0; rt < 2; ++rt)
#pragma unroll
        for (int ct = 0; ct < 4; ++ct)
#pragma unroll
          for (int r = 0; r < 4; ++r)
            cs[((wr & 1) * 32 + rt * 16 + quad * 4 + r) * 136 + wc * 64 + ct * 16 + l15] =
                (__bf16)acc[rt][ct][r];
    }
    __syncthreads();
    if (sel < 2) {
      __bf16* C = qkv + (size_t)sel * NTE;
      const int rr = tid >> 3, cb = (tid & 7) * 16;  // 64 rows x 8 col-groups
      const bf16x8 v0 = *(const bf16x8*)(cs + rr * 136 + cb);
      const bf16x8 v1 = *(const bf16x8*)(cs + rr * 136 + cb + 8);
      *(bf16x8*)(C + (size_t)(m0 + pass * 64 + rr) * N + n0s + cb)     = v0;
      *(bf16x8*)(C + (size_t)(m0 + pass * 64 + rr) * N + n0s + cb + 8) = v1;
    } else {
      // transposed: output row = b*1024 + (n0s + e_loc), cols = s
      const int e_loc = tid >> 2, sh = (tid & 3) * 16;  // 128 e x 4 s-groups
      __bf16* dst = vtb + (size_t)(b * 1024 + n0s + e_loc) * S_ + s0 + pass * 64 + sh;
#pragma unroll
      for (int p2 = 0; p2 < 2; ++p2) {
        bf16x8 v;
#pragma unroll
        for (int j = 0; j < 8; ++j)
          v[j] = cs[(sh + p2 * 8 + j) * 136 + e_loc];
        *(bf16x8*)(dst + p2 * 8) = v;
      }
    }
  }
}

// ---------------- O GEMM: 64x128 tiles, 512 thr / 8 waves -------------------
// 8 waves (2 row x 4 col, 32x32 out each, acc 2x2); grid 512 = 2 blocks/CU ->
// 16 waves/CU (vs 8 at 256 thr). XCD 2D swizzle (16m x 4n per XCD).
__global__ __launch_bounds__(512, 4) void o_gemm(const __bf16* __restrict__ cb,
                                                 const __bf16* __restrict__ wo,
                                                 float* __restrict__ out) {
  __shared__ __align__(16) __bf16 As[64 * 64];
  __shared__ __align__(16) __bf16 Bs[128 * 64];
  const int lin = blockIdx.y * 8 + blockIdx.x;   // 0..511
  const int xcd = lin & 7, slot = lin >> 3;      // slot 0..63
  const int mi = xcd >> 1, ni = xcd & 1;
  const int mB = mi * 16 + (slot >> 2);          // 0..63
  const int nB = ni * 4  + (slot & 3);           // 0..7
  const int m0 = mB * 64, n0 = nB * 128;
  constexpr int K = D_, N = D_;
  const int tid  = threadIdx.x, lane = tid & 63, wave = tid >> 6;  // 0..7
  const int l15  = lane & 15,   quad = lane >> 4;
  const int wr   = wave >> 2,   wc   = wave & 3;   // 2 x 4 wave grid

  f32x4 acc[2][2] = {};
  for (int k0 = 0; k0 < K; k0 += 64) {
    {  // A: 64x64 elems = 1 chunk/wave
      const int e = wave * 512 + lane * 8;
      const int row = e >> 6, col = e & 63;
      async16(cb + (size_t)(m0 + row) * K + k0 + col, As + wave * 512);
    }
#pragma unroll
    for (int i = 0; i < 2; ++i) {  // B: 128x64 = 2 chunks/wave
      const int e = (wave * 2 + i) * 512 + lane * 8;
      const int row = e >> 6, col = e & 63;
      async16(wo + (size_t)(n0 + row) * K + k0 + col, Bs + (wave * 2 + i) * 512);
    }
    __syncthreads();
#pragma unroll
    for (int kk = 0; kk < 2; ++kk) {
      bf16x8 af[2], bfv[2];
#pragma unroll
      for (int rt = 0; rt < 2; ++rt)
        af[rt] = *(const bf16x8*)(As + (wr * 32 + rt * 16 + l15) * 64 + kk * 32 + quad * 8);
#pragma unroll
      for (int ct = 0; ct < 2; ++ct)
        bfv[ct] = *(const bf16x8*)(Bs + (wc * 32 + ct * 16 + l15) * 64 + kk * 32 + quad * 8);
#pragma unroll
      for (int rt = 0; rt < 2; ++rt)
#pragma unroll
        for (int ct = 0; ct < 2; ++ct)
          acc[rt][ct] = __builtin_amdgcn_mfma_f32_16x16x32_bf16(af[rt], bfv[ct], acc[rt][ct], 0, 0, 0);
    }
    __syncthreads();
  }
#pragma unroll
  for (int rt = 0; rt < 2; ++rt)
#pragma unroll
    for (int ct = 0; ct < 2; ++ct)
#pragma unroll
      for (int r = 0; r < 4; ++r) {
        const int row = m0 + wr * 32 + rt * 16 + quad * 4 + r;
        const int col = n0 + wc * 32 + ct * 16 + l15;
        out[(size_t)row * N + col] = acc[rt][ct][r];
      }
}

// ---------------- flash attention, S^T form, in-register P, T14 pipeline ----------
// r2 config (best measured: 64.2us): 8 waves x 16 q, KV tile = 128 keys.
// No XCD swizzle (r5: +2.8us when working set L2-fit, m160).
// S^T = K·Q^T: lane holds P[q=l15][32 keys]; in-register P via cvt_pk +
// permlane32/16_swap; row-sum l via ones-MFMA; max-reduce via __shfl_xor
// (r6: permlane with two copies of the same value CSEs to one VGPR -> broken);
// defer-max (THR=8, exp2 domain); T14 reg-prefetch + double-buffered K/V.
__global__ __launch_bounds__(512, 4) void attn2(const __bf16* __restrict__ Q,
                                                const __bf16* __restrict__ K,
                                                const __bf16* __restrict__ Vt,
                                                const float* __restrict__ mask,
                                                __bf16* __restrict__ O) {
  constexpr int LKT = 72, LVT = 136;
  __shared__ __align__(16) __bf16 kt[2][128 * LKT];   // 2 x 18432 B
  __shared__ __align__(16) __bf16 vt[2][64 * LVT];    // 2 x 17408 B
  __shared__ __align__(16) float  mfull[S_];          // 8192 B (pre-scaled by log2e)

  const int tid  = threadIdx.x, lane = tid & 63, wave = tid >> 6;
  const int l15  = lane & 15,   quad = lane >> 4;
  const int b = blockIdx.z, h = blockIdx.y, q0 = blockIdx.x * 128;
  const size_t base   = (size_t)b * S_ * D_ + h * HD_;
  const size_t vtbase = (size_t)(b * H_ + h) * HD_ * S_;
  const int qw = q0 + wave * 16;
  constexpr float LOG2E = 1.44269504088896340736f;
  constexpr float SC    = 0.125f * LOG2E;          // 1/sqrt(HD) * log2(e)
  constexpr int  NT     = S_ / 128;

  // per-thread staging slots (2 x 16B each for K and V tiles)
  const int idx0 = tid,        kr0 = idx0 >> 3, kc0 = (idx0 & 7) * 8;
  const int idx1 = 512 + tid,  kr1 = idx1 >> 3, kc1 = (idx1 & 7) * 8;
  const int vr0 = idx0 >> 4, vc0 = (idx0 & 15) * 8;
  const int vr1 = idx1 >> 4, vc1 = (idx1 & 15) * 8;

  // Q fragments (B-operand: n=l15 -> q row, k = kb*32+quad*8+j)
  bf16x8 qf[2];
#pragma unroll
  for (int kb = 0; kb < 2; ++kb)
    qf[kb] = *(const bf16x8*)(Q + base + (size_t)(qw + l15) * D_ + kb * 32 + quad * 8);

  bf16x8 ones;
#pragma unroll
  for (int j = 0; j < 8; ++j) ones[j] = (__bf16)1.0f;

  float m_run = -1e30f;
  f32x4 oacc[4] = {};
  f32x4 lacc   = {};

  // prologue: mask table + stage tile 0 into buf 0
  bf16x8 rk0, rk1, rv0, rv1;
  rk0 = *(const bf16x8*)(K + base + (size_t)kr0 * D_ + kc0);
  rk1 = *(const bf16x8*)(K + base + (size_t)kr1 * D_ + kc1);
  rv0 = *(const bf16x8*)(Vt + vtbase + (size_t)vr0 * S_ + vc0);
  rv1 = *(const bf16x8*)(Vt + vtbase + (size_t)vr1 * S_ + vc1);
#pragma unroll
  for (int i = 0; i < S_ / 512; ++i)
    mfull[i * 512 + tid] = mask[(size_t)b * S_ + i * 512 + tid] * LOG2E;
  *(bf16x8*)(&kt[0][kr0 * LKT + kc0]) = rk0;
  *(bf16x8*)(&kt[0][kr1 * LKT + kc1]) = rk1;
  *(bf16x8*)(&vt[0][vr0 * LVT + vc0]) = rv0;
  *(bf16x8*)(&vt[0][vr1 * LVT + vc1]) = rv1;
  __syncthreads();

  for (int t = 0; t < NT; ++t) {
    const int cur = t & 1;
    const int t0  = t * 128;
    const __bf16* ktb = &kt[cur][0];
    const __bf16* vtb = &vt[cur][0];

    // T14: issue next tile's global loads now; latency hides under compute
    if (t + 1 < NT) {
      const int tn = t0 + 128;
      rk0 = *(const bf16x8*)(K + base + (size_t)(tn + kr0) * D_ + kc0);
      rk1 = *(const bf16x8*)(K + base + (size_t)(tn + kr1) * D_ + kc1);
      rv0 = *(const bf16x8*)(Vt + vtbase + (size_t)vr0 * S_ + tn + vc0);
      rv1 = *(const bf16x8*)(Vt + vtbase + (size_t)vr1 * S_ + tn + vc1);
    }

    // S^T tile: D[m=key][n=q]; lane (l15,quad): key = kti*16+quad*4+r, q = l15
    f32x4 sacc[8] = {};
    __builtin_amdgcn_s_setprio(1);
#pragma unroll
    for (int kti = 0; kti < 8; ++kti) {
      const __bf16* kr = ktb + (kti * 16 + l15) * LKT + quad * 8;
      const bf16x8 a0 = *(const bf16x8*)(kr);
      const bf16x8 a1 = *(const bf16x8*)(kr + 32);
      sacc[kti] = __builtin_amdgcn_mfma_f32_16x16x32_bf16(a0, qf[0], sacc[kti], 0, 0, 0);
      sacc[kti] = __builtin_amdgcn_mfma_f32_16x16x32_bf16(a1, qf[1], sacc[kti], 0, 0, 0);
    }
    __builtin_amdgcn_s_setprio(0);

    // scale (exp2 domain) + mask, running max with 4 independent chains
    f32x4 tm4;
#pragma unroll
    for (int r = 0; r < 4; ++r) tm4[r] = -1e30f;
#pragma unroll
    for (int kti = 0; kti < 8; ++kti) {
      const f32x4 mv = *(const f32x4*)(mfull + t0 + kti * 16 + quad * 4);
#pragma unroll
      for (int r = 0; r < 4; ++r) {
        sacc[kti][r] = sacc[kti][r] * SC + mv[r];
        tm4[r] = fmaxf(tm4[r], sacc[kti][r]);
      }
    }
    float tm = fmaxf(fmaxf(tm4[0], tm4[1]), fmaxf(tm4[2], tm4[3]));
    tm = fmaxf(tm, __shfl_xor(tm, 16));
    tm = fmaxf(tm, __shfl_xor(tm, 32));

    // defer-max (T13): only rescale when tile max grows past THR=8 (p <= 2^8)
    if (!__all(tm <= m_run + 8.f)) {
      const float mnew  = fmaxf(m_run, tm);
      const float alpha = __builtin_amdgcn_exp2f(m_run - mnew);
      m_run = mnew;
#pragma unroll
      for (int r = 0; r < 4; ++r) {
        const float aR = __shfl(alpha, quad * 4 + r);
        lacc[r] *= aR;
#pragma unroll
        for (int nt = 0; nt < 4; ++nt) oacc[nt][r] *= aR;
      }
    }

    // exp2 + pack + permlane-redistribute + PV + row-sum, per kb (32 keys each)
#pragma unroll
    for (int kb = 0; kb < 4; ++kb) {
      unsigned dd[2][2];
#pragma unroll
      for (int kk = 0; kk < 2; ++kk) {
        const int kti = 2 * kb + kk;
        float p[4];
#pragma unroll
        for (int r = 0; r < 4; ++r)
          p[r] = __builtin_amdgcn_exp2f(sacc[kti][r] - m_run);
        dd[kk][0] = cvt_pk_bf16(p[0], p[1]);
        dd[kk][1] = cvt_pk_bf16(p[2], p[3]);
      }
      // quad shuffle: rows [A0,A1,A2,A3],[B0,B1,B2,B3] -> [A0,A2,B0,B2],[A1,A3,B1,B3]
      unsigned a0 = dd[0][0], b0 = dd[1][0], a1 = dd[0][1], b1 = dd[1][1];
      asm("v_permlane32_swap_b32 %0, %1" : "+v"(a0), "+v"(b0));
      asm("v_permlane16_swap_b32 %0, %1" : "+v"(a0), "+v"(b0));
      asm("v_permlane32_swap_b32 %0, %1" : "+v"(a1), "+v"(b1));
      asm("v_permlane16_swap_b32 %0, %1" : "+v"(a1), "+v"(b1));
      union { unsigned u[4]; bf16x8 v; } pw;
      pw.u[0] = a0; pw.u[1] = a1; pw.u[2] = b0; pw.u[3] = b1;
      const bf16x8 pa = pw.v;  // A[q=l15][key = kb*32 + quad*8 + j]
      __builtin_amdgcn_s_setprio(1);
      lacc = __builtin_amdgcn_mfma_f32_16x16x32_bf16(pa, ones, lacc, 0, 0, 0);
#pragma unroll
      for (int nt = 0; nt < 4; ++nt) {
        const bf16x8 vf = *(const bf16x8*)(vtb + (nt * 16 + l15) * LVT + kb * 32 + quad * 8);
        oacc[nt] = __builtin_amdgcn_mfma_f32_16x16x32_bf16(pa, vf, oacc[nt], 0, 0, 0);
      }
      __builtin_amdgcn_s_setprio(0);
    }

    __syncthreads();  // barrier A: all waves done reading buf[cur]
    if (t + 1 < NT) {
      const int nxt = cur ^ 1;
      *(bf16x8*)(&kt[nxt][kr0 * LKT + kc0]) = rk0;
      *(bf16x8*)(&kt[nxt][kr1 * LKT + kc1]) = rk1;
      *(bf16x8*)(&vt[nxt][vr0 * LVT + vc0]) = rv0;
      *(bf16x8*)(&vt[nxt][vr1 * LVT + vc1]) = rv1;
    }
    __syncthreads();  // barrier B: buf[cur^1] ready for next iter
  }

  // epilogue: divide by l (already in row layout via ones-MFMA), store ctx
#pragma unroll
  for (int r = 0; r < 4; ++r) {
    const float inv = 1.0f / lacc[r];
    const int row = qw + quad * 4 + r;
#pragma unroll
    for (int nt = 0; nt < 4; ++nt)
      O[base + (size_t)row * D_ + nt * 16 + l15] = (__bf16)(oacc[nt][r] * inv);
  }
}

extern "C" void kernel_launch(void* const* d_in, const int* in_sizes, int n_in,
                              void* d_out, int out_size, void* d_ws, size_t ws_size,
                              hipStream_t stream) {
  const float* x    = (const float*)d_in[0];
  const float* mask = (const float*)d_in[1];
  const float* Wq   = (const float*)d_in[2];
  const float* Wk   = (const float*)d_in[3];
  const float* Wv   = (const float*)d_in[4];
  const float* Wo   = (const float*)d_in[5];

  char* ws = (char*)d_ws;
  const size_t MB = 1ull << 20;
  const size_t NT = (size_t)B_ * S_ * D_;  // 4M elems, 8 MB bf16
  __bf16* xb  = (__bf16*)(ws);             // 8 MB; freed after qkv_gemm -> reused as cb
  __bf16* wqb = (__bf16*)(ws + 8 * MB);    // wq/wk/wv contiguous = packed [3072][1024]
  __bf16* wkb = (__bf16*)(ws + 10 * MB);
  __bf16* wvb = (__bf16*)(ws + 12 * MB);
  __bf16* wob = (__bf16*)(ws + 14 * MB);
  __bf16* qkv = (__bf16*)(ws + 16 * MB);   // 24 MB: Q, K, Vt
  __bf16* qb  = qkv;
  __bf16* kb  = qkv + NT;
  __bf16* vtb = qkv + 2 * NT;  // qkv_gemm sel==2 writes V pre-transposed here
  __bf16* cb  = xb;            // x consumed by qkv_gemm before attn writes ctx

  cvt_all<<<dim3(1024, 5), 256, 0, stream>>>(x, Wq, Wk, Wv, Wo, xb, wqb, wkb, wvb, wob);
  qkv_gemm<<<dim3(24, 32), 512, 0, stream>>>(xb, wqb, qkv);
  attn2<<<dim3(S_ / 128, H_, B_), 512, 0, stream>>>(qb, kb, vtb, mask, cb);
  o_gemm<<<dim3(8, 64), 512, 0, stream>>>(cb, wob, (float*)d_out);
}

// Round 8
// 200.110 us; speedup vs baseline: 1.1614x; 1.0423x over previous
//
#include <hip/hip_runtime.h>
#include <hip/hip_bf16.h>
#include <cstdint>
#include <cstddef>

// MHA B=2,S=2048,D=1024,H=16,HD=64.
// cvt(fp32->bf16) -> fused QKV GEMM (packed [3072][1024] weights, T3 2-phase
// double-buffered global_load_lds pipeline, 1 barrier/K-step, LDS-aliased
// vector epilogue, XCD 2D swizzle; V written pre-transposed) -> flash attn
// (S^T form, 128q x 128k tiles, 8 waves x 16q, in-register P via cvt_pk +
// permlane swaps, exp2-domain softmax, defer-max, T14 reg-prefetch +
// double-buffered K/V with SINGLE barrier/tile, row-sum via ones-MFMA) ->
// O GEMM (64x128 tiles, 2-phase dbuf, XCD 2D swizzle).
//
// r6 lesson: NEVER feed two copies of the SAME value to a "+v","+v" permlane
// swap asm — the compiler CSEs them into one VGPR and the swap self-permutes.
// r7 lesson: GEMM wave-count was null; the lever is the 2-phase pipeline.

#define B_  2
#define S_  2048
#define D_  1024
#define H_  16
#define HD_ 64

typedef __bf16 bf16x8 __attribute__((ext_vector_type(8)));
typedef __bf16 bf16x4 __attribute__((ext_vector_type(4)));
typedef float  f32x4  __attribute__((ext_vector_type(4)));

// ---- async global->LDS, 16B per lane. LDS dest must be wave-uniform base;
// HW adds lane*16 (guide §5 m97/m104). AS(3) ptr = low 32 bits of flat addr.
__device__ __forceinline__ void async16(const __bf16* g, const __bf16* l) {
  __builtin_amdgcn_global_load_lds(
      (const __attribute__((address_space(1))) void*)(uintptr_t)g,
      (__attribute__((address_space(3))) void*)(uint32_t)(uintptr_t)l,
      16, 0, 0);
}

// v_cvt_pk_bf16_f32: dst.lo16 = bf16(lo), dst.hi16 = bf16(hi)
__device__ __forceinline__ unsigned cvt_pk_bf16(float lo, float hi) {
  unsigned r;
  asm("v_cvt_pk_bf16_f32 %0, %1, %2" : "=v"(r) : "v"(lo), "v"(hi));
  return r;
}

// ---------------- fp32 -> bf16 convert (x + 4 weights) ----------------
__global__ __launch_bounds__(256) void cvt_all(const float* __restrict__ x,
    const float* __restrict__ wq, const float* __restrict__ wk,
    const float* __restrict__ wv, const float* __restrict__ wo,
    __bf16* __restrict__ xb, __bf16* __restrict__ wqb, __bf16* __restrict__ wkb,
    __bf16* __restrict__ wvb, __bf16* __restrict__ wob) {
  const int sel = blockIdx.y;
  const float* src; __bf16* dst; int n;
  if      (sel == 0) { src = x;  dst = xb;  n = B_ * S_ * D_; }
  else if (sel == 1) { src = wq; dst = wqb; n = D_ * D_; }
  else if (sel == 2) { src = wk; dst = wkb; n = D_ * D_; }
  else if (sel == 3) { src = wv; dst = wvb; n = D_ * D_; }
  else               { src = wo; dst = wob; n = D_ * D_; }
  for (int i = blockIdx.x * 256 + threadIdx.x; i * 4 < n; i += gridDim.x * 256) {
    const float4 v = *(const float4*)(src + (size_t)i * 4);
    bf16x4 o;
    o[0] = (__bf16)v.x; o[1] = (__bf16)v.y; o[2] = (__bf16)v.z; o[3] = (__bf16)v.w;
    *(bf16x4*)(dst + (size_t)i * 4) = o;
  }
}

// ---------------- fused QKV GEMM, packed weights [3072][1024], 2-phase ------
// T3-minimum pipeline: STAGE(buf[cur^1], t+1) BEFORE compute(buf[cur]); the
// barrier's vmcnt(0) drain lands after the MFMA block -> staging latency
// hidden; one barrier per K-step (was two). LDS 64KB dbuf -> 2 blocks/CU
// (r7: wave count is not the GEMM bottleneck). XCD 2D swizzle.
// sel 0/1 (Q,K): vectorized bf16x8 row-major stores.
// sel 2   (V) : transposed store direct to Vt[b*1024 + e][s].
__global__ __launch_bounds__(512, 4) void qkv_gemm(const __bf16* __restrict__ xb,
                                                   const __bf16* __restrict__ wqkv,
                                                   __bf16* __restrict__ qkv) {
  __shared__ __align__(16) char smem[65536];   // 2 x (As 16K + Bs 16K)
  __bf16* cs = (__bf16*)smem;                  // 64*136*2=17408 B alias; post-loop

  const int lin = blockIdx.y * 24 + blockIdx.x;   // 0..767
  const int xcd = lin & 7, slot = lin >> 3;       // slot 0..95
  const int mi = xcd >> 2, ni = xcd & 3;
  const int mB = mi * 16 + slot / 6;              // 0..31
  const int nB = ni * 6  + slot % 6;              // 0..23
  const int m0  = mB * 128;
  const int sel = nB >> 3;                        // 0..2 -> Q,K,V
  const int n0s = (nB & 7) * 128;                 // col offset within sel
  const int n0w = nB * 128;                       // row offset in packed weights
  constexpr int K = D_, N = D_;
  constexpr size_t NTE = (size_t)B_ * S_ * D_;

  const int tid  = threadIdx.x, lane = tid & 63, wave = tid >> 6;  // wave 0..7
  const int l15  = lane & 15,   quad = lane >> 4;
  const int wr   = wave >> 1,   wc   = wave & 1;   // 4 x 2 wave grid

  // per-thread staging geometry (2 async16 each for As and Bs)
  const int e0 = (wave * 2 + 0) * 512 + lane * 8;
  const int e1 = (wave * 2 + 1) * 512 + lane * 8;
  const int r0 = e0 >> 6, c0 = e0 & 63, r1 = e1 >> 6, c1 = e1 & 63;

  f32x4 acc[2][4] = {};

  // prologue: stage K-step 0 into buf 0
  {
    __bf16* As = (__bf16*)(smem);
    __bf16* Bs = (__bf16*)(smem + 16384);
    async16(xb   + (size_t)(m0  + r0) * K + c0, As + (wave * 2 + 0) * 512);
    async16(xb   + (size_t)(m0  + r1) * K + c1, As + (wave * 2 + 1) * 512);
    async16(wqkv + (size_t)(n0w + r0) * K + c0, Bs + (wave * 2 + 0) * 512);
    async16(wqkv + (size_t)(n0w + r1) * K + c1, Bs + (wave * 2 + 1) * 512);
  }
  __syncthreads();

  for (int t = 0; t < K / 64; ++t) {
    const int cur = t & 1;
    // stage next K-step into the other buffer (loads in flight across compute)
    if (t + 1 < K / 64) {
      const int k0 = (t + 1) * 64;
      __bf16* As = (__bf16*)(smem + (cur ^ 1) * 32768);
      __bf16* Bs = (__bf16*)(smem + (cur ^ 1) * 32768 + 16384);
      async16(xb   + (size_t)(m0  + r0) * K + k0 + c0, As + (wave * 2 + 0) * 512);
      async16(xb   + (size_t)(m0  + r1) * K + k0 + c1, As + (wave * 2 + 1) * 512);
      async16(wqkv + (size_t)(n0w + r0) * K + k0 + c0, Bs + (wave * 2 + 0) * 512);
      async16(wqkv + (size_t)(n0w + r1) * K + k0 + c1, Bs + (wave * 2 + 1) * 512);
    }
    const __bf16* As = (const __bf16*)(smem + cur * 32768);
    const __bf16* Bs = (const __bf16*)(smem + cur * 32768 + 16384);
#pragma unroll
    for (int kk = 0; kk < 2; ++kk) {
      bf16x8 af[2], bfv[4];
#pragma unroll
      for (int rt = 0; rt < 2; ++rt)
        af[rt] = *(const bf16x8*)(As + (wr * 32 + rt * 16 + l15) * 64 + kk * 32 + quad * 8);
#pragma unroll
      for (int ct = 0; ct < 4; ++ct)
        bfv[ct] = *(const bf16x8*)(Bs + (wc * 64 + ct * 16 + l15) * 64 + kk * 32 + quad * 8);
#pragma unroll
      for (int rt = 0; rt < 2; ++rt)
#pragma unroll
        for (int ct = 0; ct < 4; ++ct)
          acc[rt][ct] = __builtin_amdgcn_mfma_f32_16x16x32_bf16(af[rt], bfv[ct], acc[rt][ct], 0, 0, 0);
    }
    __syncthreads();  // drains staged loads (after compute) + guards buf reuse
  }

  // epilogue: two 64-row passes through cs (aliases smem; post-loop barrier done)
  const int b  = m0 >> 11;       // batch (S_=2048 rows per batch)
  const int s0 = m0 & (S_ - 1);
  __bf16* vtb = qkv + 2 * NTE;   // Vt lives in the V slot
#pragma unroll
  for (int pass = 0; pass < 2; ++pass) {
    __syncthreads();  // prior pass's readers (or main loop) done
    if ((wave >> 2) == pass) {   // waves 0-3 own rows 0-63, waves 4-7 rows 64-127
#pragma unroll
      for (int rt = 0; rt < 2; ++rt)
#pragma unroll
        for (int ct = 0; ct < 4; ++ct)
#pragma unroll
          for (int r = 0; r < 4; ++r)
            cs[((wr & 1) * 32 + rt * 16 + quad * 4 + r) * 136 + wc * 64 + ct * 16 + l15] =
                (__bf16)acc[rt][ct][r];
    }
    __syncthreads();
    if (sel < 2) {
      __bf16* C = qkv + (size_t)sel * NTE;
      const int rr = tid >> 3, cb = (tid & 7) * 16;  // 64 rows x 8 col-groups
      const bf16x8 v0 = *(const bf16x8*)(cs + rr * 136 + cb);
      const bf16x8 v1 = *(const bf16x8*)(cs + rr * 136 + cb + 8);
      *(bf16x8*)(C + (size_t)(m0 + pass * 64 + rr) * N + n0s + cb)     = v0;
      *(bf16x8*)(C + (size_t)(m0 + pass * 64 + rr) * N + n0s + cb + 8) = v1;
    } else {
      // transposed: output row = b*1024 + (n0s + e_loc), cols = s
      const int e_loc = tid >> 2, sh = (tid & 3) * 16;  // 128 e x 4 s-groups
      __bf16* dst = vtb + (size_t)(b * 1024 + n0s + e_loc) * S_ + s0 + pass * 64 + sh;
#pragma unroll
      for (int p2 = 0; p2 < 2; ++p2) {
        bf16x8 v;
#pragma unroll
        for (int j = 0; j < 8; ++j)
          v[j] = cs[(sh + p2 * 8 + j) * 136 + e_loc];
        *(bf16x8*)(dst + p2 * 8) = v;
      }
    }
  }
}

// ---------------- O GEMM: 64x128 tiles, 2-phase dbuf pipeline ---------------
// Same T3-minimum structure; LDS 48KB dbuf -> 3 blocks/CU. XCD 2D swizzle.
__global__ __launch_bounds__(512, 4) void o_gemm(const __bf16* __restrict__ cb,
                                                 const __bf16* __restrict__ wo,
                                                 float* __restrict__ out) {
  __shared__ __align__(16) char smem[49152];   // 2 x (As 8K + Bs 16K)
  const int lin = blockIdx.y * 8 + blockIdx.x;   // 0..511
  const int xcd = lin & 7, slot = lin >> 3;      // slot 0..63
  const int mi = xcd >> 1, ni = xcd & 1;
  const int mB = mi * 16 + (slot >> 2);          // 0..63
  const int nB = ni * 4  + (slot & 3);           // 0..7
  const int m0 = mB * 64, n0 = nB * 128;
  constexpr int K = D_, N = D_;
  const int tid  = threadIdx.x, lane = tid & 63, wave = tid >> 6;  // 0..7
  const int l15  = lane & 15,   quad = lane >> 4;
  const int wr   = wave >> 2,   wc   = wave & 3;   // 2 x 4 wave grid

  // staging geometry: A 1 async16/thread, B 2 async16/thread
  const int ea  = wave * 512 + lane * 8;
  const int ra  = ea >> 6, ca = ea & 63;
  const int eb0 = (wave * 2 + 0) * 512 + lane * 8;
  const int eb1 = (wave * 2 + 1) * 512 + lane * 8;
  const int rb0 = eb0 >> 6, cb0 = eb0 & 63, rb1 = eb1 >> 6, cb1 = eb1 & 63;

  f32x4 acc[2][2] = {};
  {
    __bf16* As = (__bf16*)(smem);
    __bf16* Bs = (__bf16*)(smem + 8192);
    async16(cb + (size_t)(m0 + ra)  * K + ca,  As + wave * 512);
    async16(wo + (size_t)(n0 + rb0) * K + cb0, Bs + (wave * 2 + 0) * 512);
    async16(wo + (size_t)(n0 + rb1) * K + cb1, Bs + (wave * 2 + 1) * 512);
  }
  __syncthreads();

  for (int t = 0; t < K / 64; ++t) {
    const int cur = t & 1;
    if (t + 1 < K / 64) {
      const int k0 = (t + 1) * 64;
      __bf16* As = (__bf16*)(smem + (cur ^ 1) * 24576);
      __bf16* Bs = (__bf16*)(smem + (cur ^ 1) * 24576 + 8192);
      async16(cb + (size_t)(m0 + ra)  * K + k0 + ca,  As + wave * 512);
      async16(wo + (size_t)(n0 + rb0) * K + k0 + cb0, Bs + (wave * 2 + 0) * 512);
      async16(wo + (size_t)(n0 + rb1) * K + k0 + cb1, Bs + (wave * 2 + 1) * 512);
    }
    const __bf16* As = (const __bf16*)(smem + cur * 24576);
    const __bf16* Bs = (const __bf16*)(smem + cur * 24576 + 8192);
#pragma unroll
    for (int kk = 0; kk < 2; ++kk) {
      bf16x8 af[2], bfv[2];
#pragma unroll
      for (int rt = 0; rt < 2; ++rt)
        af[rt] = *(const bf16x8*)(As + (wr * 32 + rt * 16 + l15) * 64 + kk * 32 + quad * 8);
#pragma unroll
      for (int ct = 0; ct < 2; ++ct)
        bfv[ct] = *(const bf16x8*)(Bs + (wc * 32 + ct * 16 + l15) * 64 + kk * 32 + quad * 8);
#pragma unroll
      for (int rt = 0; rt < 2; ++rt)
#pragma unroll
        for (int ct = 0; ct < 2; ++ct)
          acc[rt][ct] = __builtin_amdgcn_mfma_f32_16x16x32_bf16(af[rt], bfv[ct], acc[rt][ct], 0, 0, 0);
    }
    __syncthreads();
  }
#pragma unroll
  for (int rt = 0; rt < 2; ++rt)
#pragma unroll
    for (int ct = 0; ct < 2; ++ct)
#pragma unroll
      for (int r = 0; r < 4; ++r) {
        const int row = m0 + wr * 32 + rt * 16 + quad * 4 + r;
        const int col = n0 + wc * 32 + ct * 16 + l15;
        out[(size_t)row * N + col] = acc[rt][ct][r];
      }
}

// ---------------- flash attention: single barrier per KV tile ---------------
// r2 config (8 waves x 16 q, 128-key tiles) + single-barrier dbuf: the
// end-of-iter barrier already separates consecutive tiles' compute, so
// ds_write of tile t+1 into buf[cur^1] at the TOP of iter t is race-free.
// Plain-register global loads pass through __syncthreads undrained (T14, r2),
// so tile t+2's loads get a full tile of latency hiding. 16 barriers (was 32).
// S^T = K·Q^T: lane holds P[q=l15][32 keys]; in-register P via cvt_pk +
// permlane32/16_swap; row-sum l via ones-MFMA; max-reduce via __shfl_xor;
// defer-max (THR=8, exp2 domain). No XCD swizzle (r5: L2-fit, m160).
__global__ __launch_bounds__(512, 4) void attn2(const __bf16* __restrict__ Q,
                                                const __bf16* __restrict__ K,
                                                const __bf16* __restrict__ Vt,
                                                const float* __restrict__ mask,
                                                __bf16* __restrict__ O) {
  constexpr int LKT = 72, LVT = 136;
  __shared__ __align__(16) __bf16 kt[2][128 * LKT];   // 2 x 18432 B
  __shared__ __align__(16) __bf16 vt[2][64 * LVT];    // 2 x 17408 B
  __shared__ __align__(16) float  mfull[S_];          // 8192 B (pre-scaled by log2e)

  const int tid  = threadIdx.x, lane = tid & 63, wave = tid >> 6;
  const int l15  = lane & 15,   quad = lane >> 4;
  const int b = blockIdx.z, h = blockIdx.y, q0 = blockIdx.x * 128;
  const size_t base   = (size_t)b * S_ * D_ + h * HD_;
  const size_t vtbase = (size_t)(b * H_ + h) * HD_ * S_;
  const int qw = q0 + wave * 16;
  constexpr float LOG2E = 1.44269504088896340736f;
  constexpr float SC    = 0.125f * LOG2E;          // 1/sqrt(HD) * log2(e)
  constexpr int  NT     = S_ / 128;

  // per-thread staging slots (2 x 16B each for K and V tiles)
  const int idx0 = tid,        kr0 = idx0 >> 3, kc0 = (idx0 & 7) * 8;
  const int idx1 = 512 + tid,  kr1 = idx1 >> 3, kc1 = (idx1 & 7) * 8;
  const int vr0 = idx0 >> 4, vc0 = (idx0 & 15) * 8;
  const int vr1 = idx1 >> 4, vc1 = (idx1 & 15) * 8;

  // Q fragments (B-operand: n=l15 -> q row, k = kb*32+quad*8+j)
  bf16x8 qf[2];
#pragma unroll
  for (int kb = 0; kb < 2; ++kb)
    qf[kb] = *(const bf16x8*)(Q + base + (size_t)(qw + l15) * D_ + kb * 32 + quad * 8);

  bf16x8 ones;
#pragma unroll
  for (int j = 0; j < 8; ++j) ones[j] = (__bf16)1.0f;

  float m_run = -1e30f;
  f32x4 oacc[4] = {};
  f32x4 lacc   = {};

  // prologue: mask table + tile 0 -> buf 0 + issue tile 1 loads
  bf16x8 rk0, rk1, rv0, rv1;
  rk0 = *(const bf16x8*)(K + base + (size_t)kr0 * D_ + kc0);
  rk1 = *(const bf16x8*)(K + base + (size_t)kr1 * D_ + kc1);
  rv0 = *(const bf16x8*)(Vt + vtbase + (size_t)vr0 * S_ + vc0);
  rv1 = *(const bf16x8*)(Vt + vtbase + (size_t)vr1 * S_ + vc1);
#pragma unroll
  for (int i = 0; i < S_ / 512; ++i)
    mfull[i * 512 + tid] = mask[(size_t)b * S_ + i * 512 + tid] * LOG2E;
  *(bf16x8*)(&kt[0][kr0 * LKT + kc0]) = rk0;
  *(bf16x8*)(&kt[0][kr1 * LKT + kc1]) = rk1;
  *(bf16x8*)(&vt[0][vr0 * LVT + vc0]) = rv0;
  *(bf16x8*)(&vt[0][vr1 * LVT + vc1]) = rv1;
  if (NT > 1) {  // issue tile 1 loads (land before their ds_write in iter 0)
    rk0 = *(const bf16x8*)(K + base + (size_t)(128 + kr0) * D_ + kc0);
    rk1 = *(const bf16x8*)(K + base + (size_t)(128 + kr1) * D_ + kc1);
    rv0 = *(const bf16x8*)(Vt + vtbase + (size_t)vr0 * S_ + 128 + vc0);
    rv1 = *(const bf16x8*)(Vt + vtbase + (size_t)vr1 * S_ + 128 + vc1);
  }
  __syncthreads();

  for (int t = 0; t < NT; ++t) {
    const int cur = t & 1;
    const int t0  = t * 128;
    const __bf16* ktb = &kt[cur][0];
    const __bf16* vtb = &vt[cur][0];

    // write staged tile t+1 into buf[cur^1] (race-free: barrier ended iter t-1)
    if (t + 1 < NT) {
      const int nxt = cur ^ 1;
      *(bf16x8*)(&kt[nxt][kr0 * LKT + kc0]) = rk0;
      *(bf16x8*)(&kt[nxt][kr1 * LKT + kc1]) = rk1;
      *(bf16x8*)(&vt[nxt][vr0 * LVT + vc0]) = rv0;
      *(bf16x8*)(&vt[nxt][vr1 * LVT + vc1]) = rv1;
    }
    // issue tile t+2 global loads (full-tile latency hiding)
    if (t + 2 < NT) {
      const int tn = t0 + 256;
      rk0 = *(const bf16x8*)(K + base + (size_t)(tn + kr0) * D_ + kc0);
      rk1 = *(const bf16x8*)(K + base + (size_t)(tn + kr1) * D_ + kc1);
      rv0 = *(const bf16x8*)(Vt + vtbase + (size_t)vr0 * S_ + tn + vc0);
      rv1 = *(const bf16x8*)(Vt + vtbase + (size_t)vr1 * S_ + tn + vc1);
    }

    // S^T tile: D[m=key][n=q]; lane (l15,quad): key = kti*16+quad*4+r, q = l15
    f32x4 sacc[8] = {};
    __builtin_amdgcn_s_setprio(1);
#pragma unroll
    for (int kti = 0; kti < 8; ++kti) {
      const __bf16* kr = ktb + (kti * 16 + l15) * LKT + quad * 8;
      const bf16x8 a0 = *(const bf16x8*)(kr);
      const bf16x8 a1 = *(const bf16x8*)(kr + 32);
      sacc[kti] = __builtin_amdgcn_mfma_f32_16x16x32_bf16(a0, qf[0], sacc[kti], 0, 0, 0);
      sacc[kti] = __builtin_amdgcn_mfma_f32_16x16x32_bf16(a1, qf[1], sacc[kti], 0, 0, 0);
    }
    __builtin_amdgcn_s_setprio(0);

    // scale (exp2 domain) + mask, running max with 4 independent chains
    f32x4 tm4;
#pragma unroll
    for (int r = 0; r < 4; ++r) tm4[r] = -1e30f;
#pragma unroll
    for (int kti = 0; kti < 8; ++kti) {
      const f32x4 mv = *(const f32x4*)(mfull + t0 + kti * 16 + quad * 4);
#pragma unroll
      for (int r = 0; r < 4; ++r) {
        sacc[kti][r] = sacc[kti][r] * SC + mv[r];
        tm4[r] = fmaxf(tm4[r], sacc[kti][r]);
      }
    }
    float tm = fmaxf(fmaxf(tm4[0], tm4[1]), fmaxf(tm4[2], tm4[3]));
    tm = fmaxf(tm, __shfl_xor(tm, 16));
    tm = fmaxf(tm, __shfl_xor(tm, 32));

    // defer-max (T13): only rescale when tile max grows past THR=8 (p <= 2^8)
    if (!__all(tm <= m_run + 8.f)) {
      const float mnew  = fmaxf(m_run, tm);
      const float alpha = __builtin_amdgcn_exp2f(m_run - mnew);
      m_run = mnew;
#pragma unroll
      for (int r = 0; r < 4; ++r) {
        const float aR = __shfl(alpha, quad * 4 + r);
        lacc[r] *= aR;
#pragma unroll
        for (int nt = 0; nt < 4; ++nt) oacc[nt][r] *= aR;
      }
    }

    // exp2 + pack + permlane-redistribute + PV + row-sum, per kb (32 keys each)
#pragma unroll
    for (int kb = 0; kb < 4; ++kb) {
      unsigned dd[2][2];
#pragma unroll
      for (int kk = 0; kk < 2; ++kk) {
        const int kti = 2 * kb + kk;
        float p[4];
#pragma unroll
        for (int r = 0; r < 4; ++r)
          p[r] = __builtin_amdgcn_exp2f(sacc[kti][r] - m_run);
        dd[kk][0] = cvt_pk_bf16(p[0], p[1]);
        dd[kk][1] = cvt_pk_bf16(p[2], p[3]);
      }
      // quad shuffle: rows [A0,A1,A2,A3],[B0,B1,B2,B3] -> [A0,A2,B0,B2],[A1,A3,B1,B3]
      unsigned a0 = dd[0][0], b0 = dd[1][0], a1 = dd[0][1], b1 = dd[1][1];
      asm("v_permlane32_swap_b32 %0, %1" : "+v"(a0), "+v"(b0));
      asm("v_permlane16_swap_b32 %0, %1" : "+v"(a0), "+v"(b0));
      asm("v_permlane32_swap_b32 %0, %1" : "+v"(a1), "+v"(b1));
      asm("v_permlane16_swap_b32 %0, %1" : "+v"(a1), "+v"(b1));
      union { unsigned u[4]; bf16x8 v; } pw;
      pw.u[0] = a0; pw.u[1] = a1; pw.u[2] = b0; pw.u[3] = b1;
      const bf16x8 pa = pw.v;  // A[q=l15][key = kb*32 + quad*8 + j]
      __builtin_amdgcn_s_setprio(1);
      lacc = __builtin_amdgcn_mfma_f32_16x16x32_bf16(pa, ones, lacc, 0, 0, 0);
#pragma unroll
      for (int nt = 0; nt < 4; ++nt) {
        const bf16x8 vf = *(const bf16x8*)(vtb + (nt * 16 + l15) * LVT + kb * 32 + quad * 8);
        oacc[nt] = __builtin_amdgcn_mfma_f32_16x16x32_bf16(pa, vf, oacc[nt], 0, 0, 0);
      }
      __builtin_amdgcn_s_setprio(0);
    }

    __syncthreads();  // single barrier: ds_writes visible + buf reuse guarded
  }

  // epilogue: divide by l (already in row layout via ones-MFMA), store ctx
#pragma unroll
  for (int r = 0; r < 4; ++r) {
    const float inv = 1.0f / lacc[r];
    const int row = qw + quad * 4 + r;
#pragma unroll
    for (int nt = 0; nt < 4; ++nt)
      O[base + (size_t)row * D_ + nt * 16 + l15] = (__bf16)(oacc[nt][r] * inv);
  }
}

extern "C" void kernel_launch(void* const* d_in, const int* in_sizes, int n_in,
                              void* d_out, int out_size, void* d_ws, size_t ws_size,
                              hipStream_t stream) {
  const float* x    = (const float*)d_in[0];
  const float* mask = (const float*)d_in[1];
  const float* Wq   = (const float*)d_in[2];
  const float* Wk   = (const float*)d_in[3];
  const float* Wv   = (const float*)d_in[4];
  const float* Wo   = (const float*)d_in[5];

  char* ws = (char*)d_ws;
  const size_t MB = 1ull << 20;
  const size_t NT = (size_t)B_ * S_ * D_;  // 4M elems, 8 MB bf16
  __bf16* xb  = (__bf16*)(ws);             // 8 MB; freed after qkv_gemm -> reused as cb
  __bf16* wqb = (__bf16*)(ws + 8 * MB);    // wq/wk/wv contiguous = packed [3072][1024]
  __bf16* wkb = (__bf16*)(ws + 10 * MB);
  __bf16* wvb = (__bf16*)(ws + 12 * MB);
  __bf16* wob = (__bf16*)(ws + 14 * MB);
  __bf16* qkv = (__bf16*)(ws + 16 * MB);   // 24 MB: Q, K, Vt
  __bf16* qb  = qkv;
  __bf16* kb  = qkv + NT;
  __bf16* vtb = qkv + 2 * NT;  // qkv_gemm sel==2 writes V pre-transposed here
  __bf16* cb  = xb;            // x consumed by qkv_gemm before attn writes ctx

  cvt_all<<<dim3(1024, 5), 256, 0, stream>>>(x, Wq, Wk, Wv, Wo, xb, wqb, wkb, wvb, wob);
  qkv_gemm<<<dim3(24, 32), 512, 0, stream>>>(xb, wqb, qkv);
  attn2<<<dim3(S_ / 128, H_, B_), 512, 0, stream>>>(qb, kb, vtb, mask, cb);
  o_gemm<<<dim3(8, 64), 512, 0, stream>>>(cb, wob, (float*)d_out);
}

// Round 9
// 198.790 us; speedup vs baseline: 1.1691x; 1.0066x over previous
//
#include <hip/hip_runtime.h>
#include <hip/hip_bf16.h>
#include <cstdint>
#include <cstddef>

// MHA B=2,S=2048,D=1024,H=16,HD=64.
// cvt(fp32->bf16) -> fused QKV GEMM (packed [3072][1024] weights, T3 2-phase
// double-buffered global_load_lds pipeline, 4 waves x acc[4][4] (MFMA:ds_read
// ratio 2.0), 1 barrier/K-step, LDS-aliased vector epilogue, XCD 2D swizzle;
// V written pre-transposed) -> flash attn (S^T form, 128q x 128k tiles,
// 8 waves x 16q, in-register P via cvt_pk + permlane swaps, exp2-domain
// softmax, defer-max, T14 reg-prefetch + dbuf K/V, single barrier/tile,
// row-sum via ones-MFMA) -> O GEMM (128x128 tiles, 4 waves x acc[4][4],
// 2-phase dbuf, XCD 2D swizzle).
//
// r6 lesson: NEVER feed two copies of the SAME value to a "+v","+v" permlane
// swap asm — the compiler CSEs them into one VGPR and the swap self-permutes.
// r7 lesson: GEMM wave-count was null; the lever is the 2-phase pipeline.
// r8 lesson: acc 2x4 (ratio 1.33) makes the LDS pipe the critical path once
// the pipeline removes the barrier drain; acc 4x4 (ratio 2.0) rebalances.

#define B_  2
#define S_  2048
#define D_  1024
#define H_  16
#define HD_ 64

typedef __bf16 bf16x8 __attribute__((ext_vector_type(8)));
typedef __bf16 bf16x4 __attribute__((ext_vector_type(4)));
typedef float  f32x4  __attribute__((ext_vector_type(4)));

// ---- async global->LDS, 16B per lane. LDS dest must be wave-uniform base;
// HW adds lane*16 (guide §5 m97/m104). AS(3) ptr = low 32 bits of flat addr.
__device__ __forceinline__ void async16(const __bf16* g, const __bf16* l) {
  __builtin_amdgcn_global_load_lds(
      (const __attribute__((address_space(1))) void*)(uintptr_t)g,
      (__attribute__((address_space(3))) void*)(uint32_t)(uintptr_t)l,
      16, 0, 0);
}

// v_cvt_pk_bf16_f32: dst.lo16 = bf16(lo), dst.hi16 = bf16(hi)
__device__ __forceinline__ unsigned cvt_pk_bf16(float lo, float hi) {
  unsigned r;
  asm("v_cvt_pk_bf16_f32 %0, %1, %2" : "=v"(r) : "v"(lo), "v"(hi));
  return r;
}

// ---------------- fp32 -> bf16 convert (x + 4 weights) ----------------
__global__ __launch_bounds__(256) void cvt_all(const float* __restrict__ x,
    const float* __restrict__ wq, const float* __restrict__ wk,
    const float* __restrict__ wv, const float* __restrict__ wo,
    __bf16* __restrict__ xb, __bf16* __restrict__ wqb, __bf16* __restrict__ wkb,
    __bf16* __restrict__ wvb, __bf16* __restrict__ wob) {
  const int sel = blockIdx.y;
  const float* src; __bf16* dst; int n;
  if      (sel == 0) { src = x;  dst = xb;  n = B_ * S_ * D_; }
  else if (sel == 1) { src = wq; dst = wqb; n = D_ * D_; }
  else if (sel == 2) { src = wk; dst = wkb; n = D_ * D_; }
  else if (sel == 3) { src = wv; dst = wvb; n = D_ * D_; }
  else               { src = wo; dst = wob; n = D_ * D_; }
  for (int i = blockIdx.x * 256 + threadIdx.x; i * 4 < n; i += gridDim.x * 256) {
    const float4 v = *(const float4*)(src + (size_t)i * 4);
    bf16x4 o;
    o[0] = (__bf16)v.x; o[1] = (__bf16)v.y; o[2] = (__bf16)v.z; o[3] = (__bf16)v.w;
    *(bf16x4*)(dst + (size_t)i * 4) = o;
  }
}

// ---------------- fused QKV GEMM, packed weights [3072][1024] ----------------
// 256 thr / 4 waves / acc[4][4] (m97 ratio-2 shape) + 2-phase dbuf pipeline:
// STAGE(buf[cur^1], t+1) BEFORE compute(buf[cur]); one barrier per K-step.
// LDS 64KB dbuf -> 2 blocks/CU. XCD 2D swizzle. LDS-aliased epilogue.
// sel 0/1 (Q,K): vectorized bf16x8 row-major stores.
// sel 2   (V) : transposed store direct to Vt[b*1024 + e][s].
__global__ __launch_bounds__(256) void qkv_gemm(const __bf16* __restrict__ xb,
                                                const __bf16* __restrict__ wqkv,
                                                __bf16* __restrict__ qkv) {
  __shared__ __align__(16) char smem[65536];   // 2 x (As 16K + Bs 16K)
  __bf16* cs = (__bf16*)smem;                  // 64*136 alias; post-loop only

  const int lin = blockIdx.y * 24 + blockIdx.x;   // 0..767
  const int xcd = lin & 7, slot = lin >> 3;       // slot 0..95
  const int mi = xcd >> 2, ni = xcd & 3;
  const int mB = mi * 16 + slot / 6;              // 0..31
  const int nB = ni * 6  + slot % 6;              // 0..23
  const int m0  = mB * 128;
  const int sel = nB >> 3;                        // 0..2 -> Q,K,V
  const int n0s = (nB & 7) * 128;                 // col offset within sel
  const int n0w = nB * 128;                       // row offset in packed weights
  constexpr int K = D_, N = D_;
  constexpr size_t NTE = (size_t)B_ * S_ * D_;

  const int tid  = threadIdx.x, lane = tid & 63, wave = tid >> 6;  // wave 0..3
  const int l15  = lane & 15,   quad = lane >> 4;
  const int wr   = wave >> 1,   wc   = wave & 1;   // 2 x 2 wave grid (64x64 each)
  const int ebase = wave * 2048 + lane * 8;

  f32x4 acc[4][4] = {};

  // prologue: stage K-step 0 into buf 0
  {
    __bf16* As = (__bf16*)(smem);
    __bf16* Bs = (__bf16*)(smem + 16384);
#pragma unroll
    for (int i = 0; i < 4; ++i) {
      const int e = ebase + i * 512;
      const int row = e >> 6, col = e & 63;
      async16(xb   + (size_t)(m0  + row) * K + col, As + (wave * 4 + i) * 512);
      async16(wqkv + (size_t)(n0w + row) * K + col, Bs + (wave * 4 + i) * 512);
    }
  }
  __syncthreads();

  for (int t = 0; t < K / 64; ++t) {
    const int cur = t & 1;
    // stage next K-step into the other buffer (loads in flight across compute)
    if (t + 1 < K / 64) {
      const int k0 = (t + 1) * 64;
      __bf16* As = (__bf16*)(smem + (cur ^ 1) * 32768);
      __bf16* Bs = (__bf16*)(smem + (cur ^ 1) * 32768 + 16384);
#pragma unroll
      for (int i = 0; i < 4; ++i) {
        const int e = ebase + i * 512;
        const int row = e >> 6, col = e & 63;
        async16(xb   + (size_t)(m0  + row) * K + k0 + col, As + (wave * 4 + i) * 512);
        async16(wqkv + (size_t)(n0w + row) * K + k0 + col, Bs + (wave * 4 + i) * 512);
      }
    }
    const __bf16* As = (const __bf16*)(smem + cur * 32768);
    const __bf16* Bs = (const __bf16*)(smem + cur * 32768 + 16384);
#pragma unroll
    for (int kk = 0; kk < 2; ++kk) {
      bf16x8 af[4], bfv[4];
#pragma unroll
      for (int rt = 0; rt < 4; ++rt)
        af[rt] = *(const bf16x8*)(As + (wr * 64 + rt * 16 + l15) * 64 + kk * 32 + quad * 8);
#pragma unroll
      for (int ct = 0; ct < 4; ++ct)
        bfv[ct] = *(const bf16x8*)(Bs + (wc * 64 + ct * 16 + l15) * 64 + kk * 32 + quad * 8);
#pragma unroll
      for (int rt = 0; rt < 4; ++rt)
#pragma unroll
        for (int ct = 0; ct < 4; ++ct)
          acc[rt][ct] = __builtin_amdgcn_mfma_f32_16x16x32_bf16(af[rt], bfv[ct], acc[rt][ct], 0, 0, 0);
    }
    __syncthreads();  // drains staged loads (after compute) + guards buf reuse
  }

  // epilogue: two 64-row passes through cs (aliases buf 0; last compute = buf 1)
  const int b  = m0 >> 11;       // batch (S_=2048 rows per batch)
  const int s0 = m0 & (S_ - 1);
  __bf16* vtb = qkv + 2 * NTE;   // Vt lives in the V slot
#pragma unroll
  for (int pass = 0; pass < 2; ++pass) {
    __syncthreads();  // prior pass's readers (or main loop) done
    if (wr == pass) {  // waves 0,1 own rows 0-63; waves 2,3 rows 64-127
#pragma unroll
      for (int rt = 0; rt < 4; ++rt)
#pragma unroll
        for (int ct = 0; ct < 4; ++ct)
#pragma unroll
          for (int r = 0; r < 4; ++r)
            cs[(rt * 16 + quad * 4 + r) * 136 + wc * 64 + ct * 16 + l15] =
                (__bf16)acc[rt][ct][r];
    }
    __syncthreads();
    if (sel < 2) {
      __bf16* C = qkv + (size_t)sel * NTE;
      const int cc = tid & 15, rr = tid >> 4;
#pragma unroll
      for (int p2 = 0; p2 < 4; ++p2) {
        const int row = p2 * 16 + rr;
        const bf16x8 v = *(const bf16x8*)(cs + row * 136 + cc * 8);
        *(bf16x8*)(C + (size_t)(m0 + pass * 64 + row) * N + n0s + cc * 8) = v;
      }
    } else {
      // transposed: output row = b*1024 + (n0s + e_loc), cols = s
      const int e_loc = tid >> 1, sh = (tid & 1) * 32;
      __bf16* dst = vtb + (size_t)(b * 1024 + n0s + e_loc) * S_ + s0 + pass * 64 + sh;
#pragma unroll
      for (int p2 = 0; p2 < 4; ++p2) {
        bf16x8 v;
#pragma unroll
        for (int j = 0; j < 8; ++j)
          v[j] = cs[(sh + p2 * 8 + j) * 136 + e_loc];
        *(bf16x8*)(dst + p2 * 8) = v;
      }
    }
  }
}

// ---------------- O GEMM: 128x128 tiles, 4 waves x acc[4][4], 2-phase -------
// Grid 256 = exactly 1 block/CU (no tail). LDS 64KB dbuf. XCD 2D swizzle
// (8m x 4n region per XCD).
__global__ __launch_bounds__(256) void o_gemm(const __bf16* __restrict__ cb,
                                              const __bf16* __restrict__ wo,
                                              float* __restrict__ out) {
  __shared__ __align__(16) char smem[65536];   // 2 x (As 16K + Bs 16K)
  const int lin = blockIdx.y * 8 + blockIdx.x;   // 0..255
  const int xcd = lin & 7, slot = lin >> 3;      // slot 0..31
  const int mi = xcd >> 1, ni = xcd & 1;
  const int mB = mi * 8 + (slot >> 2);           // 0..31
  const int nB = ni * 4 + (slot & 3);            // 0..7
  const int m0 = mB * 128, n0 = nB * 128;
  constexpr int K = D_, N = D_;
  const int tid  = threadIdx.x, lane = tid & 63, wave = tid >> 6;  // 0..3
  const int l15  = lane & 15,   quad = lane >> 4;
  const int wr   = wave >> 1,   wc   = wave & 1;
  const int ebase = wave * 2048 + lane * 8;

  f32x4 acc[4][4] = {};
  {
    __bf16* As = (__bf16*)(smem);
    __bf16* Bs = (__bf16*)(smem + 16384);
#pragma unroll
    for (int i = 0; i < 4; ++i) {
      const int e = ebase + i * 512;
      const int row = e >> 6, col = e & 63;
      async16(cb + (size_t)(m0 + row) * K + col, As + (wave * 4 + i) * 512);
      async16(wo + (size_t)(n0 + row) * K + col, Bs + (wave * 4 + i) * 512);
    }
  }
  __syncthreads();

  for (int t = 0; t < K / 64; ++t) {
    const int cur = t & 1;
    if (t + 1 < K / 64) {
      const int k0 = (t + 1) * 64;
      __bf16* As = (__bf16*)(smem + (cur ^ 1) * 32768);
      __bf16* Bs = (__bf16*)(smem + (cur ^ 1) * 32768 + 16384);
#pragma unroll
      for (int i = 0; i < 4; ++i) {
        const int e = ebase + i * 512;
        const int row = e >> 6, col = e & 63;
        async16(cb + (size_t)(m0 + row) * K + k0 + col, As + (wave * 4 + i) * 512);
        async16(wo + (size_t)(n0 + row) * K + k0 + col, Bs + (wave * 4 + i) * 512);
      }
    }
    const __bf16* As = (const __bf16*)(smem + cur * 32768);
    const __bf16* Bs = (const __bf16*)(smem + cur * 32768 + 16384);
#pragma unroll
    for (int kk = 0; kk < 2; ++kk) {
      bf16x8 af[4], bfv[4];
#pragma unroll
      for (int rt = 0; rt < 4; ++rt)
        af[rt] = *(const bf16x8*)(As + (wr * 64 + rt * 16 + l15) * 64 + kk * 32 + quad * 8);
#pragma unroll
      for (int ct = 0; ct < 4; ++ct)
        bfv[ct] = *(const bf16x8*)(Bs + (wc * 64 + ct * 16 + l15) * 64 + kk * 32 + quad * 8);
#pragma unroll
      for (int rt = 0; rt < 4; ++rt)
#pragma unroll
        for (int ct = 0; ct < 4; ++ct)
          acc[rt][ct] = __builtin_amdgcn_mfma_f32_16x16x32_bf16(af[rt], bfv[ct], acc[rt][ct], 0, 0, 0);
    }
    __syncthreads();
  }
#pragma unroll
  for (int rt = 0; rt < 4; ++rt)
#pragma unroll
    for (int ct = 0; ct < 4; ++ct)
#pragma unroll
      for (int r = 0; r < 4; ++r) {
        const int row = m0 + wr * 64 + rt * 16 + quad * 4 + r;
        const int col = n0 + wc * 64 + ct * 16 + l15;
        out[(size_t)row * N + col] = acc[rt][ct][r];
      }
}

// ---------------- flash attention: single barrier per KV tile ---------------
// r2 config (8 waves x 16 q, 128-key tiles) + single-barrier dbuf (r8).
// S^T = K·Q^T: lane holds P[q=l15][32 keys]; in-register P via cvt_pk +
// permlane32/16_swap; row-sum l via ones-MFMA; max-reduce via __shfl_xor;
// defer-max (THR=8, exp2 domain). No XCD swizzle (r5: L2-fit, m160).
__global__ __launch_bounds__(512, 4) void attn2(const __bf16* __restrict__ Q,
                                                const __bf16* __restrict__ K,
                                                const __bf16* __restrict__ Vt,
                                                const float* __restrict__ mask,
                                                __bf16* __restrict__ O) {
  constexpr int LKT = 72, LVT = 136;
  __shared__ __align__(16) __bf16 kt[2][128 * LKT];   // 2 x 18432 B
  __shared__ __align__(16) __bf16 vt[2][64 * LVT];    // 2 x 17408 B
  __shared__ __align__(16) float  mfull[S_];          // 8192 B (pre-scaled by log2e)

  const int tid  = threadIdx.x, lane = tid & 63, wave = tid >> 6;
  const int l15  = lane & 15,   quad = lane >> 4;
  const int b = blockIdx.z, h = blockIdx.y, q0 = blockIdx.x * 128;
  const size_t base   = (size_t)b * S_ * D_ + h * HD_;
  const size_t vtbase = (size_t)(b * H_ + h) * HD_ * S_;
  const int qw = q0 + wave * 16;
  constexpr float LOG2E = 1.44269504088896340736f;
  constexpr float SC    = 0.125f * LOG2E;          // 1/sqrt(HD) * log2(e)
  constexpr int  NT     = S_ / 128;

  // per-thread staging slots (2 x 16B each for K and V tiles)
  const int idx0 = tid,        kr0 = idx0 >> 3, kc0 = (idx0 & 7) * 8;
  const int idx1 = 512 + tid,  kr1 = idx1 >> 3, kc1 = (idx1 & 7) * 8;
  const int vr0 = idx0 >> 4, vc0 = (idx0 & 15) * 8;
  const int vr1 = idx1 >> 4, vc1 = (idx1 & 15) * 8;

  // Q fragments (B-operand: n=l15 -> q row, k = kb*32+quad*8+j)
  bf16x8 qf[2];
#pragma unroll
  for (int kb = 0; kb < 2; ++kb)
    qf[kb] = *(const bf16x8*)(Q + base + (size_t)(qw + l15) * D_ + kb * 32 + quad * 8);

  bf16x8 ones;
#pragma unroll
  for (int j = 0; j < 8; ++j) ones[j] = (__bf16)1.0f;

  float m_run = -1e30f;
  f32x4 oacc[4] = {};
  f32x4 lacc   = {};

  // prologue: mask table + tile 0 -> buf 0 + issue tile 1 loads
  bf16x8 rk0, rk1, rv0, rv1;
  rk0 = *(const bf16x8*)(K + base + (size_t)kr0 * D_ + kc0);
  rk1 = *(const bf16x8*)(K + base + (size_t)kr1 * D_ + kc1);
  rv0 = *(const bf16x8*)(Vt + vtbase + (size_t)vr0 * S_ + vc0);
  rv1 = *(const bf16x8*)(Vt + vtbase + (size_t)vr1 * S_ + vc1);
#pragma unroll
  for (int i = 0; i < S_ / 512; ++i)
    mfull[i * 512 + tid] = mask[(size_t)b * S_ + i * 512 + tid] * LOG2E;
  *(bf16x8*)(&kt[0][kr0 * LKT + kc0]) = rk0;
  *(bf16x8*)(&kt[0][kr1 * LKT + kc1]) = rk1;
  *(bf16x8*)(&vt[0][vr0 * LVT + vc0]) = rv0;
  *(bf16x8*)(&vt[0][vr1 * LVT + vc1]) = rv1;
  if (NT > 1) {  // issue tile 1 loads (land before their ds_write in iter 0)
    rk0 = *(const bf16x8*)(K + base + (size_t)(128 + kr0) * D_ + kc0);
    rk1 = *(const bf16x8*)(K + base + (size_t)(128 + kr1) * D_ + kc1);
    rv0 = *(const bf16x8*)(Vt + vtbase + (size_t)vr0 * S_ + 128 + vc0);
    rv1 = *(const bf16x8*)(Vt + vtbase + (size_t)vr1 * S_ + 128 + vc1);
  }
  __syncthreads();

  for (int t = 0; t < NT; ++t) {
    const int cur = t & 1;
    const int t0  = t * 128;
    const __bf16* ktb = &kt[cur][0];
    const __bf16* vtb = &vt[cur][0];

    // write staged tile t+1 into buf[cur^1] (race-free: barrier ended iter t-1)
    if (t + 1 < NT) {
      const int nxt = cur ^ 1;
      *(bf16x8*)(&kt[nxt][kr0 * LKT + kc0]) = rk0;
      *(bf16x8*)(&kt[nxt][kr1 * LKT + kc1]) = rk1;
      *(bf16x8*)(&vt[nxt][vr0 * LVT + vc0]) = rv0;
      *(bf16x8*)(&vt[nxt][vr1 * LVT + vc1]) = rv1;
    }
    // issue tile t+2 global loads (full-tile latency hiding)
    if (t + 2 < NT) {
      const int tn = t0 + 256;
      rk0 = *(const bf16x8*)(K + base + (size_t)(tn + kr0) * D_ + kc0);
      rk1 = *(const bf16x8*)(K + base + (size_t)(tn + kr1) * D_ + kc1);
      rv0 = *(const bf16x8*)(Vt + vtbase + (size_t)vr0 * S_ + tn + vc0);
      rv1 = *(const bf16x8*)(Vt + vtbase + (size_t)vr1 * S_ + tn + vc1);
    }

    // S^T tile: D[m=key][n=q]; lane (l15,quad): key = kti*16+quad*4+r, q = l15
    f32x4 sacc[8] = {};
    __builtin_amdgcn_s_setprio(1);
#pragma unroll
    for (int kti = 0; kti < 8; ++kti) {
      const __bf16* kr = ktb + (kti * 16 + l15) * LKT + quad * 8;
      const bf16x8 a0 = *(const bf16x8*)(kr);
      const bf16x8 a1 = *(const bf16x8*)(kr + 32);
      sacc[kti] = __builtin_amdgcn_mfma_f32_16x16x32_bf16(a0, qf[0], sacc[kti], 0, 0, 0);
      sacc[kti] = __builtin_amdgcn_mfma_f32_16x16x32_bf16(a1, qf[1], sacc[kti], 0, 0, 0);
    }
    __builtin_amdgcn_s_setprio(0);

    // scale (exp2 domain) + mask, running max with 4 independent chains
    f32x4 tm4;
#pragma unroll
    for (int r = 0; r < 4; ++r) tm4[r] = -1e30f;
#pragma unroll
    for (int kti = 0; kti < 8; ++kti) {
      const f32x4 mv = *(const f32x4*)(mfull + t0 + kti * 16 + quad * 4);
#pragma unroll
      for (int r = 0; r < 4; ++r) {
        sacc[kti][r] = sacc[kti][r] * SC + mv[r];
        tm4[r] = fmaxf(tm4[r], sacc[kti][r]);
      }
    }
    float tm = fmaxf(fmaxf(tm4[0], tm4[1]), fmaxf(tm4[2], tm4[3]));
    tm = fmaxf(tm, __shfl_xor(tm, 16));
    tm = fmaxf(tm, __shfl_xor(tm, 32));

    // defer-max (T13): only rescale when tile max grows past THR=8 (p <= 2^8)
    if (!__all(tm <= m_run + 8.f)) {
      const float mnew  = fmaxf(m_run, tm);
      const float alpha = __builtin_amdgcn_exp2f(m_run - mnew);
      m_run = mnew;
#pragma unroll
      for (int r = 0; r < 4; ++r) {
        const float aR = __shfl(alpha, quad * 4 + r);
        lacc[r] *= aR;
#pragma unroll
        for (int nt = 0; nt < 4; ++nt) oacc[nt][r] *= aR;
      }
    }

    // exp2 + pack + permlane-redistribute + PV + row-sum, per kb (32 keys each)
#pragma unroll
    for (int kb = 0; kb < 4; ++kb) {
      unsigned dd[2][2];
#pragma unroll
      for (int kk = 0; kk < 2; ++kk) {
        const int kti = 2 * kb + kk;
        float p[4];
#pragma unroll
        for (int r = 0; r < 4; ++r)
          p[r] = __builtin_amdgcn_exp2f(sacc[kti][r] - m_run);
        dd[kk][0] = cvt_pk_bf16(p[0], p[1]);
        dd[kk][1] = cvt_pk_bf16(p[2], p[3]);
      }
      // quad shuffle: rows [A0,A1,A2,A3],[B0,B1,B2,B3] -> [A0,A2,B0,B2],[A1,A3,B1,B3]
      unsigned a0 = dd[0][0], b0 = dd[1][0], a1 = dd[0][1], b1 = dd[1][1];
      asm("v_permlane32_swap_b32 %0, %1" : "+v"(a0), "+v"(b0));
      asm("v_permlane16_swap_b32 %0, %1" : "+v"(a0), "+v"(b0));
      asm("v_permlane32_swap_b32 %0, %1" : "+v"(a1), "+v"(b1));
      asm("v_permlane16_swap_b32 %0, %1" : "+v"(a1), "+v"(b1));
      union { unsigned u[4]; bf16x8 v; } pw;
      pw.u[0] = a0; pw.u[1] = a1; pw.u[2] = b0; pw.u[3] = b1;
      const bf16x8 pa = pw.v;  // A[q=l15][key = kb*32 + quad*8 + j]
      __builtin_amdgcn_s_setprio(1);
      lacc = __builtin_amdgcn_mfma_f32_16x16x32_bf16(pa, ones, lacc, 0, 0, 0);
#pragma unroll
      for (int nt = 0; nt < 4; ++nt) {
        const bf16x8 vf = *(const bf16x8*)(vtb + (nt * 16 + l15) * LVT + kb * 32 + quad * 8);
        oacc[nt] = __builtin_amdgcn_mfma_f32_16x16x32_bf16(pa, vf, oacc[nt], 0, 0, 0);
      }
      __builtin_amdgcn_s_setprio(0);
    }

    __syncthreads();  // single barrier: ds_writes visible + buf reuse guarded
  }

  // epilogue: divide by l (already in row layout via ones-MFMA), store ctx
#pragma unroll
  for (int r = 0; r < 4; ++r) {
    const float inv = 1.0f / lacc[r];
    const int row = qw + quad * 4 + r;
#pragma unroll
    for (int nt = 0; nt < 4; ++nt)
      O[base + (size_t)row * D_ + nt * 16 + l15] = (__bf16)(oacc[nt][r] * inv);
  }
}

extern "C" void kernel_launch(void* const* d_in, const int* in_sizes, int n_in,
                              void* d_out, int out_size, void* d_ws, size_t ws_size,
                              hipStream_t stream) {
  const float* x    = (const float*)d_in[0];
  const float* mask = (const float*)d_in[1];
  const float* Wq   = (const float*)d_in[2];
  const float* Wk   = (const float*)d_in[3];
  const float* Wv   = (const float*)d_in[4];
  const float* Wo   = (const float*)d_in[5];

  char* ws = (char*)d_ws;
  const size_t MB = 1ull << 20;
  const size_t NT = (size_t)B_ * S_ * D_;  // 4M elems, 8 MB bf16
  __bf16* xb  = (__bf16*)(ws);             // 8 MB; freed after qkv_gemm -> reused as cb
  __bf16* wqb = (__bf16*)(ws + 8 * MB);    // wq/wk/wv contiguous = packed [3072][1024]
  __bf16* wkb = (__bf16*)(ws + 10 * MB);
  __bf16* wvb = (__bf16*)(ws + 12 * MB);
  __bf16* wob = (__bf16*)(ws + 14 * MB);
  __bf16* qkv = (__bf16*)(ws + 16 * MB);   // 24 MB: Q, K, Vt
  __bf16* qb  = qkv;
  __bf16* kb  = qkv + NT;
  __bf16* vtb = qkv + 2 * NT;  // qkv_gemm sel==2 writes V pre-transposed here
  __bf16* cb  = xb;            // x consumed by qkv_gemm before attn writes ctx

  cvt_all<<<dim3(1024, 5), 256, 0, stream>>>(x, Wq, Wk, Wv, Wo, xb, wqb, wkb, wvb, wob);
  qkv_gemm<<<dim3(24, 32), 256, 0, stream>>>(xb, wqb, qkv);
  attn2<<<dim3(S_ / 128, H_, B_), 512, 0, stream>>>(qb, kb, vtb, mask, cb);
  o_gemm<<<dim3(8, 32), 256, 0, stream>>>(cb, wob, (float*)d_out);
}

// Round 11
// 196.961 us; speedup vs baseline: 1.1799x; 1.0093x over previous
//
#include <hip/hip_runtime.h>
#include <hip/hip_bf16.h>
#include <cstdint>
#include <cstddef>

// MHA B=2,S=2048,D=1024,H=16,HD=64.
// cvt(fp32->bf16) -> fused QKV GEMM (packed [3072][1024] weights, 256x256
// tiles -> 192 blocks = ONE scheduling round, 2-phase dbuf (128KB LDS),
// 8 waves x acc[8][4], XCD 2D swizzle, 4-pass LDS-bounce epilogue; V written
// pre-transposed) -> flash attn (unchanged r8 structure) -> O GEMM (64x128
// tiles, 512 blocks = 2/CU, 2-phase dbuf 48KB, XCD 2D swizzle).
//
// r6 lesson: NEVER feed two copies of the SAME value to a "+v","+v" permlane
// swap asm — compiler CSEs them into one VGPR and the swap self-permutes.
// r7: GEMM wave-count null. r8: 2-phase pipeline = -8.5us. r9: acc ratio null.
// r10 lesson: prologue staged B into buf1's A offset (65536) instead of buf0's
// B offset (32768) -> K-step 0 read uninitialized LDS -> NaN. Also: keep
// global_load_lds LDS dest EXPLICITLY wave-uniform (base + wave*512), never
// tid-dependent — don't rely on readfirstlane reconstruction.

#define B_  2
#define S_  2048
#define D_  1024
#define H_  16
#define HD_ 64

typedef __bf16 bf16x8 __attribute__((ext_vector_type(8)));
typedef __bf16 bf16x4 __attribute__((ext_vector_type(4)));
typedef float  f32x4  __attribute__((ext_vector_type(4)));

// ---- async global->LDS, 16B per lane. LDS dest must be wave-uniform base;
// HW adds lane*16 (guide §5 m97/m104). AS(3) ptr = low 32 bits of flat addr.
__device__ __forceinline__ void async16(const __bf16* g, const __bf16* l) {
  __builtin_amdgcn_global_load_lds(
      (const __attribute__((address_space(1))) void*)(uintptr_t)g,
      (__attribute__((address_space(3))) void*)(uint32_t)(uintptr_t)l,
      16, 0, 0);
}

// v_cvt_pk_bf16_f32: dst.lo16 = bf16(lo), dst.hi16 = bf16(hi)
__device__ __forceinline__ unsigned cvt_pk_bf16(float lo, float hi) {
  unsigned r;
  asm("v_cvt_pk_bf16_f32 %0, %1, %2" : "=v"(r) : "v"(lo), "v"(hi));
  return r;
}

// ---------------- fp32 -> bf16 convert (x + 4 weights) ----------------
__global__ __launch_bounds__(256) void cvt_all(const float* __restrict__ x,
    const float* __restrict__ wq, const float* __restrict__ wk,
    const float* __restrict__ wv, const float* __restrict__ wo,
    __bf16* __restrict__ xb, __bf16* __restrict__ wqb, __bf16* __restrict__ wkb,
    __bf16* __restrict__ wvb, __bf16* __restrict__ wob) {
  const int sel = blockIdx.y;
  const float* src; __bf16* dst; int n;
  if      (sel == 0) { src = x;  dst = xb;  n = B_ * S_ * D_; }
  else if (sel == 1) { src = wq; dst = wqb; n = D_ * D_; }
  else if (sel == 2) { src = wk; dst = wkb; n = D_ * D_; }
  else if (sel == 3) { src = wv; dst = wvb; n = D_ * D_; }
  else               { src = wo; dst = wob; n = D_ * D_; }
  for (int i = blockIdx.x * 256 + threadIdx.x; i * 4 < n; i += gridDim.x * 256) {
    const float4 v = *(const float4*)(src + (size_t)i * 4);
    bf16x4 o;
    o[0] = (__bf16)v.x; o[1] = (__bf16)v.y; o[2] = (__bf16)v.z; o[3] = (__bf16)v.w;
    *(bf16x4*)(dst + (size_t)i * 4) = o;
  }
}

// ---------------- fused QKV GEMM: 256x256 tiles, packed weights -------------
// Grid 16m x 12n = 192 blocks (one scheduling round, no tail). 512 thr /
// 8 waves (2M x 4N), per-wave C = 128x64 (acc[8][4]). 2-phase dbuf: stage
// K-step t+1 into buf^1 before computing t; one barrier per K-step. LDS
// 128KB (2 x (A 32K + B 32K)). XCD swizzle: each XCD gets an 8m x 3n region.
// Epilogue: 4 x 64-row passes through cs[64][264] (aliases smem).
// sel 0/1 (Q,K): bf16x8 row-major stores. sel 2 (V): transposed -> Vt.
__global__ __launch_bounds__(512, 1) void qkv_gemm(const __bf16* __restrict__ xb,
                                                   const __bf16* __restrict__ wqkv,
                                                   __bf16* __restrict__ qkv) {
  __shared__ __align__(16) char smem[131072];  // 2 x (As 32K + Bs 32K)
  __bf16* cs = (__bf16*)smem;                  // 64*264*2B = 33792; post-loop

  const int lin = blockIdx.y * 12 + blockIdx.x;   // 0..191
  const int xcd = lin & 7, slot = lin >> 3;       // slot 0..23
  const int mB = (xcd >> 2) * 8 + slot / 3;       // 0..15
  const int nB = (xcd & 3) * 3 + slot % 3;        // 0..11
  const int m0  = mB * 256;
  const int sel = nB >> 2;                        // 0..2 -> Q,K,V
  const int n0s = (nB & 3) * 256;                 // col offset within sel
  const int n0w = nB * 256;                       // row offset in packed weights
  constexpr int K = D_, N = D_;
  constexpr size_t NTE = (size_t)B_ * S_ * D_;

  const int tid  = threadIdx.x, lane = tid & 63, wave = tid >> 6;  // 0..7
  const int l15  = lane & 15,   quad = lane >> 4;
  const int wr   = wave >> 2,   wc   = wave & 3;   // 2 x 4 wave grid
  const int row8 = tid >> 3, col8 = (tid & 7) * 8; // global-side staging coords

  f32x4 acc[8][4] = {};

  // prologue: stage K-step 0 into buf 0 (4 A chunks + 4 B chunks per thread)
  // LDS dest = wave-uniform base (i*4096 + wave*512); HW adds lane*16B.
  {
    __bf16* As = (__bf16*)(smem);
    __bf16* Bs = (__bf16*)(smem + 32768);   // r10 bug was 65536 (buf1's A!)
#pragma unroll
    for (int i = 0; i < 4; ++i) {
      async16(xb   + (size_t)(m0  + i * 64 + row8) * K + col8, As + i * 4096 + wave * 512);
      async16(wqkv + (size_t)(n0w + i * 64 + row8) * K + col8, Bs + i * 4096 + wave * 512);
    }
  }
  __syncthreads();

  for (int t = 0; t < K / 64; ++t) {
    const int cur = t & 1;
    if (t + 1 < K / 64) {
      const int k0 = (t + 1) * 64;
      __bf16* As = (__bf16*)(smem + (cur ^ 1) * 65536);
      __bf16* Bs = (__bf16*)(smem + (cur ^ 1) * 65536 + 32768);
#pragma unroll
      for (int i = 0; i < 4; ++i) {
        async16(xb   + (size_t)(m0  + i * 64 + row8) * K + k0 + col8, As + i * 4096 + wave * 512);
        async16(wqkv + (size_t)(n0w + i * 64 + row8) * K + k0 + col8, Bs + i * 4096 + wave * 512);
      }
    }
    const __bf16* As = (const __bf16*)(smem + cur * 65536);
    const __bf16* Bs = (const __bf16*)(smem + cur * 65536 + 32768);
#pragma unroll
    for (int kk = 0; kk < 2; ++kk) {
      bf16x8 bfv[4];
#pragma unroll
      for (int ct = 0; ct < 4; ++ct)
        bfv[ct] = *(const bf16x8*)(Bs + (wc * 64 + ct * 16 + l15) * 64 + kk * 32 + quad * 8);
#pragma unroll
      for (int rt = 0; rt < 8; ++rt) {
        const bf16x8 af = *(const bf16x8*)(As + (wr * 128 + rt * 16 + l15) * 64 + kk * 32 + quad * 8);
#pragma unroll
        for (int ct = 0; ct < 4; ++ct)
          acc[rt][ct] = __builtin_amdgcn_mfma_f32_16x16x32_bf16(af, bfv[ct], acc[rt][ct], 0, 0, 0);
      }
    }
    __syncthreads();  // drains staged loads (after compute) + guards buf reuse
  }

  // epilogue: four 64-row passes through cs[64][264]
  const int b  = m0 >> 11;       // batch (S_=2048 rows per batch)
  const int s0 = m0 & (S_ - 1);
  __bf16* vtb = qkv + 2 * NTE;   // Vt lives in the V slot
#pragma unroll
  for (int pass = 0; pass < 4; ++pass) {
    __syncthreads();  // prior pass's readers (or main loop) done
    if (wr == (pass >> 1)) {  // owning waves: rows pass*64 .. pass*64+63
      const int rtb = (pass & 1) * 4;
#pragma unroll
      for (int rt = 0; rt < 4; ++rt)
#pragma unroll
        for (int ct = 0; ct < 4; ++ct)
#pragma unroll
          for (int r = 0; r < 4; ++r)
            cs[(rt * 16 + quad * 4 + r) * 264 + wc * 64 + ct * 16 + l15] =
                (__bf16)acc[rtb + rt][ct][r];
    }
    __syncthreads();
    if (sel < 2) {
      __bf16* C = qkv + (size_t)sel * NTE;
      const int rr = tid >> 3, cb = (tid & 7) * 32;  // 64 rows x 8 col-groups
#pragma unroll
      for (int j2 = 0; j2 < 4; ++j2) {
        const bf16x8 v = *(const bf16x8*)(cs + rr * 264 + cb + j2 * 8);
        *(bf16x8*)(C + (size_t)(m0 + pass * 64 + rr) * N + n0s + cb + j2 * 8) = v;
      }
    } else {
      // transposed: output row = b*1024 + (n0s + e_loc), cols = s
      const int e_loc = tid >> 1, sh = (tid & 1) * 32;  // 256 e x 2 s-halves
      __bf16* dst = vtb + (size_t)(b * 1024 + n0s + e_loc) * S_ + s0 + pass * 64 + sh;
#pragma unroll
      for (int j2 = 0; j2 < 4; ++j2) {
        bf16x8 v;
#pragma unroll
        for (int j = 0; j < 8; ++j)
          v[j] = cs[(sh + j2 * 8 + j) * 264 + e_loc];
        *(bf16x8*)(dst + j2 * 8) = v;
      }
    }
  }
}

// ---------------- O GEMM: 64x128 tiles, 512 blocks = 2/CU, 2-phase ----------
// 256 thr / 4 waves (2x2), per-wave 32x64 (acc[2][4]). LDS 48KB dbuf ->
// 3 blocks/CU capacity, grid 2/CU. XCD 2D swizzle (16m x 4n per XCD).
__global__ __launch_bounds__(256) void o_gemm(const __bf16* __restrict__ cb,
                                              const __bf16* __restrict__ wo,
                                              float* __restrict__ out) {
  __shared__ __align__(16) char smem[49152];   // 2 x (As 8K + Bs 16K)
  const int lin = blockIdx.y * 8 + blockIdx.x;   // 0..511
  const int xcd = lin & 7, slot = lin >> 3;      // slot 0..63
  const int mi = xcd >> 1, ni = xcd & 1;
  const int mB = mi * 16 + (slot >> 2);          // 0..63
  const int nB = ni * 4  + (slot & 3);           // 0..7
  const int m0 = mB * 64, n0 = nB * 128;
  constexpr int K = D_, N = D_;
  const int tid  = threadIdx.x, lane = tid & 63, wave = tid >> 6;  // 0..3
  const int l15  = lane & 15,   quad = lane >> 4;
  const int wr   = wave >> 1,   wc   = wave & 1;
  const int row8 = tid >> 3, col8 = (tid & 7) * 8;  // global-side staging coords

  f32x4 acc[2][4] = {};
  {
    __bf16* As = (__bf16*)(smem);
    __bf16* Bs = (__bf16*)(smem + 8192);
#pragma unroll
    for (int i = 0; i < 2; ++i)
      async16(cb + (size_t)(m0 + i * 32 + row8) * K + col8, As + i * 2048 + wave * 512);
#pragma unroll
    for (int i = 0; i < 4; ++i)
      async16(wo + (size_t)(n0 + i * 32 + row8) * K + col8, Bs + i * 2048 + wave * 512);
  }
  __syncthreads();

  for (int t = 0; t < K / 64; ++t) {
    const int cur = t & 1;
    if (t + 1 < K / 64) {
      const int k0 = (t + 1) * 64;
      __bf16* As = (__bf16*)(smem + (cur ^ 1) * 24576);
      __bf16* Bs = (__bf16*)(smem + (cur ^ 1) * 24576 + 8192);
#pragma unroll
      for (int i = 0; i < 2; ++i)
        async16(cb + (size_t)(m0 + i * 32 + row8) * K + k0 + col8, As + i * 2048 + wave * 512);
#pragma unroll
      for (int i = 0; i < 4; ++i)
        async16(wo + (size_t)(n0 + i * 32 + row8) * K + k0 + col8, Bs + i * 2048 + wave * 512);
    }
    const __bf16* As = (const __bf16*)(smem + cur * 24576);
    const __bf16* Bs = (const __bf16*)(smem + cur * 24576 + 8192);
#pragma unroll
    for (int kk = 0; kk < 2; ++kk) {
      bf16x8 af[2], bfv[4];
#pragma unroll
      for (int rt = 0; rt < 2; ++rt)
        af[rt] = *(const bf16x8*)(As + (wr * 32 + rt * 16 + l15) * 64 + kk * 32 + quad * 8);
#pragma unroll
      for (int ct = 0; ct < 4; ++ct)
        bfv[ct] = *(const bf16x8*)(Bs + (wc * 64 + ct * 16 + l15) * 64 + kk * 32 + quad * 8);
#pragma unroll
      for (int rt = 0; rt < 2; ++rt)
#pragma unroll
        for (int ct = 0; ct < 4; ++ct)
          acc[rt][ct] = __builtin_amdgcn_mfma_f32_16x16x32_bf16(af[rt], bfv[ct], acc[rt][ct], 0, 0, 0);
    }
    __syncthreads();
  }
#pragma unroll
  for (int rt = 0; rt < 2; ++rt)
#pragma unroll
    for (int ct = 0; ct < 4; ++ct)
#pragma unroll
      for (int r = 0; r < 4; ++r) {
        const int row = m0 + wr * 32 + rt * 16 + quad * 4 + r;
        const int col = n0 + wc * 64 + ct * 16 + l15;
        out[(size_t)row * N + col] = acc[rt][ct][r];
      }
}

// ---------------- flash attention: single barrier per KV tile (r8) ----------
// 8 waves x 16 q, 128-key tiles. S^T = K·Q^T: lane holds P[q=l15][32 keys];
// in-register P via cvt_pk + permlane32/16_swap; row-sum l via ones-MFMA;
// max-reduce via __shfl_xor; defer-max (THR=8, exp2 domain); T14 reg-prefetch
// + dbuf K/V, single barrier/tile. No XCD swizzle (r5: L2-fit, m160).
__global__ __launch_bounds__(512, 4) void attn2(const __bf16* __restrict__ Q,
                                                const __bf16* __restrict__ K,
                                                const __bf16* __restrict__ Vt,
                                                const float* __restrict__ mask,
                                                __bf16* __restrict__ O) {
  constexpr int LKT = 72, LVT = 136;
  __shared__ __align__(16) __bf16 kt[2][128 * LKT];   // 2 x 18432 B
  __shared__ __align__(16) __bf16 vt[2][64 * LVT];    // 2 x 17408 B
  __shared__ __align__(16) float  mfull[S_];          // 8192 B (pre-scaled by log2e)

  const int tid  = threadIdx.x, lane = tid & 63, wave = tid >> 6;
  const int l15  = lane & 15,   quad = lane >> 4;
  const int b = blockIdx.z, h = blockIdx.y, q0 = blockIdx.x * 128;
  const size_t base   = (size_t)b * S_ * D_ + h * HD_;
  const size_t vtbase = (size_t)(b * H_ + h) * HD_ * S_;
  const int qw = q0 + wave * 16;
  constexpr float LOG2E = 1.44269504088896340736f;
  constexpr float SC    = 0.125f * LOG2E;          // 1/sqrt(HD) * log2(e)
  constexpr int  NT     = S_ / 128;

  // per-thread staging slots (2 x 16B each for K and V tiles)
  const int idx0 = tid,        kr0 = idx0 >> 3, kc0 = (idx0 & 7) * 8;
  const int idx1 = 512 + tid,  kr1 = idx1 >> 3, kc1 = (idx1 & 7) * 8;
  const int vr0 = idx0 >> 4, vc0 = (idx0 & 15) * 8;
  const int vr1 = idx1 >> 4, vc1 = (idx1 & 15) * 8;

  // Q fragments (B-operand: n=l15 -> q row, k = kb*32+quad*8+j)
  bf16x8 qf[2];
#pragma unroll
  for (int kb = 0; kb < 2; ++kb)
    qf[kb] = *(const bf16x8*)(Q + base + (size_t)(qw + l15) * D_ + kb * 32 + quad * 8);

  bf16x8 ones;
#pragma unroll
  for (int j = 0; j < 8; ++j) ones[j] = (__bf16)1.0f;

  float m_run = -1e30f;
  f32x4 oacc[4] = {};
  f32x4 lacc   = {};

  // prologue: mask table + tile 0 -> buf 0 + issue tile 1 loads
  bf16x8 rk0, rk1, rv0, rv1;
  rk0 = *(const bf16x8*)(K + base + (size_t)kr0 * D_ + kc0);
  rk1 = *(const bf16x8*)(K + base + (size_t)kr1 * D_ + kc1);
  rv0 = *(const bf16x8*)(Vt + vtbase + (size_t)vr0 * S_ + vc0);
  rv1 = *(const bf16x8*)(Vt + vtbase + (size_t)vr1 * S_ + vc1);
#pragma unroll
  for (int i = 0; i < S_ / 512; ++i)
    mfull[i * 512 + tid] = mask[(size_t)b * S_ + i * 512 + tid] * LOG2E;
  *(bf16x8*)(&kt[0][kr0 * LKT + kc0]) = rk0;
  *(bf16x8*)(&kt[0][kr1 * LKT + kc1]) = rk1;
  *(bf16x8*)(&vt[0][vr0 * LVT + vc0]) = rv0;
  *(bf16x8*)(&vt[0][vr1 * LVT + vc1]) = rv1;
  if (NT > 1) {  // issue tile 1 loads (land before their ds_write in iter 0)
    rk0 = *(const bf16x8*)(K + base + (size_t)(128 + kr0) * D_ + kc0);
    rk1 = *(const bf16x8*)(K + base + (size_t)(128 + kr1) * D_ + kc1);
    rv0 = *(const bf16x8*)(Vt + vtbase + (size_t)vr0 * S_ + 128 + vc0);
    rv1 = *(const bf16x8*)(Vt + vtbase + (size_t)vr1 * S_ + 128 + vc1);
  }
  __syncthreads();

  for (int t = 0; t < NT; ++t) {
    const int cur = t & 1;
    const int t0  = t * 128;
    const __bf16* ktb = &kt[cur][0];
    const __bf16* vtb = &vt[cur][0];

    // write staged tile t+1 into buf[cur^1] (race-free: barrier ended iter t-1)
    if (t + 1 < NT) {
      const int nxt = cur ^ 1;
      *(bf16x8*)(&kt[nxt][kr0 * LKT + kc0]) = rk0;
      *(bf16x8*)(&kt[nxt][kr1 * LKT + kc1]) = rk1;
      *(bf16x8*)(&vt[nxt][vr0 * LVT + vc0]) = rv0;
      *(bf16x8*)(&vt[nxt][vr1 * LVT + vc1]) = rv1;
    }
    // issue tile t+2 global loads (full-tile latency hiding)
    if (t + 2 < NT) {
      const int tn = t0 + 256;
      rk0 = *(const bf16x8*)(K + base + (size_t)(tn + kr0) * D_ + kc0);
      rk1 = *(const bf16x8*)(K + base + (size_t)(tn + kr1) * D_ + kc1);
      rv0 = *(const bf16x8*)(Vt + vtbase + (size_t)vr0 * S_ + tn + vc0);
      rv1 = *(const bf16x8*)(Vt + vtbase + (size_t)vr1 * S_ + tn + vc1);
    }

    // S^T tile: D[m=key][n=q]; lane (l15,quad): key = kti*16+quad*4+r, q = l15
    f32x4 sacc[8] = {};
    __builtin_amdgcn_s_setprio(1);
#pragma unroll
    for (int kti = 0; kti < 8; ++kti) {
      const __bf16* kr = ktb + (kti * 16 + l15) * LKT + quad * 8;
      const bf16x8 a0 = *(const bf16x8*)(kr);
      const bf16x8 a1 = *(const bf16x8*)(kr + 32);
      sacc[kti] = __builtin_amdgcn_mfma_f32_16x16x32_bf16(a0, qf[0], sacc[kti], 0, 0, 0);
      sacc[kti] = __builtin_amdgcn_mfma_f32_16x16x32_bf16(a1, qf[1], sacc[kti], 0, 0, 0);
    }
    __builtin_amdgcn_s_setprio(0);

    // scale (exp2 domain) + mask, running max with 4 independent chains
    f32x4 tm4;
#pragma unroll
    for (int r = 0; r < 4; ++r) tm4[r] = -1e30f;
#pragma unroll
    for (int kti = 0; kti < 8; ++kti) {
      const f32x4 mv = *(const f32x4*)(mfull + t0 + kti * 16 + quad * 4);
#pragma unroll
      for (int r = 0; r < 4; ++r) {
        sacc[kti][r] = sacc[kti][r] * SC + mv[r];
        tm4[r] = fmaxf(tm4[r], sacc[kti][r]);
      }
    }
    float tm = fmaxf(fmaxf(tm4[0], tm4[1]), fmaxf(tm4[2], tm4[3]));
    tm = fmaxf(tm, __shfl_xor(tm, 16));
    tm = fmaxf(tm, __shfl_xor(tm, 32));

    // defer-max (T13): only rescale when tile max grows past THR=8 (p <= 2^8)
    if (!__all(tm <= m_run + 8.f)) {
      const float mnew  = fmaxf(m_run, tm);
      const float alpha = __builtin_amdgcn_exp2f(m_run - mnew);
      m_run = mnew;
#pragma unroll
      for (int r = 0; r < 4; ++r) {
        const float aR = __shfl(alpha, quad * 4 + r);
        lacc[r] *= aR;
#pragma unroll
        for (int nt = 0; nt < 4; ++nt) oacc[nt][r] *= aR;
      }
    }

    // exp2 + pack + permlane-redistribute + PV + row-sum, per kb (32 keys each)
#pragma unroll
    for (int kb = 0; kb < 4; ++kb) {
      unsigned dd[2][2];
#pragma unroll
      for (int kk = 0; kk < 2; ++kk) {
        const int kti = 2 * kb + kk;
        float p[4];
#pragma unroll
        for (int r = 0; r < 4; ++r)
          p[r] = __builtin_amdgcn_exp2f(sacc[kti][r] - m_run);
        dd[kk][0] = cvt_pk_bf16(p[0], p[1]);
        dd[kk][1] = cvt_pk_bf16(p[2], p[3]);
      }
      // quad shuffle: rows [A0,A1,A2,A3],[B0,B1,B2,B3] -> [A0,A2,B0,B2],[A1,A3,B1,B3]
      unsigned a0 = dd[0][0], b0 = dd[1][0], a1 = dd[0][1], b1 = dd[1][1];
      asm("v_permlane32_swap_b32 %0, %1" : "+v"(a0), "+v"(b0));
      asm("v_permlane16_swap_b32 %0, %1" : "+v"(a0), "+v"(b0));
      asm("v_permlane32_swap_b32 %0, %1" : "+v"(a1), "+v"(b1));
      asm("v_permlane16_swap_b32 %0, %1" : "+v"(a1), "+v"(b1));
      union { unsigned u[4]; bf16x8 v; } pw;
      pw.u[0] = a0; pw.u[1] = a1; pw.u[2] = b0; pw.u[3] = b1;
      const bf16x8 pa = pw.v;  // A[q=l15][key = kb*32 + quad*8 + j]
      __builtin_amdgcn_s_setprio(1);
      lacc = __builtin_amdgcn_mfma_f32_16x16x32_bf16(pa, ones, lacc, 0, 0, 0);
#pragma unroll
      for (int nt = 0; nt < 4; ++nt) {
        const bf16x8 vf = *(const bf16x8*)(vtb + (nt * 16 + l15) * LVT + kb * 32 + quad * 8);
        oacc[nt] = __builtin_amdgcn_mfma_f32_16x16x32_bf16(pa, vf, oacc[nt], 0, 0, 0);
      }
      __builtin_amdgcn_s_setprio(0);
    }

    __syncthreads();  // single barrier: ds_writes visible + buf reuse guarded
  }

  // epilogue: divide by l (already in row layout via ones-MFMA), store ctx
#pragma unroll
  for (int r = 0; r < 4; ++r) {
    const float inv = 1.0f / lacc[r];
    const int row = qw + quad * 4 + r;
#pragma unroll
    for (int nt = 0; nt < 4; ++nt)
      O[base + (size_t)row * D_ + nt * 16 + l15] = (__bf16)(oacc[nt][r] * inv);
  }
}

extern "C" void kernel_launch(void* const* d_in, const int* in_sizes, int n_in,
                              void* d_out, int out_size, void* d_ws, size_t ws_size,
                              hipStream_t stream) {
  const float* x    = (const float*)d_in[0];
  const float* mask = (const float*)d_in[1];
  const float* Wq   = (const float*)d_in[2];
  const float* Wk   = (const float*)d_in[3];
  const float* Wv   = (const float*)d_in[4];
  const float* Wo   = (const float*)d_in[5];

  char* ws = (char*)d_ws;
  const size_t MB = 1ull << 20;
  const size_t NT = (size_t)B_ * S_ * D_;  // 4M elems, 8 MB bf16
  __bf16* xb  = (__bf16*)(ws);             // 8 MB; freed after qkv_gemm -> reused as cb
  __bf16* wqb = (__bf16*)(ws + 8 * MB);    // wq/wk/wv contiguous = packed [3072][1024]
  __bf16* wkb = (__bf16*)(ws + 10 * MB);
  __bf16* wvb = (__bf16*)(ws + 12 * MB);
  __bf16* wob = (__bf16*)(ws + 14 * MB);
  __bf16* qkv = (__bf16*)(ws + 16 * MB);   // 24 MB: Q, K, Vt
  __bf16* qb  = qkv;
  __bf16* kb  = qkv + NT;
  __bf16* vtb = qkv + 2 * NT;  // qkv_gemm sel==2 writes V pre-transposed here
  __bf16* cb  = xb;            // x consumed by qkv_gemm before attn writes ctx

  cvt_all<<<dim3(1024, 5), 256, 0, stream>>>(x, Wq, Wk, Wv, Wo, xb, wqb, wkb, wvb, wob);
  qkv_gemm<<<dim3(12, 16), 512, 0, stream>>>(xb, wqb, qkv);
  attn2<<<dim3(S_ / 128, H_, B_), 512, 0, stream>>>(qb, kb, vtb, mask, cb);
  o_gemm<<<dim3(8, 64), 256, 0, stream>>>(cb, wob, (float*)d_out);
}

// Round 12
// 188.727 us; speedup vs baseline: 1.2314x; 1.0436x over previous
//
#include <hip/hip_runtime.h>
#include <hip/hip_bf16.h>
#include <cstdint>
#include <cstddef>

// MHA B=2,S=2048,D=1024,H=16,HD=64.
// cvt(fp32->bf16) -> fused QKV GEMM (256x256 tiles, 2-phase dbuf, T2 LDS
// XOR-swizzle via pre-swizzled GLOBAL source + XOR'd reads; V pre-transposed)
// -> flash attn (r8 structure, unchanged) -> O GEMM (64x128, 2-phase, T2).
//
// r6: never feed two copies of one value to "+v","+v" permlane asm (CSE).
// r7: GEMM wave-count null. r8: 2-phase = -8.5us. r9: acc ratio null.
// r10: prologue buf offset bug -> NaN. r11: 256^2 tile alone null.
// r12 THEORY: unpadded [*][64] bf16 LDS tiles (128B row stride) make every
// fragment read a 16-WAY BANK CONFLICT (row*128/4 = 0 mod 32) -> LDS pipe
// ~3.6x oversubscribed -> all prior GEMM restructures null. Fix = T2/rule#21:
// LDS stays linear (global_load_lds), global source col pre-XOR'd by row&7,
// reads XOR the same -> 2-way (free).

#define B_  2
#define S_  2048
#define D_  1024
#define H_  16
#define HD_ 64

typedef __bf16 bf16x8 __attribute__((ext_vector_type(8)));
typedef __bf16 bf16x4 __attribute__((ext_vector_type(4)));
typedef float  f32x4  __attribute__((ext_vector_type(4)));

// ---- async global->LDS, 16B per lane. LDS dest must be wave-uniform base;
// HW adds lane*16 (guide §5 m97/m104). AS(3) ptr = low 32 bits of flat addr.
__device__ __forceinline__ void async16(const __bf16* g, const __bf16* l) {
  __builtin_amdgcn_global_load_lds(
      (const __attribute__((address_space(1))) void*)(uintptr_t)g,
      (__attribute__((address_space(3))) void*)(uint32_t)(uintptr_t)l,
      16, 0, 0);
}

// v_cvt_pk_bf16_f32: dst.lo16 = bf16(lo), dst.hi16 = bf16(hi)
__device__ __forceinline__ unsigned cvt_pk_bf16(float lo, float hi) {
  unsigned r;
  asm("v_cvt_pk_bf16_f32 %0, %1, %2" : "=v"(r) : "v"(lo), "v"(hi));
  return r;
}

// ---------------- fp32 -> bf16 convert (x + 4 weights) ----------------
__global__ __launch_bounds__(256) void cvt_all(const float* __restrict__ x,
    const float* __restrict__ wq, const float* __restrict__ wk,
    const float* __restrict__ wv, const float* __restrict__ wo,
    __bf16* __restrict__ xb, __bf16* __restrict__ wqb, __bf16* __restrict__ wkb,
    __bf16* __restrict__ wvb, __bf16* __restrict__ wob) {
  const int sel = blockIdx.y;
  const float* src; __bf16* dst; int n;
  if      (sel == 0) { src = x;  dst = xb;  n = B_ * S_ * D_; }
  else if (sel == 1) { src = wq; dst = wqb; n = D_ * D_; }
  else if (sel == 2) { src = wk; dst = wkb; n = D_ * D_; }
  else if (sel == 3) { src = wv; dst = wvb; n = D_ * D_; }
  else               { src = wo; dst = wob; n = D_ * D_; }
  for (int i = blockIdx.x * 256 + threadIdx.x; i * 4 < n; i += gridDim.x * 256) {
    const float4 v = *(const float4*)(src + (size_t)i * 4);
    bf16x4 o;
    o[0] = (__bf16)v.x; o[1] = (__bf16)v.y; o[2] = (__bf16)v.z; o[3] = (__bf16)v.w;
    *(bf16x4*)(dst + (size_t)i * 4) = o;
  }
}

// ---------------- fused QKV GEMM: 256x256 tiles, T2-swizzled LDS ------------
// Grid 16m x 12n = 192 blocks. 512 thr / 8 waves (2M x 4N), acc[8][4].
// 2-phase dbuf, one barrier/K-step. LDS 128KB linear; bank-conflict-free via
// pre-swizzled global source col (col16 ^= row&7) + XOR'd fragment reads.
// XCD swizzle (8m x 3n per XCD). Epilogue: 4 x 64-row LDS-bounce passes.
// sel 0/1 (Q,K): bf16x8 row-major stores. sel 2 (V): transposed -> Vt.
__global__ __launch_bounds__(512, 1) void qkv_gemm(const __bf16* __restrict__ xb,
                                                   const __bf16* __restrict__ wqkv,
                                                   __bf16* __restrict__ qkv) {
  __shared__ __align__(16) char smem[131072];  // 2 x (As 32K + Bs 32K)
  __bf16* cs = (__bf16*)smem;                  // 64*264*2B alias; post-loop

  const int lin = blockIdx.y * 12 + blockIdx.x;   // 0..191
  const int xcd = lin & 7, slot = lin >> 3;       // slot 0..23
  const int mB = (xcd >> 2) * 8 + slot / 3;       // 0..15
  const int nB = (xcd & 3) * 3 + slot % 3;        // 0..11
  const int m0  = mB * 256;
  const int sel = nB >> 2;                        // 0..2 -> Q,K,V
  const int n0s = (nB & 3) * 256;                 // col offset within sel
  const int n0w = nB * 256;                       // row offset in packed weights
  constexpr int K = D_, N = D_;
  constexpr size_t NTE = (size_t)B_ * S_ * D_;

  const int tid  = threadIdx.x, lane = tid & 63, wave = tid >> 6;  // 0..7
  const int l15  = lane & 15,   quad = lane >> 4;
  const int wr   = wave >> 2,   wc   = wave & 3;   // 2 x 4 wave grid
  const int row8 = tid >> 3;                       // global-side staging row
  // T2: swizzled global col — lane's 16B chunk lands at LDS slot (tid&7),
  // which must hold global col slot (tid&7)^(row&7).
  const int colS = (((tid & 7) ^ (row8 & 7)) * 8);
  const int rx   = (l15 & 7) << 3;                 // read-side XOR (elems)

  f32x4 acc[8][4] = {};

  // prologue: stage K-step 0 into buf 0 (wave-uniform LDS dest)
  {
    __bf16* As = (__bf16*)(smem);
    __bf16* Bs = (__bf16*)(smem + 32768);
#pragma unroll
    for (int i = 0; i < 4; ++i) {
      async16(xb   + (size_t)(m0  + i * 64 + row8) * K + colS, As + i * 4096 + wave * 512);
      async16(wqkv + (size_t)(n0w + i * 64 + row8) * K + colS, Bs + i * 4096 + wave * 512);
    }
  }
  __syncthreads();

  for (int t = 0; t < K / 64; ++t) {
    const int cur = t & 1;
    if (t + 1 < K / 64) {
      const int k0 = (t + 1) * 64;
      __bf16* As = (__bf16*)(smem + (cur ^ 1) * 65536);
      __bf16* Bs = (__bf16*)(smem + (cur ^ 1) * 65536 + 32768);
#pragma unroll
      for (int i = 0; i < 4; ++i) {
        async16(xb   + (size_t)(m0  + i * 64 + row8) * K + k0 + colS, As + i * 4096 + wave * 512);
        async16(wqkv + (size_t)(n0w + i * 64 + row8) * K + k0 + colS, Bs + i * 4096 + wave * 512);
      }
    }
    const __bf16* As = (const __bf16*)(smem + cur * 65536);
    const __bf16* Bs = (const __bf16*)(smem + cur * 65536 + 32768);
#pragma unroll
    for (int kk = 0; kk < 2; ++kk) {
      bf16x8 bfv[4];
#pragma unroll
      for (int ct = 0; ct < 4; ++ct)
        bfv[ct] = *(const bf16x8*)(Bs + (wc * 64 + ct * 16 + l15) * 64 + ((kk * 32 + quad * 8) ^ rx));
#pragma unroll
      for (int rt = 0; rt < 8; ++rt) {
        const bf16x8 af = *(const bf16x8*)(As + (wr * 128 + rt * 16 + l15) * 64 + ((kk * 32 + quad * 8) ^ rx));
#pragma unroll
        for (int ct = 0; ct < 4; ++ct)
          acc[rt][ct] = __builtin_amdgcn_mfma_f32_16x16x32_bf16(af, bfv[ct], acc[rt][ct], 0, 0, 0);
      }
    }
    __syncthreads();  // drains staged loads (after compute) + guards buf reuse
  }

  // epilogue: four 64-row passes through cs[64][264]
  const int b  = m0 >> 11;       // batch (S_=2048 rows per batch)
  const int s0 = m0 & (S_ - 1);
  __bf16* vtb = qkv + 2 * NTE;   // Vt lives in the V slot
#pragma unroll
  for (int pass = 0; pass < 4; ++pass) {
    __syncthreads();  // prior pass's readers (or main loop) done
    if (wr == (pass >> 1)) {  // owning waves: rows pass*64 .. pass*64+63
      const int rtb = (pass & 1) * 4;
#pragma unroll
      for (int rt = 0; rt < 4; ++rt)
#pragma unroll
        for (int ct = 0; ct < 4; ++ct)
#pragma unroll
          for (int r = 0; r < 4; ++r)
            cs[(rt * 16 + quad * 4 + r) * 264 + wc * 64 + ct * 16 + l15] =
                (__bf16)acc[rtb + rt][ct][r];
    }
    __syncthreads();
    if (sel < 2) {
      __bf16* C = qkv + (size_t)sel * NTE;
      const int rr = tid >> 3, cb = (tid & 7) * 32;  // 64 rows x 8 col-groups
#pragma unroll
      for (int j2 = 0; j2 < 4; ++j2) {
        const bf16x8 v = *(const bf16x8*)(cs + rr * 264 + cb + j2 * 8);
        *(bf16x8*)(C + (size_t)(m0 + pass * 64 + rr) * N + n0s + cb + j2 * 8) = v;
      }
    } else {
      // transposed: output row = b*1024 + (n0s + e_loc), cols = s
      const int e_loc = tid >> 1, sh = (tid & 1) * 32;  // 256 e x 2 s-halves
      __bf16* dst = vtb + (size_t)(b * 1024 + n0s + e_loc) * S_ + s0 + pass * 64 + sh;
#pragma unroll
      for (int j2 = 0; j2 < 4; ++j2) {
        bf16x8 v;
#pragma unroll
        for (int j = 0; j < 8; ++j)
          v[j] = cs[(sh + j2 * 8 + j) * 264 + e_loc];
        *(bf16x8*)(dst + j2 * 8) = v;
      }
    }
  }
}

// ---------------- O GEMM: 64x128 tiles, 2-phase, T2-swizzled LDS ------------
// 256 thr / 4 waves (2x2), acc[2][4]. LDS 48KB dbuf. XCD 2D swizzle.
__global__ __launch_bounds__(256) void o_gemm(const __bf16* __restrict__ cb,
                                              const __bf16* __restrict__ wo,
                                              float* __restrict__ out) {
  __shared__ __align__(16) char smem[49152];   // 2 x (As 8K + Bs 16K)
  const int lin = blockIdx.y * 8 + blockIdx.x;   // 0..511
  const int xcd = lin & 7, slot = lin >> 3;      // slot 0..63
  const int mi = xcd >> 1, ni = xcd & 1;
  const int mB = mi * 16 + (slot >> 2);          // 0..63
  const int nB = ni * 4  + (slot & 3);           // 0..7
  const int m0 = mB * 64, n0 = nB * 128;
  constexpr int K = D_, N = D_;
  const int tid  = threadIdx.x, lane = tid & 63, wave = tid >> 6;  // 0..3
  const int l15  = lane & 15,   quad = lane >> 4;
  const int wr   = wave >> 1,   wc   = wave & 1;
  const int row8 = tid >> 3;
  const int colS = (((tid & 7) ^ (row8 & 7)) * 8);  // T2 swizzled global col
  const int rx   = (l15 & 7) << 3;                  // read-side XOR

  f32x4 acc[2][4] = {};
  {
    __bf16* As = (__bf16*)(smem);
    __bf16* Bs = (__bf16*)(smem + 8192);
#pragma unroll
    for (int i = 0; i < 2; ++i)
      async16(cb + (size_t)(m0 + i * 32 + row8) * K + colS, As + i * 2048 + wave * 512);
#pragma unroll
    for (int i = 0; i < 4; ++i)
      async16(wo + (size_t)(n0 + i * 32 + row8) * K + colS, Bs + i * 2048 + wave * 512);
  }
  __syncthreads();

  for (int t = 0; t < K / 64; ++t) {
    const int cur = t & 1;
    if (t + 1 < K / 64) {
      const int k0 = (t + 1) * 64;
      __bf16* As = (__bf16*)(smem + (cur ^ 1) * 24576);
      __bf16* Bs = (__bf16*)(smem + (cur ^ 1) * 24576 + 8192);
#pragma unroll
      for (int i = 0; i < 2; ++i)
        async16(cb + (size_t)(m0 + i * 32 + row8) * K + k0 + colS, As + i * 2048 + wave * 512);
#pragma unroll
      for (int i = 0; i < 4; ++i)
        async16(wo + (size_t)(n0 + i * 32 + row8) * K + k0 + colS, Bs + i * 2048 + wave * 512);
    }
    const __bf16* As = (const __bf16*)(smem + cur * 24576);
    const __bf16* Bs = (const __bf16*)(smem + cur * 24576 + 8192);
#pragma unroll
    for (int kk = 0; kk < 2; ++kk) {
      bf16x8 af[2], bfv[4];
#pragma unroll
      for (int rt = 0; rt < 2; ++rt)
        af[rt] = *(const bf16x8*)(As + (wr * 32 + rt * 16 + l15) * 64 + ((kk * 32 + quad * 8) ^ rx));
#pragma unroll
      for (int ct = 0; ct < 4; ++ct)
        bfv[ct] = *(const bf16x8*)(Bs + (wc * 64 + ct * 16 + l15) * 64 + ((kk * 32 + quad * 8) ^ rx));
#pragma unroll
      for (int rt = 0; rt < 2; ++rt)
#pragma unroll
        for (int ct = 0; ct < 4; ++ct)
          acc[rt][ct] = __builtin_amdgcn_mfma_f32_16x16x32_bf16(af[rt], bfv[ct], acc[rt][ct], 0, 0, 0);
    }
    __syncthreads();
  }
#pragma unroll
  for (int rt = 0; rt < 2; ++rt)
#pragma unroll
    for (int ct = 0; ct < 4; ++ct)
#pragma unroll
      for (int r = 0; r < 4; ++r) {
        const int row = m0 + wr * 32 + rt * 16 + quad * 4 + r;
        const int col = n0 + wc * 64 + ct * 16 + l15;
        out[(size_t)row * N + col] = acc[rt][ct][r];
      }
}

// ---------------- flash attention: single barrier per KV tile (r8) ----------
// 8 waves x 16 q, 128-key tiles. S^T = K·Q^T: lane holds P[q=l15][32 keys];
// in-register P via cvt_pk + permlane32/16_swap; row-sum l via ones-MFMA;
// max-reduce via __shfl_xor; defer-max (THR=8, exp2 domain); T14 reg-prefetch
// + dbuf K/V, single barrier/tile. No XCD swizzle (r5: L2-fit, m160).
// kt/vt padded (144/272 B strides) -> already bank-conflict-benign.
__global__ __launch_bounds__(512, 4) void attn2(const __bf16* __restrict__ Q,
                                                const __bf16* __restrict__ K,
                                                const __bf16* __restrict__ Vt,
                                                const float* __restrict__ mask,
                                                __bf16* __restrict__ O) {
  constexpr int LKT = 72, LVT = 136;
  __shared__ __align__(16) __bf16 kt[2][128 * LKT];   // 2 x 18432 B
  __shared__ __align__(16) __bf16 vt[2][64 * LVT];    // 2 x 17408 B
  __shared__ __align__(16) float  mfull[S_];          // 8192 B (pre-scaled by log2e)

  const int tid  = threadIdx.x, lane = tid & 63, wave = tid >> 6;
  const int l15  = lane & 15,   quad = lane >> 4;
  const int b = blockIdx.z, h = blockIdx.y, q0 = blockIdx.x * 128;
  const size_t base   = (size_t)b * S_ * D_ + h * HD_;
  const size_t vtbase = (size_t)(b * H_ + h) * HD_ * S_;
  const int qw = q0 + wave * 16;
  constexpr float LOG2E = 1.44269504088896340736f;
  constexpr float SC    = 0.125f * LOG2E;          // 1/sqrt(HD) * log2(e)
  constexpr int  NT     = S_ / 128;

  // per-thread staging slots (2 x 16B each for K and V tiles)
  const int idx0 = tid,        kr0 = idx0 >> 3, kc0 = (idx0 & 7) * 8;
  const int idx1 = 512 + tid,  kr1 = idx1 >> 3, kc1 = (idx1 & 7) * 8;
  const int vr0 = idx0 >> 4, vc0 = (idx0 & 15) * 8;
  const int vr1 = idx1 >> 4, vc1 = (idx1 & 15) * 8;

  // Q fragments (B-operand: n=l15 -> q row, k = kb*32+quad*8+j)
  bf16x8 qf[2];
#pragma unroll
  for (int kb = 0; kb < 2; ++kb)
    qf[kb] = *(const bf16x8*)(Q + base + (size_t)(qw + l15) * D_ + kb * 32 + quad * 8);

  bf16x8 ones;
#pragma unroll
  for (int j = 0; j < 8; ++j) ones[j] = (__bf16)1.0f;

  float m_run = -1e30f;
  f32x4 oacc[4] = {};
  f32x4 lacc   = {};

  // prologue: mask table + tile 0 -> buf 0 + issue tile 1 loads
  bf16x8 rk0, rk1, rv0, rv1;
  rk0 = *(const bf16x8*)(K + base + (size_t)kr0 * D_ + kc0);
  rk1 = *(const bf16x8*)(K + base + (size_t)kr1 * D_ + kc1);
  rv0 = *(const bf16x8*)(Vt + vtbase + (size_t)vr0 * S_ + vc0);
  rv1 = *(const bf16x8*)(Vt + vtbase + (size_t)vr1 * S_ + vc1);
#pragma unroll
  for (int i = 0; i < S_ / 512; ++i)
    mfull[i * 512 + tid] = mask[(size_t)b * S_ + i * 512 + tid] * LOG2E;
  *(bf16x8*)(&kt[0][kr0 * LKT + kc0]) = rk0;
  *(bf16x8*)(&kt[0][kr1 * LKT + kc1]) = rk1;
  *(bf16x8*)(&vt[0][vr0 * LVT + vc0]) = rv0;
  *(bf16x8*)(&vt[0][vr1 * LVT + vc1]) = rv1;
  if (NT > 1) {  // issue tile 1 loads (land before their ds_write in iter 0)
    rk0 = *(const bf16x8*)(K + base + (size_t)(128 + kr0) * D_ + kc0);
    rk1 = *(const bf16x8*)(K + base + (size_t)(128 + kr1) * D_ + kc1);
    rv0 = *(const bf16x8*)(Vt + vtbase + (size_t)vr0 * S_ + 128 + vc0);
    rv1 = *(const bf16x8*)(Vt + vtbase + (size_t)vr1 * S_ + 128 + vc1);
  }
  __syncthreads();

  for (int t = 0; t < NT; ++t) {
    const int cur = t & 1;
    const int t0  = t * 128;
    const __bf16* ktb = &kt[cur][0];
    const __bf16* vtb = &vt[cur][0];

    // write staged tile t+1 into buf[cur^1] (race-free: barrier ended iter t-1)
    if (t + 1 < NT) {
      const int nxt = cur ^ 1;
      *(bf16x8*)(&kt[nxt][kr0 * LKT + kc0]) = rk0;
      *(bf16x8*)(&kt[nxt][kr1 * LKT + kc1]) = rk1;
      *(bf16x8*)(&vt[nxt][vr0 * LVT + vc0]) = rv0;
      *(bf16x8*)(&vt[nxt][vr1 * LVT + vc1]) = rv1;
    }
    // issue tile t+2 global loads (full-tile latency hiding)
    if (t + 2 < NT) {
      const int tn = t0 + 256;
      rk0 = *(const bf16x8*)(K + base + (size_t)(tn + kr0) * D_ + kc0);
      rk1 = *(const bf16x8*)(K + base + (size_t)(tn + kr1) * D_ + kc1);
      rv0 = *(const bf16x8*)(Vt + vtbase + (size_t)vr0 * S_ + tn + vc0);
      rv1 = *(const bf16x8*)(Vt + vtbase + (size_t)vr1 * S_ + tn + vc1);
    }

    // S^T tile: D[m=key][n=q]; lane (l15,quad): key = kti*16+quad*4+r, q = l15
    f32x4 sacc[8] = {};
    __builtin_amdgcn_s_setprio(1);
#pragma unroll
    for (int kti = 0; kti < 8; ++kti) {
      const __bf16* kr = ktb + (kti * 16 + l15) * LKT + quad * 8;
      const bf16x8 a0 = *(const bf16x8*)(kr);
      const bf16x8 a1 = *(const bf16x8*)(kr + 32);
      sacc[kti] = __builtin_amdgcn_mfma_f32_16x16x32_bf16(a0, qf[0], sacc[kti], 0, 0, 0);
      sacc[kti] = __builtin_amdgcn_mfma_f32_16x16x32_bf16(a1, qf[1], sacc[kti], 0, 0, 0);
    }
    __builtin_amdgcn_s_setprio(0);

    // scale (exp2 domain) + mask, running max with 4 independent chains
    f32x4 tm4;
#pragma unroll
    for (int r = 0; r < 4; ++r) tm4[r] = -1e30f;
#pragma unroll
    for (int kti = 0; kti < 8; ++kti) {
      const f32x4 mv = *(const f32x4*)(mfull + t0 + kti * 16 + quad * 4);
#pragma unroll
      for (int r = 0; r < 4; ++r) {
        sacc[kti][r] = sacc[kti][r] * SC + mv[r];
        tm4[r] = fmaxf(tm4[r], sacc[kti][r]);
      }
    }
    float tm = fmaxf(fmaxf(tm4[0], tm4[1]), fmaxf(tm4[2], tm4[3]));
    tm = fmaxf(tm, __shfl_xor(tm, 16));
    tm = fmaxf(tm, __shfl_xor(tm, 32));

    // defer-max (T13): only rescale when tile max grows past THR=8 (p <= 2^8)
    if (!__all(tm <= m_run + 8.f)) {
      const float mnew  = fmaxf(m_run, tm);
      const float alpha = __builtin_amdgcn_exp2f(m_run - mnew);
      m_run = mnew;
#pragma unroll
      for (int r = 0; r < 4; ++r) {
        const float aR = __shfl(alpha, quad * 4 + r);
        lacc[r] *= aR;
#pragma unroll
        for (int nt = 0; nt < 4; ++nt) oacc[nt][r] *= aR;
      }
    }

    // exp2 + pack + permlane-redistribute + PV + row-sum, per kb (32 keys each)
#pragma unroll
    for (int kb = 0; kb < 4; ++kb) {
      unsigned dd[2][2];
#pragma unroll
      for (int kk = 0; kk < 2; ++kk) {
        const int kti = 2 * kb + kk;
        float p[4];
#pragma unroll
        for (int r = 0; r < 4; ++r)
          p[r] = __builtin_amdgcn_exp2f(sacc[kti][r] - m_run);
        dd[kk][0] = cvt_pk_bf16(p[0], p[1]);
        dd[kk][1] = cvt_pk_bf16(p[2], p[3]);
      }
      // quad shuffle: rows [A0,A1,A2,A3],[B0,B1,B2,B3] -> [A0,A2,B0,B2],[A1,A3,B1,B3]
      unsigned a0 = dd[0][0], b0 = dd[1][0], a1 = dd[0][1], b1 = dd[1][1];
      asm("v_permlane32_swap_b32 %0, %1" : "+v"(a0), "+v"(b0));
      asm("v_permlane16_swap_b32 %0, %1" : "+v"(a0), "+v"(b0));
      asm("v_permlane32_swap_b32 %0, %1" : "+v"(a1), "+v"(b1));
      asm("v_permlane16_swap_b32 %0, %1" : "+v"(a1), "+v"(b1));
      union { unsigned u[4]; bf16x8 v; } pw;
      pw.u[0] = a0; pw.u[1] = a1; pw.u[2] = b0; pw.u[3] = b1;
      const bf16x8 pa = pw.v;  // A[q=l15][key = kb*32 + quad*8 + j]
      __builtin_amdgcn_s_setprio(1);
      lacc = __builtin_amdgcn_mfma_f32_16x16x32_bf16(pa, ones, lacc, 0, 0, 0);
#pragma unroll
      for (int nt = 0; nt < 4; ++nt) {
        const bf16x8 vf = *(const bf16x8*)(vtb + (nt * 16 + l15) * LVT + kb * 32 + quad * 8);
        oacc[nt] = __builtin_amdgcn_mfma_f32_16x16x32_bf16(pa, vf, oacc[nt], 0, 0, 0);
      }
      __builtin_amdgcn_s_setprio(0);
    }

    __syncthreads();  // single barrier: ds_writes visible + buf reuse guarded
  }

  // epilogue: divide by l (already in row layout via ones-MFMA), store ctx
#pragma unroll
  for (int r = 0; r < 4; ++r) {
    const float inv = 1.0f / lacc[r];
    const int row = qw + quad * 4 + r;
#pragma unroll
    for (int nt = 0; nt < 4; ++nt)
      O[base + (size_t)row * D_ + nt * 16 + l15] = (__bf16)(oacc[nt][r] * inv);
  }
}

extern "C" void kernel_launch(void* const* d_in, const int* in_sizes, int n_in,
                              void* d_out, int out_size, void* d_ws, size_t ws_size,
                              hipStream_t stream) {
  const float* x    = (const float*)d_in[0];
  const float* mask = (const float*)d_in[1];
  const float* Wq   = (const float*)d_in[2];
  const float* Wk   = (const float*)d_in[3];
  const float* Wv   = (const float*)d_in[4];
  const float* Wo   = (const float*)d_in[5];

  char* ws = (char*)d_ws;
  const size_t MB = 1ull << 20;
  const size_t NT = (size_t)B_ * S_ * D_;  // 4M elems, 8 MB bf16
  __bf16* xb  = (__bf16*)(ws);             // 8 MB; freed after qkv_gemm -> reused as cb
  __bf16* wqb = (__bf16*)(ws + 8 * MB);    // wq/wk/wv contiguous = packed [3072][1024]
  __bf16* wkb = (__bf16*)(ws + 10 * MB);
  __bf16* wvb = (__bf16*)(ws + 12 * MB);
  __bf16* wob = (__bf16*)(ws + 14 * MB);
  __bf16* qkv = (__bf16*)(ws + 16 * MB);   // 24 MB: Q, K, Vt
  __bf16* qb  = qkv;
  __bf16* kb  = qkv + NT;
  __bf16* vtb = qkv + 2 * NT;  // qkv_gemm sel==2 writes V pre-transposed here
  __bf16* cb  = xb;            // x consumed by qkv_gemm before attn writes ctx

  cvt_all<<<dim3(1024, 5), 256, 0, stream>>>(x, Wq, Wk, Wv, Wo, xb, wqb, wkb, wvb, wob);
  qkv_gemm<<<dim3(12, 16), 512, 0, stream>>>(xb, wqb, qkv);
  attn2<<<dim3(S_ / 128, H_, B_), 512, 0, stream>>>(qb, kb, vtb, mask, cb);
  o_gemm<<<dim3(8, 64), 256, 0, stream>>>(cb, wob, (float*)d_out);
}